// Round 4
// baseline (6918.358 us; speedup 1.0000x reference)
//
#include <hip/hip_runtime.h>
#include <hip/hip_bf16.h>

typedef __hip_bfloat16 bf16;

#define A_  5
#define D_  512
#define E_  256
#define NS_ 2048
#define NQ_ 8192
#define NWAY_ 5

// ---- per-tensor dtype dispatch: flags[i]=1 -> input i is f32, 0 -> bf16 ----
__device__ inline float ldw(const void* p, size_t i, int f32) {
  return f32 ? ((const float*)p)[i] : __bfloat162float(((const bf16*)p)[i]);
}
template<bool DYN>
__device__ inline float ldT(const void* p, size_t i, int f32) {
  if (DYN) return ldw(p, i, f32);
  return ((const float*)p)[i];
}

struct Ptrs { const void* p[64]; int sz[64]; };

__global__ void probe_k(Ptrs P, int* flags) {
  int b = blockIdx.x;
  if (threadIdx.x != 0) return;
  if (b == 1 || b == 3) { flags[b] = 0; return; }   // int tensors
  const bf16* t = (const bf16*)P.p[b];
  int n = P.sz[b];
  int K = (n >> 1) < 64 ? (n >> 1) : 64;
  int big = 0, cntE = 0, cntO = 0;
  for (int k = 0; k < K; ++k) {
    float e = __bfloat162float(t[2 * k]);
    float o = __bfloat162float(t[2 * k + 1]);
    if (!(fabsf(e) <= 1e3f)) big++;
    if (e != 0.f) cntE++;
    if (o != 0.f) cntO++;
  }
  flags[b] = (big > 0 || (cntE == 0 && cntO > 0)) ? 1 : 0;
}

// ---------------- generic tiled GEMM: C[M,N] = act(alpha*A@B (+C) (+bias)) ----------------
template<bool DYNA, bool DYNB, bool DYNBIAS, bool TRB, int ACT, bool ACCUM>
__global__ __launch_bounds__(256) void gemm_k(
    const void* __restrict__ A, int lda,
    const void* __restrict__ B, int ldb, size_t offB,
    const void* __restrict__ bias, size_t offBias,
    float* __restrict__ C, int ldc,
    int M, int N, int K, float alpha,
    int ia, int ib, int ibias, const int* __restrict__ flags)
{
  const int fA = DYNA ? flags[ia] : 1;
  const int fB = DYNB ? flags[ib] : 1;
  const int fBi = DYNBIAS ? flags[ibias] : 1;
  __shared__ float As[16][68];
  __shared__ float Bs[16][68];
  int tid = threadIdx.x;
  int tx = tid & 15, ty = tid >> 4;
  int bm = blockIdx.y * 64, bn = blockIdx.x * 64;
  float acc[4][4] = {{0.f}};
  int am = tid >> 2;
  int ak = (tid & 3) * 4;
  for (int k0 = 0; k0 < K; k0 += 16) {
    {
      int gm = bm + am;
      size_t abase = (size_t)gm * lda + k0 + ak;
      #pragma unroll
      for (int i = 0; i < 4; ++i) {
        float v = 0.f;
        if (gm < M && (k0 + ak + i) < K) v = ldT<DYNA>(A, abase + i, fA);
        As[ak + i][am] = v;
      }
    }
    if (!TRB) {
      int bk = tid >> 4;
      int bn0 = (tid & 15) * 4;
      size_t bbase = offB + (size_t)(k0 + bk) * ldb + bn + bn0;
      #pragma unroll
      for (int j = 0; j < 4; ++j) {
        float v = 0.f;
        if ((k0 + bk) < K && (bn + bn0 + j) < N) v = ldT<DYNB>(B, bbase + j, fB);
        Bs[bk][bn0 + j] = v;
      }
    } else {
      int bnn = tid >> 2;
      int bkq = (tid & 3) * 4;
      size_t bbase = offB + (size_t)(bn + bnn) * ldb + k0 + bkq;
      #pragma unroll
      for (int i = 0; i < 4; ++i) {
        float v = 0.f;
        if ((bn + bnn) < N && (k0 + bkq + i) < K) v = ldT<DYNB>(B, bbase + i, fB);
        Bs[bkq + i][bnn] = v;
      }
    }
    __syncthreads();
    #pragma unroll
    for (int k = 0; k < 16; ++k) {
      float4 av = *(const float4*)(&As[k][ty * 4]);
      float4 bv = *(const float4*)(&Bs[k][tx * 4]);
      float a0[4] = {av.x, av.y, av.z, av.w};
      float b0[4] = {bv.x, bv.y, bv.z, bv.w};
      #pragma unroll
      for (int i = 0; i < 4; ++i)
        #pragma unroll
        for (int j = 0; j < 4; ++j)
          acc[i][j] += a0[i] * b0[j];
    }
    __syncthreads();
  }
  #pragma unroll
  for (int i = 0; i < 4; ++i) {
    int r = bm + ty * 4 + i;
    if (r >= M) continue;
    #pragma unroll
    for (int j = 0; j < 4; ++j) {
      int c = bn + tx * 4 + j;
      if (c >= N) continue;
      float v = acc[i][j] * alpha;
      if (ACCUM) v += C[(size_t)r * ldc + c];
      if (bias) v += ldT<DYNBIAS>(bias, offBias + c, fBi);
      if (ACT == 1) v = fmaxf(v, 0.f);
      else if (ACT == 2) v = tanhf(v);
      else if (ACT == 3) v = 1.f / (1.f + expf(-v));
      C[(size_t)r * ldc + c] = v;
    }
  }
}

template<bool DYNA, bool DYNB, bool DYNBIAS, bool TRB, int ACT, bool ACCUM>
static void gemm(hipStream_t s, const void* A, int lda, const void* B, int ldb, size_t offB,
                 const void* bias, size_t offBias, float* C, int ldc, int M, int N, int K,
                 float alpha, int ia, int ib, int ibias, const int* flags) {
  dim3 g((N + 63) / 64, (M + 63) / 64), b(256);
  gemm_k<DYNA, DYNB, DYNBIAS, TRB, ACT, ACCUM><<<g, b, 0, s>>>(
      A, lda, B, ldb, offB, bias, offBias, C, ldc, M, N, K, alpha, ia, ib, ibias, flags);
}

// ---------------- LayerNorm (+relu/sigmoid) over last dim W, block per row ----------------
template<int ACT>
__global__ __launch_bounds__(256) void ln_k(const float* __restrict__ X, const void* __restrict__ g,
                                            const void* __restrict__ be, float* __restrict__ Y, int W,
                                            int ig, int ibe, const int* __restrict__ flags) {
  const int fG = flags[ig], fBe = flags[ibe];
  int row = blockIdx.x;
  const float* x = X + (size_t)row * W;
  float* y = Y + (size_t)row * W;
  __shared__ float red[256];
  int tid = threadIdx.x;
  float s1 = 0.f, s2 = 0.f;
  for (int i = tid; i < W; i += 256) { float v = x[i]; s1 += v; s2 += v * v; }
  red[tid] = s1; __syncthreads();
  for (int o = 128; o > 0; o >>= 1) { if (tid < o) red[tid] += red[tid + o]; __syncthreads(); }
  float mean = red[0] / W; __syncthreads();
  red[tid] = s2; __syncthreads();
  for (int o = 128; o > 0; o >>= 1) { if (tid < o) red[tid] += red[tid + o]; __syncthreads(); }
  float var = fmaxf(red[0] / W - mean * mean, 0.f);
  float rstd = rsqrtf(var + 1e-5f);
  for (int i = tid; i < W; i += 256) {
    float v = (x[i] - mean) * rstd * ldw(g, i, fG) + ldw(be, i, fBe);
    if (ACT == 1) v = fmaxf(v, 0.f);
    else if (ACT == 3) v = 1.f / (1.f + expf(-v));
    y[i] = v;
  }
}

// ---------------- comm round ----------------
__global__ void agent_state_k(const float* __restrict__ feats_s, const void* __restrict__ internal,
                              float* __restrict__ state, const int* __restrict__ flags) {
  const int fI = flags[46];
  int a = blockIdx.x, e = threadIdx.x;
  const float* p = feats_s + (size_t)a * NS_ * E_ + e;
  float s = 0.f;
  for (int n = 0; n < NS_; ++n) s += p[(size_t)n * E_];
  state[a * E_ + e] = s * (1.f / NS_) + ldw(internal, (size_t)a * E_ + e, fI);
}

__global__ void messages_k(const float* __restrict__ state, const void* __restrict__ W,
                           const void* __restrict__ b, float* __restrict__ msg,
                           const int* __restrict__ flags) {
  const int fW = flags[36], fB = flags[37];
  int a = blockIdx.x, f = threadIdx.x;
  __shared__ float st[E_];
  st[f] = state[a * E_ + f]; __syncthreads();
  size_t wbase = (size_t)a * E_ * E_ + f;
  float s = 0.f;
  for (int e = 0; e < E_; ++e) s += st[e] * ldw(W, wbase + (size_t)e * E_, fW);
  msg[a * E_ + f] = tanhf(s + ldw(b, (size_t)a * E_ + f, fB));
}

__global__ __launch_bounds__(256) void comm_k(
    const float* __restrict__ msg, const void* __restrict__ comm_w,
    const void* __restrict__ in_w, const void* __restrict__ in_b,
    const void* __restrict__ out_w, const void* __restrict__ out_b,
    const void* __restrict__ internal,
    const void* __restrict__ pw1, const void* __restrict__ pb1,
    const void* __restrict__ pw2, const void* __restrict__ pb2,
    float* __restrict__ ck, const int* __restrict__ flags)
{
  const int fCW = flags[57], fIW = flags[38], fIB = flags[39], fOW = flags[40], fOB = flags[41];
  const int fIN = flags[46], fP1 = flags[42], fQ1 = flags[43], fP2 = flags[44], fQ2 = flags[45];
  int a = blockIdx.x, tid = threadIdx.x;
  __shared__ float m[4][E_];
  __shared__ float qkv[4][3 * E_];
  __shared__ float attw[4][4][4];
  __shared__ float obar[E_];
  __shared__ float comb[E_];
  __shared__ float hh[E_];
  float w[5]; float mx = -1e30f;
  for (int j = 0; j < 5; ++j) { w[j] = ldw(comm_w, a * 5 + j, fCW); mx = fmaxf(mx, w[j]); }
  float sum = 0.f;
  for (int j = 0; j < 5; ++j) { w[j] = expf(w[j] - mx); sum += w[j]; }
  for (int j = 0; j < 5; ++j) w[j] /= sum;
  int others[4]; { int c = 0; for (int j = 0; j < 5; ++j) if (j != a) others[c++] = j; }
  for (int t = 0; t < 4; ++t) m[t][tid] = msg[others[t] * E_ + tid] * w[others[t]];
  __syncthreads();
  for (int f = tid; f < 3 * E_; f += 256) {
    size_t wr = (size_t)a * 3 * E_ * E_ + (size_t)f * E_;
    float a0 = 0.f, a1 = 0.f, a2 = 0.f, a3 = 0.f;
    for (int e = 0; e < E_; ++e) {
      float ww = ldw(in_w, wr + e, fIW);
      a0 += m[0][e] * ww; a1 += m[1][e] * ww; a2 += m[2][e] * ww; a3 += m[3][e] * ww;
    }
    float bb = ldw(in_b, (size_t)a * 3 * E_ + f, fIB);
    qkv[0][f] = a0 + bb; qkv[1][f] = a1 + bb; qkv[2][f] = a2 + bb; qkv[3][f] = a3 + bb;
  }
  __syncthreads();
  if (tid < 16) {
    int h = tid >> 2, t = tid & 3;
    float sc[4]; float mx2 = -1e30f;
    for (int t2 = 0; t2 < 4; ++t2) {
      float s = 0.f;
      for (int d = 0; d < 64; ++d) s += qkv[t][h * 64 + d] * qkv[t2][E_ + h * 64 + d];
      sc[t2] = s * 0.125f; mx2 = fmaxf(mx2, sc[t2]);
    }
    float ss = 0.f;
    for (int t2 = 0; t2 < 4; ++t2) { sc[t2] = expf(sc[t2] - mx2); ss += sc[t2]; }
    for (int t2 = 0; t2 < 4; ++t2) attw[h][t][t2] = sc[t2] / ss;
  }
  __syncthreads();
  {
    int e = tid, h = e >> 6;
    float s = 0.f;
    for (int t = 0; t < 4; ++t)
      for (int t2 = 0; t2 < 4; ++t2)
        s += attw[h][t][t2] * qkv[t2][2 * E_ + e];
    obar[e] = s * 0.25f;
  }
  __syncthreads();
  {
    int f = tid;
    size_t wr = (size_t)a * E_ * E_ + (size_t)f * E_;
    float s = 0.f;
    for (int e = 0; e < E_; ++e) s += obar[e] * ldw(out_w, wr + e, fOW);
    comb[f] = ldw(internal, (size_t)a * E_ + f, fIN) + s + ldw(out_b, (size_t)a * E_ + f, fOB);
  }
  __syncthreads();
  {
    int f = tid; float s = 0.f;
    size_t wr = (size_t)a * E_ * E_ + f;
    for (int e = 0; e < E_; ++e) s += comb[e] * ldw(pw1, wr + (size_t)e * E_, fP1);
    hh[f] = fmaxf(s + ldw(pb1, (size_t)a * E_ + f, fQ1), 0.f);
  }
  __syncthreads();
  {
    int f = tid; float s = 0.f;
    size_t wr = (size_t)a * E_ * E_ + f;
    for (int e = 0; e < E_; ++e) s += hh[e] * ldw(pw2, wr + (size_t)e * E_, fP2);
    ck[a * E_ + f] = s + ldw(pb2, (size_t)a * E_ + f, fQ2);
  }
}

// ---------------- attention helpers ----------------
__global__ void addck_k(const float* __restrict__ fs, const float* __restrict__ ck, float* __restrict__ xs) {
  int i = blockIdx.x * 256 + threadIdx.x;
  xs[i] = fs[i] + ck[i & (E_ - 1)];
}

__global__ __launch_bounds__(256) void softmax_mask_k(float* __restrict__ scores, const int* __restrict__ y) {
  int i = blockIdx.x;
  int h = blockIdx.y;
  float* row = scores + (size_t)h * NS_ * NS_ + (size_t)i * NS_;
  int yi = y[i];
  __shared__ float red[256];
  int tid = threadIdx.x;
  float mx = -1e30f;
  for (int j = tid; j < NS_; j += 256) {
    float v = (y[j] == yi) ? row[j] : -1e9f;
    mx = fmaxf(mx, v);
  }
  red[tid] = mx; __syncthreads();
  for (int o = 128; o > 0; o >>= 1) { if (tid < o) red[tid] = fmaxf(red[tid], red[tid + o]); __syncthreads(); }
  mx = red[0]; __syncthreads();
  float s = 0.f;
  for (int j = tid; j < NS_; j += 256) {
    float v = (y[j] == yi) ? expf(row[j] - mx) : 0.f;
    row[j] = v; s += v;
  }
  red[tid] = s; __syncthreads();
  for (int o = 128; o > 0; o >>= 1) { if (tid < o) red[tid] += red[tid + o]; __syncthreads(); }
  float inv = 1.f / red[0];
  for (int j = tid; j < NS_; j += 256) row[j] *= inv;
}

__global__ void protos_k(const float* __restrict__ att, const int* __restrict__ y, float* __restrict__ protos) {
  int c = blockIdx.x, e = threadIdx.x;
  float s = 0.f; int cnt = 0;
  for (int n = 0; n < NS_; ++n) {
    if (y[n] == c) { s += att[(size_t)n * E_ + e]; cnt++; }
  }
  protos[c * E_ + e] = (cnt > 0) ? s / (float)cnt : 0.f;
}

__global__ void bias2_k(const float* __restrict__ ck, const void* __restrict__ w1,
                        const void* __restrict__ b1, int a, float* __restrict__ bias2,
                        const int* __restrict__ flags) {
  const int fW = flags[51], fB = flags[52];
  int n = threadIdx.x;
  __shared__ float c[E_];
  c[n] = ck[n]; __syncthreads();
  size_t wbase = (size_t)a * 2 * E_ * E_ + (size_t)E_ * E_ + n;
  float s = 0.f;
  for (int k = 0; k < E_; ++k) s += c[k] * ldw(w1, wbase + (size_t)k * E_, fW);
  bias2[n] = s + ldw(b1, (size_t)a * E_ + n, fB);
}

// ---------------- epilogues (wave per query row) — OUTPUT IS FLOAT32 ----------------
__device__ inline float wave_sum(float v) {
  for (int o = 32; o > 0; o >>= 1) v += __shfl_down(v, o);
  return v;
}

__global__ __launch_bounds__(64) void logits_k(const float* __restrict__ fq, const float* __restrict__ protos,
                                               const float* __restrict__ c2, const void* __restrict__ w3,
                                               const void* __restrict__ b3, int a, float* __restrict__ out,
                                               const int* __restrict__ flags) {
  const int fW = flags[55], fB = flags[56];
  int i = blockIdx.x, lane = threadIdx.x;
  float4 xv = ((const float4*)(fq + (size_t)i * E_))[lane];
  float qq = wave_sum(xv.x * xv.x + xv.y * xv.y + xv.z * xv.z + xv.w * xv.w);
  float cpart = c2[(size_t)i * 128 + lane * 2] * ldw(w3, (size_t)a * 128 + lane * 2, fW) +
                c2[(size_t)i * 128 + lane * 2 + 1] * ldw(w3, (size_t)a * 128 + lane * 2 + 1, fW);
  float conf = wave_sum(cpart);
  if (lane == 0) conf += ldw(b3, a, fB);
  for (int c = 0; c < NWAY_; ++c) {
    float4 pv = ((const float4*)(protos + c * E_))[lane];
    float dt = wave_sum(xv.x * pv.x + xv.y * pv.y + xv.z * pv.z + xv.w * pv.w);
    float pp = wave_sum(pv.x * pv.x + pv.y * pv.y + pv.z * pv.z + pv.w * pv.w);
    if (lane == 0) {
      float d2 = fmaxf(qq + pp - 2.f * dt, 1e-12f);
      out[(size_t)i * NWAY_ + c] = -sqrtf(d2) + 0.1f * conf;
    }
  }
}

__global__ __launch_bounds__(64) void fused_k(const float* __restrict__ h2, const void* __restrict__ w3,
                                              const void* __restrict__ b3, float* __restrict__ out,
                                              const int* __restrict__ flags) {
  const int fW = flags[62], fB = flags[63];
  int i = blockIdx.x, lane = threadIdx.x;
  float s = h2[(size_t)i * 128 + lane * 2] * ldw(w3, lane * 2, fW) +
            h2[(size_t)i * 128 + lane * 2 + 1] * ldw(w3, lane * 2 + 1, fW);
  s = wave_sum(s);
  if (lane == 0) out[i] = s + ldw(b3, 0, fB);
}

// ---------------- host ----------------
extern "C" void kernel_launch(void* const* d_in, const int* in_sizes, int n_in,
                              void* d_out, int out_size, void* d_ws, size_t ws_size,
                              hipStream_t stream) {
  (void)out_size; (void)ws_size;
  #define P(i) ((const void*)d_in[i])
  const int* support_y = (const int*)d_in[1];
  float* out = (float*)d_out;   // reference output dtype is float32

  int* flags = (int*)d_ws;                              // 64 ints
  float* W = (float*)((char*)d_ws + 256);
  float* feats_s = W;                                   // A*NS*E
  float* feats_q = feats_s + (size_t)A_ * NS_ * E_;     // A*NQ*E
  float* U1      = feats_q + (size_t)A_ * NQ_ * E_;     // 2*NS*NS (== NQ*768 + NQ*256)
  float* qkv_s   = U1 + (size_t)2 * NS_ * NS_;          // NS*768
  float* attb    = qkv_s + (size_t)NS_ * 3 * E_;        // NS*E
  float* att_out = attb + (size_t)NS_ * E_;             // NS*E
  float* smalls  = att_out + (size_t)NS_ * E_;
  float* state  = smalls;
  float* msg    = state + A_ * E_;
  float* ck     = msg + A_ * E_;
  float* protos = ck + A_ * E_;
  float* bias2  = protos + NWAY_ * E_;

  float* t1 = U1;
  float* t2 = U1 + (size_t)NQ_ * 3 * E_;

  Ptrs ps;
  for (int i = 0; i < 64; ++i) {
    ps.p[i] = (i < n_in) ? d_in[i] : nullptr;
    ps.sz[i] = (i < n_in) ? in_sizes[i] : 0;
  }
  probe_k<<<64, 64, 0, stream>>>(ps, flags);

  auto fe = [&](const void* x, int xi, int N, float* feats) {
    gemm<true, true, true, false, 0, false>(stream, x, 512, P(4), 512, 0, P(5), 0, t1, 512, N, 512, 512, 1.f, xi, 4, 5, flags);
    ln_k<1><<<N, 256, 0, stream>>>(t1, P(6), P(7), t1, 512, 6, 7, flags);
    gemm<false, true, true, false, 0, false>(stream, t1, 512, P(8), 256, 0, P(9), 0, t2, 256, N, 256, 512, 1.f, -1, 8, 9, flags);
    ln_k<1><<<N, 256, 0, stream>>>(t2, P(10), P(11), feats, 256, 10, 11, flags);
    gemm<true, true, true, false, 0, false>(stream, x, 512, P(12), 256, 0, P(13), 0, t2, 256, N, 256, 512, 1.f, xi, 12, 13, flags);
    ln_k<1><<<N, 256, 0, stream>>>(t2, P(14), P(15), t2, 256, 14, 15, flags);
    gemm<false, true, true, false, 2, false>(stream, t2, 256, P(16), 256, 0, P(17), 0, feats + (size_t)N * E_, 256, N, 256, 256, 1.f, -1, 16, 17, flags);
    gemm<true, true, true, false, 1, false>(stream, x, 512, P(18), 768, 0, P(19), 0, t1, 768, N, 768, 512, 1.f, xi, 18, 19, flags);
    gemm<false, true, true, false, 0, false>(stream, t1, 768, P(20), 256, 0, P(21), 0, t2, 256, N, 256, 768, 1.f, -1, 20, 21, flags);
    ln_k<1><<<N, 256, 0, stream>>>(t2, P(22), P(23), feats + (size_t)2 * N * E_, 256, 22, 23, flags);
    gemm<true, true, true, false, 1, false>(stream, x, 512, P(24), 256, 0, P(25), 0, t2, 256, N, 256, 512, 1.f, xi, 24, 25, flags);
    gemm<false, true, true, false, 0, false>(stream, t2, 256, P(26), 256, 0, P(27), 0, t1, 256, N, 256, 256, 1.f, -1, 26, 27, flags);
    ln_k<3><<<N, 256, 0, stream>>>(t1, P(28), P(29), feats + (size_t)3 * N * E_, 256, 28, 29, flags);
    gemm<true, true, true, false, 1, false>(stream, x, 512, P(30), 512, 0, P(31), 0, t1, 512, N, 512, 512, 1.f, xi, 30, 31, flags);
    gemm<false, true, true, false, 1, false>(stream, t1, 512, P(32), 256, 0, P(33), 0, t2, 256, N, 256, 512, 1.f, -1, 32, 33, flags);
    gemm<false, true, true, false, 0, false>(stream, t2, 256, P(34), 256, 0, P(35), 0, feats + (size_t)4 * N * E_, 256, N, 256, 256, 1.f, -1, 34, 35, flags);
  };
  fe(P(0), 0, NS_, feats_s);
  fe(P(2), 2, NQ_, feats_q);

  agent_state_k<<<A_, 256, 0, stream>>>(feats_s, P(46), state, flags);
  messages_k<<<A_, 256, 0, stream>>>(state, P(36), P(37), msg, flags);
  comm_k<<<A_, 256, 0, stream>>>(msg, P(57), P(38), P(39), P(40), P(41), P(46),
                                 P(42), P(43), P(44), P(45), ck, flags);

  const float qscale = 0.088388347648318447f;  // 1/sqrt(128)
  for (int a = 0; a < A_; ++a) {
    addck_k<<<(NS_ * E_) / 256, 256, 0, stream>>>(feats_s + (size_t)a * NS_ * E_, ck + a * E_, attb);
    gemm<false, true, true, true, 0, false>(stream, attb, 256, P(47), 256, (size_t)a * 3 * E_ * E_,
                                            P(48), (size_t)a * 3 * E_, qkv_s, 768, NS_, 768, 256, 1.f, -1, 47, 48, flags);
    for (int h = 0; h < 2; ++h)
      gemm<false, false, false, true, 0, false>(stream, qkv_s + h * 128, 768, qkv_s + 256 + h * 128, 768, 0,
                                                nullptr, 0, U1 + (size_t)h * NS_ * NS_, NS_,
                                                NS_, NS_, 128, qscale, -1, -1, -1, flags);
    softmax_mask_k<<<dim3(NS_, 2), 256, 0, stream>>>(U1, support_y);
    for (int h = 0; h < 2; ++h)
      gemm<false, false, false, false, 0, false>(stream, U1 + (size_t)h * NS_ * NS_, NS_,
                                                 qkv_s + 512 + h * 128, 768, 0, nullptr, 0,
                                                 attb + h * 128, 256, NS_, 128, NS_, 1.f, -1, -1, -1, flags);
    gemm<false, true, true, true, 0, false>(stream, attb, 256, P(49), 256, (size_t)a * E_ * E_,
                                            P(50), (size_t)a * E_, att_out, 256, NS_, 256, 256, 1.f, -1, 49, 50, flags);
    protos_k<<<NWAY_, 256, 0, stream>>>(att_out, support_y, protos);
    bias2_k<<<1, 256, 0, stream>>>(ck + a * E_, P(51), P(52), a, bias2, flags);
    float* clsC = U1;
    float* clsC2 = U1 + (size_t)NQ_ * E_;
    gemm<false, true, false, false, 1, false>(stream, feats_q + (size_t)a * NQ_ * E_, 256,
                                              P(51), 256, (size_t)a * 2 * E_ * E_, bias2, 0, clsC, 256,
                                              NQ_, 256, 256, 1.f, -1, 51, -1, flags);
    gemm<false, true, true, false, 1, false>(stream, clsC, 256, P(53), 128, (size_t)a * E_ * 128,
                                             P(54), (size_t)a * 128, clsC2, 128, NQ_, 128, 256, 1.f, -1, 53, 54, flags);
    logits_k<<<NQ_, 64, 0, stream>>>(feats_q + (size_t)a * NQ_ * E_, protos, clsC2,
                                     P(55), P(56), a, out + (size_t)a * NQ_ * NWAY_, flags);
  }

  float* fh1 = U1;
  float* fh2 = U1 + (size_t)NQ_ * E_;
  gemm<false, true, true, false, 0, false>(stream, feats_q, 256, P(58), 256, 0, P(59), 0, fh1, 256, NQ_, 256, 256, 1.f, -1, 58, 59, flags);
  for (int a = 1; a < 4; ++a)
    gemm<false, true, false, false, 0, true>(stream, feats_q + (size_t)a * NQ_ * E_, 256,
                                             P(58), 256, (size_t)a * E_ * 256, nullptr, 0,
                                             fh1, 256, NQ_, 256, 256, 1.f, -1, 58, -1, flags);
  gemm<false, true, false, false, 1, true>(stream, feats_q + (size_t)4 * NQ_ * E_, 256,
                                           P(58), 256, (size_t)4 * E_ * 256, nullptr, 0,
                                           fh1, 256, NQ_, 256, 256, 1.f, -1, 58, -1, flags);
  gemm<false, true, true, false, 1, false>(stream, fh1, 256, P(60), 128, 0, P(61), 0, fh2, 128, NQ_, 128, 256, 1.f, -1, 60, 61, flags);
  fused_k<<<NQ_, 64, 0, stream>>>(fh2, P(62), P(63), out + (size_t)A_ * NQ_ * NWAY_, flags);
}

// Round 5
// 3484.700 us; speedup vs baseline: 1.9854x; 1.9854x over previous
//
#include <hip/hip_runtime.h>
#include <hip/hip_bf16.h>

typedef __hip_bfloat16 bf16;

#define A_  5
#define D_  512
#define E_  256
#define NS_ 2048
#define NQ_ 8192
#define NWAY_ 5
#define QSCALE 0.088388347648318447f

// ---- per-tensor dtype dispatch: flags[i]=1 -> input i is f32, 0 -> bf16 ----
__device__ inline float ldw(const void* p, size_t i, int f32) {
  return f32 ? ((const float*)p)[i] : __bfloat162float(((const bf16*)p)[i]);
}
template<bool DYN>
__device__ inline float ldT(const void* p, size_t i, int f32) {
  if (DYN) return ldw(p, i, f32);
  return ((const float*)p)[i];
}

struct Ptrs { const void* p[64]; int sz[64]; };

__global__ void probe_k(Ptrs P, int* flags) {
  int b = blockIdx.x;
  if (threadIdx.x != 0) return;
  if (b == 1 || b == 3) { flags[b] = 0; return; }
  const bf16* t = (const bf16*)P.p[b];
  int n = P.sz[b];
  int K = (n >> 1) < 64 ? (n >> 1) : 64;
  int big = 0, cntE = 0, cntO = 0;
  for (int k = 0; k < K; ++k) {
    float e = __bfloat162float(t[2 * k]);
    float o = __bfloat162float(t[2 * k + 1]);
    if (!(fabsf(e) <= 1e3f)) big++;
    if (e != 0.f) cntE++;
    if (o != 0.f) cntO++;
  }
  flags[b] = (big > 0 || (cntE == 0 && cntO > 0)) ? 1 : 0;
}

// ---- class index lists ----
__global__ void classidx_k(const int* __restrict__ y, int* __restrict__ idx,
                           int* __restrict__ cnt, int* __restrict__ cstart) {
  int c = threadIdx.x;
  if (c < NWAY_) {
    int n = 0;
    for (int i = 0; i < NS_; ++i) if (y[i] == c) idx[c * NS_ + (n++)] = i;
    cnt[c] = n;
  }
  __syncthreads();
  if (c == 0) { int s = 0; for (int q = 0; q < NWAY_; ++q) { cstart[q] = s; s += cnt[q]; } }
}

// ---------------- generic tiled GEMM (batched via grid.z) ----------------
template<bool DYNA, bool DYNB, bool DYNBIAS, bool TRB, int ACT, bool ACCUM>
__global__ __launch_bounds__(256) void gemm_k(
    const void* __restrict__ A, int lda,
    const void* __restrict__ B, int ldb, size_t offB,
    const void* __restrict__ bias, size_t offBias,
    float* __restrict__ C, int ldc,
    int M, int N, int K, float alpha,
    int ia, int ib, int ibias, const int* __restrict__ flags,
    size_t sA, size_t sB, size_t sBias, size_t sC)
{
  const int fA = DYNA ? flags[ia] : 1;
  const int fB = DYNB ? flags[ib] : 1;
  const int fBi = DYNBIAS ? flags[ibias] : 1;
  const size_t zA = (size_t)blockIdx.z * sA;
  const size_t zB = offB + (size_t)blockIdx.z * sB;
  const size_t zBias = offBias + (size_t)blockIdx.z * sBias;
  float* Cz = C + (size_t)blockIdx.z * sC;
  __shared__ float As[16][68];
  __shared__ float Bs[16][68];
  int tid = threadIdx.x;
  int tx = tid & 15, ty = tid >> 4;
  int bm = blockIdx.y * 64, bn = blockIdx.x * 64;
  float acc[4][4] = {{0.f}};
  int am = tid >> 2;
  int ak = (tid & 3) * 4;
  for (int k0 = 0; k0 < K; k0 += 16) {
    {
      int gm = bm + am;
      size_t abase = zA + (size_t)gm * lda + k0 + ak;
      #pragma unroll
      for (int i = 0; i < 4; ++i) {
        float v = 0.f;
        if (gm < M && (k0 + ak + i) < K) v = ldT<DYNA>(A, abase + i, fA);
        As[ak + i][am] = v;
      }
    }
    if (!TRB) {
      int bk = tid >> 4;
      int bn0 = (tid & 15) * 4;
      size_t bbase = zB + (size_t)(k0 + bk) * ldb + bn + bn0;
      #pragma unroll
      for (int j = 0; j < 4; ++j) {
        float v = 0.f;
        if ((k0 + bk) < K && (bn + bn0 + j) < N) v = ldT<DYNB>(B, bbase + j, fB);
        Bs[bk][bn0 + j] = v;
      }
    } else {
      int bnn = tid >> 2;
      int bkq = (tid & 3) * 4;
      size_t bbase = zB + (size_t)(bn + bnn) * ldb + k0 + bkq;
      #pragma unroll
      for (int i = 0; i < 4; ++i) {
        float v = 0.f;
        if ((bn + bnn) < N && (k0 + bkq + i) < K) v = ldT<DYNB>(B, bbase + i, fB);
        Bs[bkq + i][bnn] = v;
      }
    }
    __syncthreads();
    #pragma unroll
    for (int k = 0; k < 16; ++k) {
      float4 av = *(const float4*)(&As[k][ty * 4]);
      float4 bv = *(const float4*)(&Bs[k][tx * 4]);
      float a0[4] = {av.x, av.y, av.z, av.w};
      float b0[4] = {bv.x, bv.y, bv.z, bv.w};
      #pragma unroll
      for (int i = 0; i < 4; ++i)
        #pragma unroll
        for (int j = 0; j < 4; ++j)
          acc[i][j] += a0[i] * b0[j];
    }
    __syncthreads();
  }
  #pragma unroll
  for (int i = 0; i < 4; ++i) {
    int r = bm + ty * 4 + i;
    if (r >= M) continue;
    #pragma unroll
    for (int j = 0; j < 4; ++j) {
      int c = bn + tx * 4 + j;
      if (c >= N) continue;
      float v = acc[i][j] * alpha;
      if (ACCUM) v += Cz[(size_t)r * ldc + c];
      if (bias) v += ldT<DYNBIAS>(bias, zBias + c, fBi);
      if (ACT == 1) v = fmaxf(v, 0.f);
      else if (ACT == 2) v = tanhf(v);
      else if (ACT == 3) v = 1.f / (1.f + expf(-v));
      Cz[(size_t)r * ldc + c] = v;
    }
  }
}

template<bool DYNA, bool DYNB, bool DYNBIAS, bool TRB, int ACT, bool ACCUM>
static void gemm(hipStream_t s, const void* A, int lda, const void* B, int ldb, size_t offB,
                 const void* bias, size_t offBias, float* C, int ldc, int M, int N, int K,
                 float alpha, int ia, int ib, int ibias, const int* flags,
                 int batch = 1, size_t sA = 0, size_t sB = 0, size_t sBias = 0, size_t sC = 0) {
  dim3 g((N + 63) / 64, (M + 63) / 64, batch), b(256);
  gemm_k<DYNA, DYNB, DYNBIAS, TRB, ACT, ACCUM><<<g, b, 0, s>>>(
      A, lda, B, ldb, offB, bias, offBias, C, ldc, M, N, K, alpha, ia, ib, ibias, flags,
      sA, sB, sBias, sC);
}

// ---------------- LayerNorm (+relu/sigmoid) ----------------
template<int ACT>
__global__ __launch_bounds__(256) void ln_k(const float* __restrict__ X, const void* __restrict__ g,
                                            const void* __restrict__ be, float* __restrict__ Y, int W,
                                            int ig, int ibe, const int* __restrict__ flags) {
  const int fG = flags[ig], fBe = flags[ibe];
  int row = blockIdx.x;
  const float* x = X + (size_t)row * W;
  float* y = Y + (size_t)row * W;
  __shared__ float red[256];
  int tid = threadIdx.x;
  float s1 = 0.f, s2 = 0.f;
  for (int i = tid; i < W; i += 256) { float v = x[i]; s1 += v; s2 += v * v; }
  red[tid] = s1; __syncthreads();
  for (int o = 128; o > 0; o >>= 1) { if (tid < o) red[tid] += red[tid + o]; __syncthreads(); }
  float mean = red[0] / W; __syncthreads();
  red[tid] = s2; __syncthreads();
  for (int o = 128; o > 0; o >>= 1) { if (tid < o) red[tid] += red[tid + o]; __syncthreads(); }
  float var = fmaxf(red[0] / W - mean * mean, 0.f);
  float rstd = rsqrtf(var + 1e-5f);
  for (int i = tid; i < W; i += 256) {
    float v = (x[i] - mean) * rstd * ldw(g, i, fG) + ldw(be, i, fBe);
    if (ACT == 1) v = fmaxf(v, 0.f);
    else if (ACT == 3) v = 1.f / (1.f + expf(-v));
    y[i] = v;
  }
}

// ---------------- comm round ----------------
__global__ void agent_state_k(const float* __restrict__ feats_s, const void* __restrict__ internal,
                              float* __restrict__ state, const int* __restrict__ flags) {
  const int fI = flags[46];
  int a = blockIdx.x, e = threadIdx.x;
  const float* p = feats_s + (size_t)a * NS_ * E_ + e;
  float s = 0.f;
  for (int n = 0; n < NS_; ++n) s += p[(size_t)n * E_];
  state[a * E_ + e] = s * (1.f / NS_) + ldw(internal, (size_t)a * E_ + e, fI);
}

__global__ void messages_k(const float* __restrict__ state, const void* __restrict__ W,
                           const void* __restrict__ b, float* __restrict__ msg,
                           const int* __restrict__ flags) {
  const int fW = flags[36], fB = flags[37];
  int a = blockIdx.x, f = threadIdx.x;
  __shared__ float st[E_];
  st[f] = state[a * E_ + f]; __syncthreads();
  size_t wbase = (size_t)a * E_ * E_ + f;
  float s = 0.f;
  for (int e = 0; e < E_; ++e) s += st[e] * ldw(W, wbase + (size_t)e * E_, fW);
  msg[a * E_ + f] = tanhf(s + ldw(b, (size_t)a * E_ + f, fB));
}

__global__ __launch_bounds__(256) void comm_k(
    const float* __restrict__ msg, const void* __restrict__ comm_w,
    const void* __restrict__ in_w, const void* __restrict__ in_b,
    const void* __restrict__ out_w, const void* __restrict__ out_b,
    const void* __restrict__ internal,
    const void* __restrict__ pw1, const void* __restrict__ pb1,
    const void* __restrict__ pw2, const void* __restrict__ pb2,
    float* __restrict__ ck, const int* __restrict__ flags)
{
  const int fCW = flags[57], fIW = flags[38], fIB = flags[39], fOW = flags[40], fOB = flags[41];
  const int fIN = flags[46], fP1 = flags[42], fQ1 = flags[43], fP2 = flags[44], fQ2 = flags[45];
  int a = blockIdx.x, tid = threadIdx.x;
  __shared__ float m[4][E_];
  __shared__ float qkv[4][3 * E_];
  __shared__ float attw[4][4][4];
  __shared__ float obar[E_];
  __shared__ float comb[E_];
  __shared__ float hh[E_];
  float w[5]; float mx = -1e30f;
  for (int j = 0; j < 5; ++j) { w[j] = ldw(comm_w, a * 5 + j, fCW); mx = fmaxf(mx, w[j]); }
  float sum = 0.f;
  for (int j = 0; j < 5; ++j) { w[j] = expf(w[j] - mx); sum += w[j]; }
  for (int j = 0; j < 5; ++j) w[j] /= sum;
  int others[4]; { int c = 0; for (int j = 0; j < 5; ++j) if (j != a) others[c++] = j; }
  for (int t = 0; t < 4; ++t) m[t][tid] = msg[others[t] * E_ + tid] * w[others[t]];
  __syncthreads();
  for (int f = tid; f < 3 * E_; f += 256) {
    size_t wr = (size_t)a * 3 * E_ * E_ + (size_t)f * E_;
    float a0 = 0.f, a1 = 0.f, a2 = 0.f, a3 = 0.f;
    for (int e = 0; e < E_; ++e) {
      float ww = ldw(in_w, wr + e, fIW);
      a0 += m[0][e] * ww; a1 += m[1][e] * ww; a2 += m[2][e] * ww; a3 += m[3][e] * ww;
    }
    float bb = ldw(in_b, (size_t)a * 3 * E_ + f, fIB);
    qkv[0][f] = a0 + bb; qkv[1][f] = a1 + bb; qkv[2][f] = a2 + bb; qkv[3][f] = a3 + bb;
  }
  __syncthreads();
  if (tid < 16) {
    int h = tid >> 2, t = tid & 3;
    float sc[4]; float mx2 = -1e30f;
    for (int t2 = 0; t2 < 4; ++t2) {
      float s = 0.f;
      for (int d = 0; d < 64; ++d) s += qkv[t][h * 64 + d] * qkv[t2][E_ + h * 64 + d];
      sc[t2] = s * 0.125f; mx2 = fmaxf(mx2, sc[t2]);
    }
    float ss = 0.f;
    for (int t2 = 0; t2 < 4; ++t2) { sc[t2] = expf(sc[t2] - mx2); ss += sc[t2]; }
    for (int t2 = 0; t2 < 4; ++t2) attw[h][t][t2] = sc[t2] / ss;
  }
  __syncthreads();
  {
    int e = tid, h = e >> 6;
    float s = 0.f;
    for (int t = 0; t < 4; ++t)
      for (int t2 = 0; t2 < 4; ++t2)
        s += attw[h][t][t2] * qkv[t2][2 * E_ + e];
    obar[e] = s * 0.25f;
  }
  __syncthreads();
  {
    int f = tid;
    size_t wr = (size_t)a * E_ * E_ + (size_t)f * E_;
    float s = 0.f;
    for (int e = 0; e < E_; ++e) s += obar[e] * ldw(out_w, wr + e, fOW);
    comb[f] = ldw(internal, (size_t)a * E_ + f, fIN) + s + ldw(out_b, (size_t)a * E_ + f, fOB);
  }
  __syncthreads();
  {
    int f = tid; float s = 0.f;
    size_t wr = (size_t)a * E_ * E_ + f;
    for (int e = 0; e < E_; ++e) s += comb[e] * ldw(pw1, wr + (size_t)e * E_, fP1);
    hh[f] = fmaxf(s + ldw(pb1, (size_t)a * E_ + f, fQ1), 0.f);
  }
  __syncthreads();
  {
    int f = tid; float s = 0.f;
    size_t wr = (size_t)a * E_ * E_ + f;
    for (int e = 0; e < E_; ++e) s += hh[e] * ldw(pw2, wr + (size_t)e * E_, fP2);
    ck[a * E_ + f] = s + ldw(pb2, (size_t)a * E_ + f, fQ2);
  }
}

// ---- xs_all[a][i][:] = feats_s[a][i][:] + ck[a][:]  (batched over agents) ----
__global__ void addck_k(const float* __restrict__ fs, const float* __restrict__ ck,
                        float* __restrict__ xs) {
  size_t i = (size_t)blockIdx.x * 256 + threadIdx.x;   // NS_*E_ = 2^19
  int a = (int)(i >> 19);
  xs[i] = fs[i] + ck[a * E_ + (i & (E_ - 1))];
}

// ---- class-block attention, stage A: per-row softmax stats (m,l) ----
__global__ __launch_bounds__(256) void attn_stats_k(
    const float* __restrict__ qkv_all, const int* __restrict__ idx,
    const int* __restrict__ cnt, const int* __restrict__ cstart,
    float* __restrict__ ml)
{
  int c = blockIdx.x; int z = blockIdx.z; int a = z >> 1, h = z & 1;
  int n = cnt[c];
  int r0 = blockIdx.y * 64;
  if (r0 >= n) return;
  const float* qkv = qkv_all + (size_t)a * NS_ * 768;
  const int* myidx = idx + c * NS_;
  int tid = threadIdx.x;
  int tx = tid & 15, ty = tid >> 4;
  __shared__ float Qs[16][68], Ks[16][68];
  float m4[4], l4[4];
  #pragma unroll
  for (int i = 0; i < 4; ++i) { m4[i] = -3e38f; l4[i] = 0.f; }
  int lrow = tid >> 2, lk = (tid & 3) * 4;
  for (int j0 = 0; j0 < n; j0 += 64) {
    float acc[4][4] = {{0.f}};
    for (int d0 = 0; d0 < 128; d0 += 16) {
      {
        int rr = r0 + lrow;
        float4 v = make_float4(0.f, 0.f, 0.f, 0.f);
        if (rr < n) {
          const float* s = qkv + (size_t)myidx[rr] * 768 + h * 128 + d0 + lk;
          v = make_float4(s[0], s[1], s[2], s[3]);
        }
        Qs[lk][lrow] = v.x; Qs[lk + 1][lrow] = v.y; Qs[lk + 2][lrow] = v.z; Qs[lk + 3][lrow] = v.w;
      }
      {
        int jj = j0 + lrow;
        float4 v = make_float4(0.f, 0.f, 0.f, 0.f);
        if (jj < n) {
          const float* s = qkv + (size_t)myidx[jj] * 768 + 256 + h * 128 + d0 + lk;
          v = make_float4(s[0], s[1], s[2], s[3]);
        }
        Ks[lk][lrow] = v.x; Ks[lk + 1][lrow] = v.y; Ks[lk + 2][lrow] = v.z; Ks[lk + 3][lrow] = v.w;
      }
      __syncthreads();
      #pragma unroll
      for (int k = 0; k < 16; ++k) {
        float4 av = *(const float4*)(&Qs[k][ty * 4]);
        float4 bv = *(const float4*)(&Ks[k][tx * 4]);
        float aa[4] = {av.x, av.y, av.z, av.w};
        float bb[4] = {bv.x, bv.y, bv.z, bv.w};
        #pragma unroll
        for (int i = 0; i < 4; ++i)
          #pragma unroll
          for (int j = 0; j < 4; ++j)
            acc[i][j] += aa[i] * bb[j];
      }
      __syncthreads();
    }
    #pragma unroll
    for (int jj = 0; jj < 4; ++jj) {
      int j = j0 + tx * 4 + jj;
      if (j >= n) continue;
      #pragma unroll
      for (int i = 0; i < 4; ++i) {
        float s = acc[i][jj] * QSCALE;
        if (s > m4[i]) { l4[i] = l4[i] * __expf(m4[i] - s) + 1.f; m4[i] = s; }
        else l4[i] += __expf(s - m4[i]);
      }
    }
  }
  __shared__ float Ms[64][17], Ls[64][17];
  #pragma unroll
  for (int i = 0; i < 4; ++i) { Ms[ty * 4 + i][tx] = m4[i]; Ls[ty * 4 + i][tx] = l4[i]; }
  __syncthreads();
  if (tid < 64 && r0 + tid < n) {
    float m = -3e38f;
    for (int t = 0; t < 16; ++t) m = fmaxf(m, Ms[tid][t]);
    float l = 0.f;
    for (int t = 0; t < 16; ++t) l += Ls[tid][t] * __expf(Ms[tid][t] - m);
    size_t p = (size_t)z * NS_ + cstart[c] + r0 + tid;
    ml[p * 2] = m; ml[p * 2 + 1] = l;
  }
}

// ---- stage B: colsum_j = sum_i P_ij (normalized attention column sums) ----
__global__ __launch_bounds__(256) void attn_colsum_k(
    const float* __restrict__ qkv_all, const int* __restrict__ idx,
    const int* __restrict__ cnt, const int* __restrict__ cstart,
    const float* __restrict__ ml, float* __restrict__ colsum)
{
  int c = blockIdx.x; int z = blockIdx.z; int a = z >> 1, h = z & 1;
  int n = cnt[c];
  int j0 = blockIdx.y * 64;
  if (j0 >= n) return;
  const float* qkv = qkv_all + (size_t)a * NS_ * 768;
  const int* myidx = idx + c * NS_;
  int tid = threadIdx.x;
  int tx = tid & 15, ty = tid >> 4;
  __shared__ float Qs[16][68], Ks[16][68];
  float cs[4] = {0.f, 0.f, 0.f, 0.f};
  int lrow = tid >> 2, lk = (tid & 3) * 4;
  for (int i0 = 0; i0 < n; i0 += 64) {
    float acc[4][4] = {{0.f}};
    for (int d0 = 0; d0 < 128; d0 += 16) {
      {
        int rr = i0 + lrow;
        float4 v = make_float4(0.f, 0.f, 0.f, 0.f);
        if (rr < n) {
          const float* s = qkv + (size_t)myidx[rr] * 768 + h * 128 + d0 + lk;
          v = make_float4(s[0], s[1], s[2], s[3]);
        }
        Qs[lk][lrow] = v.x; Qs[lk + 1][lrow] = v.y; Qs[lk + 2][lrow] = v.z; Qs[lk + 3][lrow] = v.w;
      }
      {
        int jj = j0 + lrow;
        float4 v = make_float4(0.f, 0.f, 0.f, 0.f);
        if (jj < n) {
          const float* s = qkv + (size_t)myidx[jj] * 768 + 256 + h * 128 + d0 + lk;
          v = make_float4(s[0], s[1], s[2], s[3]);
        }
        Ks[lk][lrow] = v.x; Ks[lk + 1][lrow] = v.y; Ks[lk + 2][lrow] = v.z; Ks[lk + 3][lrow] = v.w;
      }
      __syncthreads();
      #pragma unroll
      for (int k = 0; k < 16; ++k) {
        float4 av = *(const float4*)(&Qs[k][ty * 4]);
        float4 bv = *(const float4*)(&Ks[k][tx * 4]);
        float aa[4] = {av.x, av.y, av.z, av.w};
        float bb[4] = {bv.x, bv.y, bv.z, bv.w};
        #pragma unroll
        for (int i = 0; i < 4; ++i)
          #pragma unroll
          for (int j = 0; j < 4; ++j)
            acc[i][j] += aa[i] * bb[j];
      }
      __syncthreads();
    }
    #pragma unroll
    for (int i = 0; i < 4; ++i) {
      int gi = i0 + ty * 4 + i;
      if (gi >= n) continue;
      size_t p = (size_t)z * NS_ + cstart[c] + gi;
      float m = ml[p * 2];
      float invl = 1.f / ml[p * 2 + 1];
      #pragma unroll
      for (int jj = 0; jj < 4; ++jj) {
        int j = j0 + tx * 4 + jj;
        if (j >= n) continue;
        cs[jj] += __expf(acc[i][jj] * QSCALE - m) * invl;
      }
    }
  }
  __shared__ float Cs[64][17];
  #pragma unroll
  for (int jj = 0; jj < 4; ++jj) Cs[tx * 4 + jj][ty] = cs[jj];
  __syncthreads();
  if (tid < 64 && j0 + tid < n) {
    float s = 0.f;
    for (int t = 0; t < 16; ++t) s += Cs[tid][t];
    colsum[(size_t)z * NS_ + cstart[c] + j0 + tid] = s;
  }
}

// ---- proto_pre[a][c][e] = (1/n_c) * sum_k colsum[k] * V[idx_k][e] ----
__global__ void proto_combine_k(const float* __restrict__ qkv_all, const int* __restrict__ idx,
                                const int* __restrict__ cnt, const int* __restrict__ cstart,
                                const float* __restrict__ colsum, float* __restrict__ proto_pre) {
  int c = blockIdx.x, a = blockIdx.y;
  int e = threadIdx.x, h = e >> 7, d = e & 127;
  int n = cnt[c];
  const float* qkv = qkv_all + (size_t)a * NS_ * 768;
  const float* csum = colsum + (size_t)(a * 2 + h) * NS_ + cstart[c];
  const int* myidx = idx + c * NS_;
  float s = 0.f;
  for (int k = 0; k < n; ++k)
    s += csum[k] * qkv[(size_t)myidx[k] * 768 + 512 + h * 128 + d];
  proto_pre[((size_t)a * NWAY_ + c) * E_ + e] = (n > 0) ? s / (float)n : 0.f;
}

// ---- protos[a][c][:] = proto_pre @ out_w.T + out_b  (0 if class empty) ----
__global__ void proto_outproj_k(const float* __restrict__ proto_pre, const void* __restrict__ ow,
                                const void* __restrict__ ob, const int* __restrict__ cnt,
                                float* __restrict__ protos_all, const int* __restrict__ flags) {
  int c = blockIdx.x, a = blockIdx.y, e = threadIdx.x;
  const int fW = flags[49], fB = flags[50];
  __shared__ float pp[E_];
  pp[e] = proto_pre[((size_t)a * NWAY_ + c) * E_ + e];
  __syncthreads();
  size_t wb = (size_t)a * E_ * E_ + (size_t)e * E_;
  float s = 0.f;
  for (int k = 0; k < E_; ++k) s += pp[k] * ldw(ow, wb + k, fW);
  float v = s + ldw(ob, (size_t)a * E_ + e, fB);
  protos_all[((size_t)a * NWAY_ + c) * E_ + e] = (cnt[c] > 0) ? v : 0.f;
}

// ---- bias2_all[a] = ck[a] @ w1[rows 256:512] + b1 (batched over agents) ----
__global__ void bias2_k(const float* __restrict__ ck, const void* __restrict__ w1,
                        const void* __restrict__ b1, float* __restrict__ bias2_all,
                        const int* __restrict__ flags) {
  const int fW = flags[51], fB = flags[52];
  int a = blockIdx.x, n = threadIdx.x;
  __shared__ float c[E_];
  c[n] = ck[a * E_ + n]; __syncthreads();
  size_t wbase = (size_t)a * 2 * E_ * E_ + (size_t)E_ * E_ + n;
  float s = 0.f;
  for (int k = 0; k < E_; ++k) s += c[k] * ldw(w1, wbase + (size_t)k * E_, fW);
  bias2_all[a * E_ + n] = s + ldw(b1, (size_t)a * E_ + n, fB);
}

// ---------------- epilogues (wave per query row) — f32 output ----------------
__device__ inline float wave_sum(float v) {
  for (int o = 32; o > 0; o >>= 1) v += __shfl_down(v, o);
  return v;
}

__global__ __launch_bounds__(64) void logits_k(const float* __restrict__ fq, const float* __restrict__ protos,
                                               const float* __restrict__ c2, const void* __restrict__ w3,
                                               const void* __restrict__ b3, int a, float* __restrict__ out,
                                               const int* __restrict__ flags) {
  const int fW = flags[55], fB = flags[56];
  int i = blockIdx.x, lane = threadIdx.x;
  float4 xv = ((const float4*)(fq + (size_t)i * E_))[lane];
  float qq = wave_sum(xv.x * xv.x + xv.y * xv.y + xv.z * xv.z + xv.w * xv.w);
  float cpart = c2[(size_t)i * 128 + lane * 2] * ldw(w3, (size_t)a * 128 + lane * 2, fW) +
                c2[(size_t)i * 128 + lane * 2 + 1] * ldw(w3, (size_t)a * 128 + lane * 2 + 1, fW);
  float conf = wave_sum(cpart);
  if (lane == 0) conf += ldw(b3, a, fB);
  for (int c = 0; c < NWAY_; ++c) {
    float4 pv = ((const float4*)(protos + c * E_))[lane];
    float dt = wave_sum(xv.x * pv.x + xv.y * pv.y + xv.z * pv.z + xv.w * pv.w);
    float pp = wave_sum(pv.x * pv.x + pv.y * pv.y + pv.z * pv.z + pv.w * pv.w);
    if (lane == 0) {
      float d2 = fmaxf(qq + pp - 2.f * dt, 1e-12f);
      out[(size_t)i * NWAY_ + c] = -sqrtf(d2) + 0.1f * conf;
    }
  }
}

__global__ __launch_bounds__(64) void fused_k(const float* __restrict__ h2, const void* __restrict__ w3,
                                              const void* __restrict__ b3, float* __restrict__ out,
                                              const int* __restrict__ flags) {
  const int fW = flags[62], fB = flags[63];
  int i = blockIdx.x, lane = threadIdx.x;
  float s = h2[(size_t)i * 128 + lane * 2] * ldw(w3, lane * 2, fW) +
            h2[(size_t)i * 128 + lane * 2 + 1] * ldw(w3, lane * 2 + 1, fW);
  s = wave_sum(s);
  if (lane == 0) out[i] = s + ldw(b3, 0, fB);
}

// ---------------- host ----------------
extern "C" void kernel_launch(void* const* d_in, const int* in_sizes, int n_in,
                              void* d_out, int out_size, void* d_ws, size_t ws_size,
                              hipStream_t stream) {
  (void)out_size; (void)ws_size;
  #define P(i) ((const void*)d_in[i])
  const int* support_y = (const int*)d_in[1];
  float* out = (float*)d_out;

  int* flags = (int*)d_ws;                               // 64 ints
  float* W = (float*)((char*)d_ws + 256);
  float* feats_s = W;                                    // A*NS*E      (2.62M)
  float* feats_q = feats_s + (size_t)A_ * NS_ * E_;      // A*NQ*E      (10.49M)
  float* R12     = feats_q + (size_t)A_ * NQ_ * E_;      // 10.49M shared region
  const size_t R12_SZ = (size_t)A_ * NS_ * E_ + (size_t)A_ * NS_ * 768;
  // FE phase:       t1 = R12 (NQ*768), t2 = R12 + NQ*768 (NQ*256)
  // attention:      xs_all = R12 (A*NS*E), qkv_all = R12 + A*NS*E (A*NS*768)
  // cls/fusion:     clsC/fh1 = R12 (NQ*256), clsC2/fh2 = R12 + NQ*256 (NQ*128)
  float* t1 = R12;
  float* t2 = R12 + (size_t)NQ_ * 3 * E_;
  float* xs_all  = R12;
  float* qkv_all = R12 + (size_t)A_ * NS_ * E_;

  float* smalls = R12 + R12_SZ;
  float* state      = smalls;                 // A*E
  float* msg        = state + A_ * E_;        // A*E
  float* ck         = msg + A_ * E_;          // A*E
  float* protos_all = ck + A_ * E_;           // A*NWAY*E
  float* bias2_all  = protos_all + A_ * NWAY_ * E_;   // A*E
  float* ml         = bias2_all + A_ * E_;    // A*2*NS*2
  float* colsum     = ml + (size_t)A_ * 2 * NS_ * 2;  // A*2*NS
  float* proto_pre  = colsum + (size_t)A_ * 2 * NS_;  // A*NWAY*E
  int*   idx        = (int*)(proto_pre + A_ * NWAY_ * E_);  // NWAY*NS
  int*   cnt        = idx + NWAY_ * NS_;      // NWAY
  int*   cstart     = cnt + NWAY_;            // NWAY

  Ptrs ps;
  for (int i = 0; i < 64; ++i) {
    ps.p[i] = (i < n_in) ? d_in[i] : nullptr;
    ps.sz[i] = (i < n_in) ? in_sizes[i] : 0;
  }
  probe_k<<<64, 64, 0, stream>>>(ps, flags);
  classidx_k<<<1, 64, 0, stream>>>(support_y, idx, cnt, cstart);

  auto fe = [&](const void* x, int xi, int N, float* feats) {
    gemm<true, true, true, false, 0, false>(stream, x, 512, P(4), 512, 0, P(5), 0, t1, 512, N, 512, 512, 1.f, xi, 4, 5, flags);
    ln_k<1><<<N, 256, 0, stream>>>(t1, P(6), P(7), t1, 512, 6, 7, flags);
    gemm<false, true, true, false, 0, false>(stream, t1, 512, P(8), 256, 0, P(9), 0, t2, 256, N, 256, 512, 1.f, -1, 8, 9, flags);
    ln_k<1><<<N, 256, 0, stream>>>(t2, P(10), P(11), feats, 256, 10, 11, flags);
    gemm<true, true, true, false, 0, false>(stream, x, 512, P(12), 256, 0, P(13), 0, t2, 256, N, 256, 512, 1.f, xi, 12, 13, flags);
    ln_k<1><<<N, 256, 0, stream>>>(t2, P(14), P(15), t2, 256, 14, 15, flags);
    gemm<false, true, true, false, 2, false>(stream, t2, 256, P(16), 256, 0, P(17), 0, feats + (size_t)N * E_, 256, N, 256, 256, 1.f, -1, 16, 17, flags);
    gemm<true, true, true, false, 1, false>(stream, x, 512, P(18), 768, 0, P(19), 0, t1, 768, N, 768, 512, 1.f, xi, 18, 19, flags);
    gemm<false, true, true, false, 0, false>(stream, t1, 768, P(20), 256, 0, P(21), 0, t2, 256, N, 256, 768, 1.f, -1, 20, 21, flags);
    ln_k<1><<<N, 256, 0, stream>>>(t2, P(22), P(23), feats + (size_t)2 * N * E_, 256, 22, 23, flags);
    gemm<true, true, true, false, 1, false>(stream, x, 512, P(24), 256, 0, P(25), 0, t2, 256, N, 256, 512, 1.f, xi, 24, 25, flags);
    gemm<false, true, true, false, 0, false>(stream, t2, 256, P(26), 256, 0, P(27), 0, t1, 256, N, 256, 256, 1.f, -1, 26, 27, flags);
    ln_k<3><<<N, 256, 0, stream>>>(t1, P(28), P(29), feats + (size_t)3 * N * E_, 256, 28, 29, flags);
    gemm<true, true, true, false, 1, false>(stream, x, 512, P(30), 512, 0, P(31), 0, t1, 512, N, 512, 512, 1.f, xi, 30, 31, flags);
    gemm<false, true, true, false, 1, false>(stream, t1, 512, P(32), 256, 0, P(33), 0, t2, 256, N, 256, 512, 1.f, -1, 32, 33, flags);
    gemm<false, true, true, false, 0, false>(stream, t2, 256, P(34), 256, 0, P(35), 0, feats + (size_t)4 * N * E_, 256, N, 256, 256, 1.f, -1, 34, 35, flags);
  };
  fe(P(0), 0, NS_, feats_s);
  fe(P(2), 2, NQ_, feats_q);

  agent_state_k<<<A_, 256, 0, stream>>>(feats_s, P(46), state, flags);
  messages_k<<<A_, 256, 0, stream>>>(state, P(36), P(37), msg, flags);
  comm_k<<<A_, 256, 0, stream>>>(msg, P(57), P(38), P(39), P(40), P(41), P(46),
                                 P(42), P(43), P(44), P(45), ck, flags);

  // ---- batched prototype attention ----
  addck_k<<<(A_ * NS_ * E_) / 256, 256, 0, stream>>>(feats_s, ck, xs_all);
  gemm<false, true, true, true, 0, false>(stream, xs_all, 256, P(47), 256, 0, P(48), 0,
                                          qkv_all, 768, NS_, 768, 256, 1.f, -1, 47, 48, flags,
                                          A_, (size_t)NS_ * E_, (size_t)3 * E_ * E_, (size_t)3 * E_,
                                          (size_t)NS_ * 768);
  {
    dim3 g(NWAY_, NS_ / 64, A_ * 2);
    attn_stats_k<<<g, 256, 0, stream>>>(qkv_all, idx, cnt, cstart, ml);
    attn_colsum_k<<<g, 256, 0, stream>>>(qkv_all, idx, cnt, cstart, ml, colsum);
  }
  proto_combine_k<<<dim3(NWAY_, A_), 256, 0, stream>>>(qkv_all, idx, cnt, cstart, colsum, proto_pre);
  proto_outproj_k<<<dim3(NWAY_, A_), 256, 0, stream>>>(proto_pre, P(49), P(50), cnt, protos_all, flags);
  bias2_k<<<A_, 256, 0, stream>>>(ck, P(51), P(52), bias2_all, flags);

  // ---- per-agent classifier chain + logits ----
  float* clsC = R12;
  float* clsC2 = R12 + (size_t)NQ_ * E_;
  for (int a = 0; a < A_; ++a) {
    gemm<false, true, false, false, 1, false>(stream, feats_q + (size_t)a * NQ_ * E_, 256,
                                              P(51), 256, (size_t)a * 2 * E_ * E_, bias2_all + a * E_, 0,
                                              clsC, 256, NQ_, 256, 256, 1.f, -1, 51, -1, flags);
    gemm<false, true, true, false, 1, false>(stream, clsC, 256, P(53), 128, (size_t)a * E_ * 128,
                                             P(54), (size_t)a * 128, clsC2, 128, NQ_, 128, 256, 1.f, -1, 53, 54, flags);
    logits_k<<<NQ_, 64, 0, stream>>>(feats_q + (size_t)a * NQ_ * E_, protos_all + (size_t)a * NWAY_ * E_,
                                     clsC2, P(55), P(56), a, out + (size_t)a * NQ_ * NWAY_, flags);
  }

  // ---- fusion ----
  float* fh1 = R12;
  float* fh2 = R12 + (size_t)NQ_ * E_;
  gemm<false, true, true, false, 0, false>(stream, feats_q, 256, P(58), 256, 0, P(59), 0, fh1, 256, NQ_, 256, 256, 1.f, -1, 58, 59, flags);
  for (int a = 1; a < 4; ++a)
    gemm<false, true, false, false, 0, true>(stream, feats_q + (size_t)a * NQ_ * E_, 256,
                                             P(58), 256, (size_t)a * E_ * 256, nullptr, 0,
                                             fh1, 256, NQ_, 256, 256, 1.f, -1, 58, -1, flags);
  gemm<false, true, false, false, 1, true>(stream, feats_q + (size_t)4 * NQ_ * E_, 256,
                                           P(58), 256, (size_t)4 * E_ * 256, nullptr, 0,
                                           fh1, 256, NQ_, 256, 256, 1.f, -1, 58, -1, flags);
  gemm<false, true, true, false, 1, false>(stream, fh1, 256, P(60), 128, 0, P(61), 0, fh2, 128, NQ_, 128, 256, 1.f, -1, 60, 61, flags);
  fused_k<<<NQ_, 64, 0, stream>>>(fh2, P(62), P(63), out + (size_t)A_ * NQ_ * NWAY_, flags);
}

// Round 6
// 2172.974 us; speedup vs baseline: 3.1838x; 1.6037x over previous
//
#include <hip/hip_runtime.h>
#include <hip/hip_bf16.h>

typedef __hip_bfloat16 bf16;
typedef short s8v __attribute__((ext_vector_type(8)));
typedef short s4v __attribute__((ext_vector_type(4)));
typedef float f4v __attribute__((ext_vector_type(4)));

#define A_  5
#define D_  512
#define E_  256
#define NS_ 2048
#define NQ_ 8192
#define NWAY_ 5
#define QSCALE 0.088388347648318447f

// ---- per-tensor dtype dispatch: flags[i]=1 -> input i is f32, 0 -> bf16 ----
__device__ inline float ldw(const void* p, size_t i, int f32) {
  return f32 ? ((const float*)p)[i] : __bfloat162float(((const bf16*)p)[i]);
}
template<bool DYN>
__device__ inline float ldT(const void* p, size_t i, int f32) {
  if (DYN) return ldw(p, i, f32);
  return ((const float*)p)[i];
}

__device__ inline short f2bf(float v) {
  union { float f; unsigned u; } x; x.f = v;
  unsigned r = x.u + 0x7fffu + ((x.u >> 16) & 1u);
  return (short)(r >> 16);
}

struct Ptrs { const void* p[64]; int sz[64]; };

__global__ void probe_k(Ptrs P, int* flags) {
  int b = blockIdx.x;
  if (threadIdx.x != 0) return;
  if (b == 1 || b == 3) { flags[b] = 0; return; }
  const bf16* t = (const bf16*)P.p[b];
  int n = P.sz[b];
  int K = (n >> 1) < 64 ? (n >> 1) : 64;
  int big = 0, cntE = 0, cntO = 0;
  for (int k = 0; k < K; ++k) {
    float e = __bfloat162float(t[2 * k]);
    float o = __bfloat162float(t[2 * k + 1]);
    if (!(fabsf(e) <= 1e3f)) big++;
    if (e != 0.f) cntE++;
    if (o != 0.f) cntO++;
  }
  flags[b] = (big > 0 || (cntE == 0 && cntO > 0)) ? 1 : 0;
}

__global__ void classidx_k(const int* __restrict__ y, int* __restrict__ idx,
                           int* __restrict__ cnt, int* __restrict__ cstart) {
  int c = threadIdx.x;
  if (c < NWAY_) {
    int n = 0;
    for (int i = 0; i < NS_; ++i) if (y[i] == c) idx[c * NS_ + (n++)] = i;
    cnt[c] = n;
  }
  __syncthreads();
  if (c == 0) { int s = 0; for (int q = 0; q < NWAY_; ++q) { cstart[q] = s; s += cnt[q]; } }
}

// ============ MFMA bf16 GEMM: C[M,N] = act(alpha*A@B (+C) (+bias)) ============
// REQUIRES: M%128==0, N%128==0, K%32==0 (all call sites satisfy this).
// A f32 row-major [M,K]; B row-major [K,N] (TRB=false) or [N,K] (TRB=true).
// f32->bf16 convert during LDS staging; f32 accumulate via MFMA.
#define LSTR 40   // LDS row stride in bf16 units (80 B: 16B-aligned, 2-way bank alias only)
template<bool DYNA, bool DYNB, bool DYNBIAS, bool TRB, int ACT, bool ACCUM>
__global__ __launch_bounds__(256) void gemm_k(
    const void* __restrict__ A, int lda,
    const void* __restrict__ B, int ldb, size_t offB,
    const void* __restrict__ bias, size_t offBias,
    float* __restrict__ C, int ldc,
    int M, int N, int K, float alpha,
    int ia, int ib, int ibias, const int* __restrict__ flags,
    size_t sA, size_t sB, size_t sBias, size_t sC)
{
  const int fA = DYNA ? flags[ia] : 1;
  const int fB = DYNB ? flags[ib] : 1;
  const int fBi = DYNBIAS ? flags[ibias] : 1;
  const size_t zA = (size_t)blockIdx.z * sA;
  const size_t zB = offB + (size_t)blockIdx.z * sB;
  const size_t zBias = offBias + (size_t)blockIdx.z * sBias;
  float* Cz = C + (size_t)blockIdx.z * sC;
  __shared__ short As[128 * LSTR];
  __shared__ short Bs[128 * LSTR];
  const int tid = threadIdx.x;
  const int bm = blockIdx.y * 128, bn = blockIdx.x * 128;
  const int lane = tid & 63, wid = tid >> 6;
  const int lm = lane & 15, quad = lane >> 4;
  const int wy = (wid >> 1) * 64, wx = (wid & 1) * 64;
  f4v acc[4][4];
  #pragma unroll
  for (int i = 0; i < 4; ++i)
    #pragma unroll
    for (int j = 0; j < 4; ++j) acc[i][j] = (f4v)(0.f);

  const int am = tid >> 1, ah = (tid & 1) * 16;

  for (int k0 = 0; k0 < K; k0 += 32) {
    // ---- stage A tile [128 x 32] ----
    {
      size_t base = zA + (size_t)(bm + am) * lda + k0 + ah;
      short tmp[16];
      if (fA) {
        const float4* src = (const float4*)((const float*)A + base);
        #pragma unroll
        for (int q = 0; q < 4; ++q) {
          float4 v = src[q];
          tmp[q*4+0] = f2bf(v.x); tmp[q*4+1] = f2bf(v.y);
          tmp[q*4+2] = f2bf(v.z); tmp[q*4+3] = f2bf(v.w);
        }
      } else {
        #pragma unroll
        for (int q = 0; q < 16; ++q) tmp[q] = f2bf(ldw(A, base + q, 0));
      }
      s4v* dst = (s4v*)&As[am * LSTR + ah];
      #pragma unroll
      for (int q = 0; q < 4; ++q) dst[q] = *(s4v*)&tmp[q*4];
    }
    // ---- stage B tile, stored transposed as Bt[n][k] ----
    if (TRB) {
      int n = tid >> 1, h = (tid & 1) * 16;
      size_t base = zB + (size_t)(bn + n) * ldb + k0 + h;
      short tmp[16];
      if (fB) {
        const float4* src = (const float4*)((const float*)B + base);
        #pragma unroll
        for (int q = 0; q < 4; ++q) {
          float4 v = src[q];
          tmp[q*4+0] = f2bf(v.x); tmp[q*4+1] = f2bf(v.y);
          tmp[q*4+2] = f2bf(v.z); tmp[q*4+3] = f2bf(v.w);
        }
      } else {
        #pragma unroll
        for (int q = 0; q < 16; ++q) tmp[q] = f2bf(ldw(B, base + q, 0));
      }
      s4v* dst = (s4v*)&Bs[n * LSTR + h];
      #pragma unroll
      for (int q = 0; q < 4; ++q) dst[q] = *(s4v*)&tmp[q*4];
    } else {
      int n = tid & 127, kk = (tid >> 7) * 16;
      short tmp[16];
      #pragma unroll
      for (int j = 0; j < 16; ++j)
        tmp[j] = f2bf(ldT<DYNB>(B, zB + (size_t)(k0 + kk + j) * ldb + bn + n, fB));
      s4v* dst = (s4v*)&Bs[n * LSTR + kk];
      #pragma unroll
      for (int q = 0; q < 4; ++q) dst[q] = *(s4v*)&tmp[q*4];
    }
    __syncthreads();
    // ---- fragments + MFMA: each wave does 64x64 via 4x4 of 16x16x32 ----
    s8v af[4], bfr[4];
    #pragma unroll
    for (int mi = 0; mi < 4; ++mi)
      af[mi] = *(const s8v*)&As[(wy + mi*16 + lm) * LSTR + quad * 8];
    #pragma unroll
    for (int ni = 0; ni < 4; ++ni)
      bfr[ni] = *(const s8v*)&Bs[(wx + ni*16 + lm) * LSTR + quad * 8];
    #pragma unroll
    for (int mi = 0; mi < 4; ++mi)
      #pragma unroll
      for (int ni = 0; ni < 4; ++ni)
        acc[mi][ni] = __builtin_amdgcn_mfma_f32_16x16x32_bf16(af[mi], bfr[ni], acc[mi][ni], 0, 0, 0);
    __syncthreads();
  }
  // ---- epilogue: C/D layout col=lane&15, row=quad*4+reg ----
  #pragma unroll
  for (int mi = 0; mi < 4; ++mi) {
    #pragma unroll
    for (int r = 0; r < 4; ++r) {
      int row = bm + wy + mi*16 + quad*4 + r;
      #pragma unroll
      for (int ni = 0; ni < 4; ++ni) {
        int col = bn + wx + ni*16 + lm;
        float v = acc[mi][ni][r] * alpha;
        if (ACCUM) v += Cz[(size_t)row * ldc + col];
        if (bias) v += ldT<DYNBIAS>(bias, zBias + col, fBi);
        if (ACT == 1) v = fmaxf(v, 0.f);
        else if (ACT == 2) v = tanhf(v);
        else if (ACT == 3) v = 1.f / (1.f + expf(-v));
        Cz[(size_t)row * ldc + col] = v;
      }
    }
  }
}

template<bool DYNA, bool DYNB, bool DYNBIAS, bool TRB, int ACT, bool ACCUM>
static void gemm(hipStream_t s, const void* A, int lda, const void* B, int ldb, size_t offB,
                 const void* bias, size_t offBias, float* C, int ldc, int M, int N, int K,
                 float alpha, int ia, int ib, int ibias, const int* flags,
                 int batch = 1, size_t sA = 0, size_t sB = 0, size_t sBias = 0, size_t sC = 0) {
  dim3 g(N / 128, M / 128, batch), b(256);
  gemm_k<DYNA, DYNB, DYNBIAS, TRB, ACT, ACCUM><<<g, b, 0, s>>>(
      A, lda, B, ldb, offB, bias, offBias, C, ldc, M, N, K, alpha, ia, ib, ibias, flags,
      sA, sB, sBias, sC);
}

// ---------------- LayerNorm (+relu/sigmoid) ----------------
template<int ACT>
__global__ __launch_bounds__(256) void ln_k(const float* __restrict__ X, const void* __restrict__ g,
                                            const void* __restrict__ be, float* __restrict__ Y, int W,
                                            int ig, int ibe, const int* __restrict__ flags) {
  const int fG = flags[ig], fBe = flags[ibe];
  int row = blockIdx.x;
  const float* x = X + (size_t)row * W;
  float* y = Y + (size_t)row * W;
  __shared__ float red[256];
  int tid = threadIdx.x;
  float s1 = 0.f, s2 = 0.f;
  for (int i = tid; i < W; i += 256) { float v = x[i]; s1 += v; s2 += v * v; }
  red[tid] = s1; __syncthreads();
  for (int o = 128; o > 0; o >>= 1) { if (tid < o) red[tid] += red[tid + o]; __syncthreads(); }
  float mean = red[0] / W; __syncthreads();
  red[tid] = s2; __syncthreads();
  for (int o = 128; o > 0; o >>= 1) { if (tid < o) red[tid] += red[tid + o]; __syncthreads(); }
  float var = fmaxf(red[0] / W - mean * mean, 0.f);
  float rstd = rsqrtf(var + 1e-5f);
  for (int i = tid; i < W; i += 256) {
    float v = (x[i] - mean) * rstd * ldw(g, i, fG) + ldw(be, i, fBe);
    if (ACT == 1) v = fmaxf(v, 0.f);
    else if (ACT == 3) v = 1.f / (1.f + expf(-v));
    y[i] = v;
  }
}

// ================= comm round, parallelized =================
__global__ void statepart_k(const float* __restrict__ fs, float* __restrict__ part) {
  int a = blockIdx.x, g = blockIdx.y, e = threadIdx.x;
  const float* p = fs + ((size_t)a * NS_ + g * 128) * E_ + e;
  float s = 0.f;
  for (int n = 0; n < 128; ++n) s += p[(size_t)n * E_];
  part[((size_t)a * 16 + g) * E_ + e] = s;
}

__global__ void statecomb_k(const float* __restrict__ part, const void* __restrict__ internal,
                            float* __restrict__ state, const int* __restrict__ flags) {
  int a = blockIdx.x, e = threadIdx.x;
  float s = 0.f;
  for (int g = 0; g < 16; ++g) s += part[((size_t)a * 16 + g) * E_ + e];
  state[a * E_ + e] = s * (1.f / NS_) + ldw(internal, (size_t)a * E_ + e, flags[46]);
}

// partial[a][g][f] = sum_{e in chunk g} x[a][e] * W[a][e][f]   (W f-contiguous)
__global__ void mvpart_k(const float* __restrict__ x, const void* __restrict__ W, int iw,
                         float* __restrict__ part, const int* __restrict__ flags) {
  int a = blockIdx.x, g = blockIdx.y, f = threadIdx.x;
  const int fW = flags[iw];
  float s = 0.f;
  size_t wb = (size_t)a * E_ * E_ + f;
  for (int e = g * 32; e < g * 32 + 32; ++e)
    s += x[a * E_ + e] * ldw(W, wb + (size_t)e * E_, fW);
  part[((size_t)a * 8 + g) * E_ + f] = s;
}

template<int ACT>
__global__ void mvcomb_k(const float* __restrict__ part, const void* __restrict__ b, int ibb,
                         float* __restrict__ y, const int* __restrict__ flags) {
  int a = blockIdx.x, f = threadIdx.x;
  float s = 0.f;
  for (int g = 0; g < 8; ++g) s += part[((size_t)a * 8 + g) * E_ + f];
  s += ldw(b, (size_t)a * E_ + f, flags[ibb]);
  if (ACT == 1) s = fmaxf(s, 0.f);
  else if (ACT == 2) s = tanhf(s);
  y[a * E_ + f] = s;
}

__device__ inline float wave_sum64(float v) {
  for (int o = 32; o > 0; o >>= 1) v += __shfl_down(v, o);
  return v;
}

// qkvc[a][t][f] = w_t * (msg[others[t]] . in_w[a][f][:]) + in_b[a][f]  (wave per (a,f))
__global__ __launch_bounds__(256) void qkvcomm_k(const float* __restrict__ msg,
                                                 const void* __restrict__ comm_w,
                                                 const void* __restrict__ in_w,
                                                 const void* __restrict__ in_b,
                                                 float* __restrict__ qkvc,
                                                 const int* __restrict__ flags) {
  const int fCW = flags[57], fIW = flags[38], fIB = flags[39];
  int gw = blockIdx.x * 4 + (threadIdx.x >> 6);
  int a = gw / 768, f = gw % 768;
  int lane = threadIdx.x & 63;
  float w[5]; float mx = -1e30f;
  for (int j = 0; j < 5; ++j) { w[j] = ldw(comm_w, a * 5 + j, fCW); mx = fmaxf(mx, w[j]); }
  float sum = 0.f;
  for (int j = 0; j < 5; ++j) { w[j] = __expf(w[j] - mx); sum += w[j]; }
  for (int j = 0; j < 5; ++j) w[j] /= sum;
  int others[4]; { int c = 0; for (int j = 0; j < 5; ++j) if (j != a) others[c++] = j; }
  int e0 = lane * 4;
  float4 wv;
  if (fIW) wv = *(const float4*)((const float*)in_w + (size_t)a * 768 * E_ + (size_t)f * E_ + e0);
  else {
    size_t b = (size_t)a * 768 * E_ + (size_t)f * E_ + e0;
    wv = make_float4(ldw(in_w, b, 0), ldw(in_w, b + 1, 0), ldw(in_w, b + 2, 0), ldw(in_w, b + 3, 0));
  }
  float acc[4];
  #pragma unroll
  for (int t = 0; t < 4; ++t) {
    const float4 mv = *(const float4*)(msg + others[t] * E_ + e0);
    acc[t] = mv.x * wv.x + mv.y * wv.y + mv.z * wv.z + mv.w * wv.w;
  }
  #pragma unroll
  for (int t = 0; t < 4; ++t) acc[t] = wave_sum64(acc[t]);
  if (lane == 0) {
    float bb = ldw(in_b, (size_t)a * 768 + f, fIB);
    #pragma unroll
    for (int t = 0; t < 4; ++t)
      qkvc[((size_t)a * 4 + t) * 768 + f] = acc[t] * w[others[t]] + bb;
  }
}

// 4-token MHA (4 heads, hd=64) + token-mean -> obar[a][e]
__global__ __launch_bounds__(256) void attn4_k(const float* __restrict__ qkvc,
                                               float* __restrict__ obar) {
  int a = blockIdx.x, tid = threadIdx.x;
  __shared__ float qkv[4][768];
  __shared__ float attw[4][16];
  for (int i = tid; i < 4 * 768; i += 256) qkv[i / 768][i % 768] = qkvc[(size_t)a * 4 * 768 + i];
  __syncthreads();
  if (tid < 16) {
    int h = tid >> 2, t = tid & 3;
    float sc[4]; float mx = -1e30f;
    for (int t2 = 0; t2 < 4; ++t2) {
      float s = 0.f;
      for (int d = 0; d < 64; ++d) s += qkv[t][h * 64 + d] * qkv[t2][256 + h * 64 + d];
      sc[t2] = s * 0.125f; mx = fmaxf(mx, sc[t2]);
    }
    float ss = 0.f;
    for (int t2 = 0; t2 < 4; ++t2) { sc[t2] = __expf(sc[t2] - mx); ss += sc[t2]; }
    for (int t2 = 0; t2 < 4; ++t2) attw[h][t * 4 + t2] = sc[t2] / ss;
  }
  __syncthreads();
  {
    int e = tid, h = e >> 6;
    float s = 0.f;
    for (int t = 0; t < 4; ++t)
      for (int t2 = 0; t2 < 4; ++t2)
        s += attw[h][t * 4 + t2] * qkv[t2][512 + e];
    obar[a * E_ + e] = s * 0.25f;
  }
}

// comb[a][f] = internal + obar . out_w[a][f][:] + out_b   (wave per (a,f))
__global__ __launch_bounds__(256) void combproj_k(const float* __restrict__ obar,
                                                  const void* __restrict__ ow,
                                                  const void* __restrict__ ob,
                                                  const void* __restrict__ internal,
                                                  float* __restrict__ comb,
                                                  const int* __restrict__ flags) {
  const int fOW = flags[40], fOB = flags[41], fIN = flags[46];
  int gw = blockIdx.x * 4 + (threadIdx.x >> 6);
  int a = gw >> 8, f = gw & 255;
  int lane = threadIdx.x & 63;
  int e0 = lane * 4;
  float4 wv;
  if (fOW) wv = *(const float4*)((const float*)ow + (size_t)a * E_ * E_ + (size_t)f * E_ + e0);
  else {
    size_t b = (size_t)a * E_ * E_ + (size_t)f * E_ + e0;
    wv = make_float4(ldw(ow, b, 0), ldw(ow, b + 1, 0), ldw(ow, b + 2, 0), ldw(ow, b + 3, 0));
  }
  const float4 ov = *(const float4*)(obar + a * E_ + e0);
  float s = wave_sum64(ov.x * wv.x + ov.y * wv.y + ov.z * wv.z + ov.w * wv.w);
  if (lane == 0)
    comb[a * E_ + f] = ldw(internal, (size_t)a * E_ + f, fIN) + s + ldw(ob, (size_t)a * E_ + f, fOB);
}

// ---- xs_all = feats_s + ck (broadcast) ----
__global__ void addck_k(const float* __restrict__ fs, const float* __restrict__ ck,
                        float* __restrict__ xs) {
  size_t i = (size_t)blockIdx.x * 256 + threadIdx.x;
  int a = (int)(i >> 19);
  xs[i] = fs[i] + ck[a * E_ + (i & (E_ - 1))];
}

// ---- class-block attention stages (unchanged from R5) ----
__global__ __launch_bounds__(256) void attn_stats_k(
    const float* __restrict__ qkv_all, const int* __restrict__ idx,
    const int* __restrict__ cnt, const int* __restrict__ cstart,
    float* __restrict__ ml)
{
  int c = blockIdx.x; int z = blockIdx.z; int a = z >> 1, h = z & 1;
  int n = cnt[c];
  int r0 = blockIdx.y * 64;
  if (r0 >= n) return;
  const float* qkv = qkv_all + (size_t)a * NS_ * 768;
  const int* myidx = idx + c * NS_;
  int tid = threadIdx.x;
  int tx = tid & 15, ty = tid >> 4;
  __shared__ float Qs[16][68], Ks[16][68];
  float m4[4], l4[4];
  #pragma unroll
  for (int i = 0; i < 4; ++i) { m4[i] = -3e38f; l4[i] = 0.f; }
  int lrow = tid >> 2, lk = (tid & 3) * 4;
  for (int j0 = 0; j0 < n; j0 += 64) {
    float acc[4][4] = {{0.f}};
    for (int d0 = 0; d0 < 128; d0 += 16) {
      {
        int rr = r0 + lrow;
        float4 v = make_float4(0.f, 0.f, 0.f, 0.f);
        if (rr < n) {
          const float* s = qkv + (size_t)myidx[rr] * 768 + h * 128 + d0 + lk;
          v = make_float4(s[0], s[1], s[2], s[3]);
        }
        Qs[lk][lrow] = v.x; Qs[lk + 1][lrow] = v.y; Qs[lk + 2][lrow] = v.z; Qs[lk + 3][lrow] = v.w;
      }
      {
        int jj = j0 + lrow;
        float4 v = make_float4(0.f, 0.f, 0.f, 0.f);
        if (jj < n) {
          const float* s = qkv + (size_t)myidx[jj] * 768 + 256 + h * 128 + d0 + lk;
          v = make_float4(s[0], s[1], s[2], s[3]);
        }
        Ks[lk][lrow] = v.x; Ks[lk + 1][lrow] = v.y; Ks[lk + 2][lrow] = v.z; Ks[lk + 3][lrow] = v.w;
      }
      __syncthreads();
      #pragma unroll
      for (int k = 0; k < 16; ++k) {
        float4 av = *(const float4*)(&Qs[k][ty * 4]);
        float4 bv = *(const float4*)(&Ks[k][tx * 4]);
        float aa[4] = {av.x, av.y, av.z, av.w};
        float bb[4] = {bv.x, bv.y, bv.z, bv.w};
        #pragma unroll
        for (int i = 0; i < 4; ++i)
          #pragma unroll
          for (int j = 0; j < 4; ++j)
            acc[i][j] += aa[i] * bb[j];
      }
      __syncthreads();
    }
    #pragma unroll
    for (int jj = 0; jj < 4; ++jj) {
      int j = j0 + tx * 4 + jj;
      if (j >= n) continue;
      #pragma unroll
      for (int i = 0; i < 4; ++i) {
        float s = acc[i][jj] * QSCALE;
        if (s > m4[i]) { l4[i] = l4[i] * __expf(m4[i] - s) + 1.f; m4[i] = s; }
        else l4[i] += __expf(s - m4[i]);
      }
    }
  }
  __shared__ float Ms[64][17], Ls[64][17];
  #pragma unroll
  for (int i = 0; i < 4; ++i) { Ms[ty * 4 + i][tx] = m4[i]; Ls[ty * 4 + i][tx] = l4[i]; }
  __syncthreads();
  if (tid < 64 && r0 + tid < n) {
    float m = -3e38f;
    for (int t = 0; t < 16; ++t) m = fmaxf(m, Ms[tid][t]);
    float l = 0.f;
    for (int t = 0; t < 16; ++t) l += Ls[tid][t] * __expf(Ms[tid][t] - m);
    size_t p = (size_t)z * NS_ + cstart[c] + r0 + tid;
    ml[p * 2] = m; ml[p * 2 + 1] = l;
  }
}

__global__ __launch_bounds__(256) void attn_colsum_k(
    const float* __restrict__ qkv_all, const int* __restrict__ idx,
    const int* __restrict__ cnt, const int* __restrict__ cstart,
    const float* __restrict__ ml, float* __restrict__ colsum)
{
  int c = blockIdx.x; int z = blockIdx.z; int a = z >> 1, h = z & 1;
  int n = cnt[c];
  int j0 = blockIdx.y * 64;
  if (j0 >= n) return;
  const float* qkv = qkv_all + (size_t)a * NS_ * 768;
  const int* myidx = idx + c * NS_;
  int tid = threadIdx.x;
  int tx = tid & 15, ty = tid >> 4;
  __shared__ float Qs[16][68], Ks[16][68];
  float cs[4] = {0.f, 0.f, 0.f, 0.f};
  int lrow = tid >> 2, lk = (tid & 3) * 4;
  for (int i0 = 0; i0 < n; i0 += 64) {
    float acc[4][4] = {{0.f}};
    for (int d0 = 0; d0 < 128; d0 += 16) {
      {
        int rr = i0 + lrow;
        float4 v = make_float4(0.f, 0.f, 0.f, 0.f);
        if (rr < n) {
          const float* s = qkv + (size_t)myidx[rr] * 768 + h * 128 + d0 + lk;
          v = make_float4(s[0], s[1], s[2], s[3]);
        }
        Qs[lk][lrow] = v.x; Qs[lk + 1][lrow] = v.y; Qs[lk + 2][lrow] = v.z; Qs[lk + 3][lrow] = v.w;
      }
      {
        int jj = j0 + lrow;
        float4 v = make_float4(0.f, 0.f, 0.f, 0.f);
        if (jj < n) {
          const float* s = qkv + (size_t)myidx[jj] * 768 + 256 + h * 128 + d0 + lk;
          v = make_float4(s[0], s[1], s[2], s[3]);
        }
        Ks[lk][lrow] = v.x; Ks[lk + 1][lrow] = v.y; Ks[lk + 2][lrow] = v.z; Ks[lk + 3][lrow] = v.w;
      }
      __syncthreads();
      #pragma unroll
      for (int k = 0; k < 16; ++k) {
        float4 av = *(const float4*)(&Qs[k][ty * 4]);
        float4 bv = *(const float4*)(&Ks[k][tx * 4]);
        float aa[4] = {av.x, av.y, av.z, av.w};
        float bb[4] = {bv.x, bv.y, bv.z, bv.w};
        #pragma unroll
        for (int i = 0; i < 4; ++i)
          #pragma unroll
          for (int j = 0; j < 4; ++j)
            acc[i][j] += aa[i] * bb[j];
      }
      __syncthreads();
    }
    #pragma unroll
    for (int i = 0; i < 4; ++i) {
      int gi = i0 + ty * 4 + i;
      if (gi >= n) continue;
      size_t p = (size_t)z * NS_ + cstart[c] + gi;
      float m = ml[p * 2];
      float invl = 1.f / ml[p * 2 + 1];
      #pragma unroll
      for (int jj = 0; jj < 4; ++jj) {
        int j = j0 + tx * 4 + jj;
        if (j >= n) continue;
        cs[jj] += __expf(acc[i][jj] * QSCALE - m) * invl;
      }
    }
  }
  __shared__ float Cs[64][17];
  #pragma unroll
  for (int jj = 0; jj < 4; ++jj) Cs[tx * 4 + jj][ty] = cs[jj];
  __syncthreads();
  if (tid < 64 && j0 + tid < n) {
    float s = 0.f;
    for (int t = 0; t < 16; ++t) s += Cs[tid][t];
    colsum[(size_t)z * NS_ + cstart[c] + j0 + tid] = s;
  }
}

__global__ void proto_combine_k(const float* __restrict__ qkv_all, const int* __restrict__ idx,
                                const int* __restrict__ cnt, const int* __restrict__ cstart,
                                const float* __restrict__ colsum, float* __restrict__ proto_pre) {
  int c = blockIdx.x, a = blockIdx.y;
  int e = threadIdx.x, h = e >> 7, d = e & 127;
  int n = cnt[c];
  const float* qkv = qkv_all + (size_t)a * NS_ * 768;
  const float* csum = colsum + (size_t)(a * 2 + h) * NS_ + cstart[c];
  const int* myidx = idx + c * NS_;
  float s = 0.f;
  for (int k = 0; k < n; ++k)
    s += csum[k] * qkv[(size_t)myidx[k] * 768 + 512 + h * 128 + d];
  proto_pre[((size_t)a * NWAY_ + c) * E_ + e] = (n > 0) ? s / (float)n : 0.f;
}

__global__ void proto_outproj_k(const float* __restrict__ proto_pre, const void* __restrict__ ow,
                                const void* __restrict__ ob, const int* __restrict__ cnt,
                                float* __restrict__ protos_all, const int* __restrict__ flags) {
  int c = blockIdx.x, a = blockIdx.y, e = threadIdx.x;
  const int fW = flags[49], fB = flags[50];
  __shared__ float pp[E_];
  pp[e] = proto_pre[((size_t)a * NWAY_ + c) * E_ + e];
  __syncthreads();
  size_t wb = (size_t)a * E_ * E_ + (size_t)e * E_;
  float s = 0.f;
  for (int k = 0; k < E_; ++k) s += pp[k] * ldw(ow, wb + k, fW);
  float v = s + ldw(ob, (size_t)a * E_ + e, fB);
  protos_all[((size_t)a * NWAY_ + c) * E_ + e] = (cnt[c] > 0) ? v : 0.f;
}

__global__ void bias2_k(const float* __restrict__ ck, const void* __restrict__ w1,
                        const void* __restrict__ b1, float* __restrict__ bias2_all,
                        const int* __restrict__ flags) {
  const int fW = flags[51], fB = flags[52];
  int a = blockIdx.x, n = threadIdx.x;
  __shared__ float c[E_];
  c[n] = ck[a * E_ + n]; __syncthreads();
  size_t wbase = (size_t)a * 2 * E_ * E_ + (size_t)E_ * E_ + n;
  float s = 0.f;
  for (int k = 0; k < E_; ++k) s += c[k] * ldw(w1, wbase + (size_t)k * E_, fW);
  bias2_all[a * E_ + n] = s + ldw(b1, (size_t)a * E_ + n, fB);
}

// ---------------- epilogues ----------------
__global__ __launch_bounds__(64) void logits_k(const float* __restrict__ fq, const float* __restrict__ protos,
                                               const float* __restrict__ c2, const void* __restrict__ w3,
                                               const void* __restrict__ b3, int a, float* __restrict__ out,
                                               const int* __restrict__ flags) {
  const int fW = flags[55], fB = flags[56];
  int i = blockIdx.x, lane = threadIdx.x;
  float4 xv = ((const float4*)(fq + (size_t)i * E_))[lane];
  float qq = wave_sum64(xv.x * xv.x + xv.y * xv.y + xv.z * xv.z + xv.w * xv.w);
  float cpart = c2[(size_t)i * 128 + lane * 2] * ldw(w3, (size_t)a * 128 + lane * 2, fW) +
                c2[(size_t)i * 128 + lane * 2 + 1] * ldw(w3, (size_t)a * 128 + lane * 2 + 1, fW);
  float conf = wave_sum64(cpart);
  if (lane == 0) conf += ldw(b3, a, fB);
  for (int c = 0; c < NWAY_; ++c) {
    float4 pv = ((const float4*)(protos + c * E_))[lane];
    float dt = wave_sum64(xv.x * pv.x + xv.y * pv.y + xv.z * pv.z + xv.w * pv.w);
    float pp = wave_sum64(pv.x * pv.x + pv.y * pv.y + pv.z * pv.z + pv.w * pv.w);
    if (lane == 0) {
      float d2 = fmaxf(qq + pp - 2.f * dt, 1e-12f);
      out[(size_t)i * NWAY_ + c] = -sqrtf(d2) + 0.1f * conf;
    }
  }
}

__global__ __launch_bounds__(64) void fused_k(const float* __restrict__ h2, const void* __restrict__ w3,
                                              const void* __restrict__ b3, float* __restrict__ out,
                                              const int* __restrict__ flags) {
  const int fW = flags[62], fB = flags[63];
  int i = blockIdx.x, lane = threadIdx.x;
  float s = h2[(size_t)i * 128 + lane * 2] * ldw(w3, lane * 2, fW) +
            h2[(size_t)i * 128 + lane * 2 + 1] * ldw(w3, lane * 2 + 1, fW);
  s = wave_sum64(s);
  if (lane == 0) out[i] = s + ldw(b3, 0, fB);
}

// ---------------- host ----------------
extern "C" void kernel_launch(void* const* d_in, const int* in_sizes, int n_in,
                              void* d_out, int out_size, void* d_ws, size_t ws_size,
                              hipStream_t stream) {
  (void)out_size; (void)ws_size;
  #define P(i) ((const void*)d_in[i])
  const int* support_y = (const int*)d_in[1];
  float* out = (float*)d_out;

  int* flags = (int*)d_ws;
  float* W = (float*)((char*)d_ws + 256);
  float* feats_s = W;                                    // A*NS*E
  float* feats_q = feats_s + (size_t)A_ * NS_ * E_;      // A*NQ*E
  float* R12     = feats_q + (size_t)A_ * NQ_ * E_;
  const size_t R12_SZ = (size_t)A_ * NS_ * E_ + (size_t)A_ * NS_ * 768;
  float* t1 = R12;
  float* t2 = R12 + (size_t)NQ_ * 3 * E_;
  float* xs_all  = R12;
  float* qkv_all = R12 + (size_t)A_ * NS_ * E_;

  float* smalls = R12 + R12_SZ;
  float* state      = smalls;
  float* msg        = state + A_ * E_;
  float* ck         = msg + A_ * E_;
  float* protos_all = ck + A_ * E_;
  float* bias2_all  = protos_all + A_ * NWAY_ * E_;
  float* ml         = bias2_all + A_ * E_;
  float* colsum     = ml + (size_t)A_ * 2 * NS_ * 2;
  float* proto_pre  = colsum + (size_t)A_ * 2 * NS_;
  int*   idx        = (int*)(proto_pre + A_ * NWAY_ * E_);
  int*   cnt        = idx + NWAY_ * NS_;
  int*   cstart     = cnt + NWAY_;
  float* statepart  = (float*)(cstart + NWAY_ + 3);   // A*16*E
  float* mvp        = statepart + A_ * 16 * E_;       // A*8*E
  float* qkvc       = mvp + A_ * 8 * E_;              // A*4*768
  float* obar       = qkvc + A_ * 4 * 768;            // A*E
  float* comb       = obar + A_ * E_;                 // A*E
  float* hh         = comb + A_ * E_;                 // A*E

  Ptrs ps;
  for (int i = 0; i < 64; ++i) {
    ps.p[i] = (i < n_in) ? d_in[i] : nullptr;
    ps.sz[i] = (i < n_in) ? in_sizes[i] : 0;
  }
  probe_k<<<64, 64, 0, stream>>>(ps, flags);
  classidx_k<<<1, 64, 0, stream>>>(support_y, idx, cnt, cstart);

  auto fe = [&](const void* x, int xi, int N, float* feats) {
    gemm<true, true, true, false, 0, false>(stream, x, 512, P(4), 512, 0, P(5), 0, t1, 512, N, 512, 512, 1.f, xi, 4, 5, flags);
    ln_k<1><<<N, 256, 0, stream>>>(t1, P(6), P(7), t1, 512, 6, 7, flags);
    gemm<false, true, true, false, 0, false>(stream, t1, 512, P(8), 256, 0, P(9), 0, t2, 256, N, 256, 512, 1.f, -1, 8, 9, flags);
    ln_k<1><<<N, 256, 0, stream>>>(t2, P(10), P(11), feats, 256, 10, 11, flags);
    gemm<true, true, true, false, 0, false>(stream, x, 512, P(12), 256, 0, P(13), 0, t2, 256, N, 256, 512, 1.f, xi, 12, 13, flags);
    ln_k<1><<<N, 256, 0, stream>>>(t2, P(14), P(15), t2, 256, 14, 15, flags);
    gemm<false, true, true, false, 2, false>(stream, t2, 256, P(16), 256, 0, P(17), 0, feats + (size_t)N * E_, 256, N, 256, 256, 1.f, -1, 16, 17, flags);
    gemm<true, true, true, false, 1, false>(stream, x, 512, P(18), 768, 0, P(19), 0, t1, 768, N, 768, 512, 1.f, xi, 18, 19, flags);
    gemm<false, true, true, false, 0, false>(stream, t1, 768, P(20), 256, 0, P(21), 0, t2, 256, N, 256, 768, 1.f, -1, 20, 21, flags);
    ln_k<1><<<N, 256, 0, stream>>>(t2, P(22), P(23), feats + (size_t)2 * N * E_, 256, 22, 23, flags);
    gemm<true, true, true, false, 1, false>(stream, x, 512, P(24), 256, 0, P(25), 0, t2, 256, N, 256, 512, 1.f, xi, 24, 25, flags);
    gemm<false, true, true, false, 0, false>(stream, t2, 256, P(26), 256, 0, P(27), 0, t1, 256, N, 256, 256, 1.f, -1, 26, 27, flags);
    ln_k<3><<<N, 256, 0, stream>>>(t1, P(28), P(29), feats + (size_t)3 * N * E_, 256, 28, 29, flags);
    gemm<true, true, true, false, 1, false>(stream, x, 512, P(30), 512, 0, P(31), 0, t1, 512, N, 512, 512, 1.f, xi, 30, 31, flags);
    gemm<false, true, true, false, 1, false>(stream, t1, 512, P(32), 256, 0, P(33), 0, t2, 256, N, 256, 512, 1.f, -1, 32, 33, flags);
    gemm<false, true, true, false, 0, false>(stream, t2, 256, P(34), 256, 0, P(35), 0, feats + (size_t)4 * N * E_, 256, N, 256, 256, 1.f, -1, 34, 35, flags);
  };
  fe(P(0), 0, NS_, feats_s);
  fe(P(2), 2, NQ_, feats_q);

  // ---- comm round (parallel micro-kernels) ----
  statepart_k<<<dim3(A_, 16), 256, 0, stream>>>(feats_s, statepart);
  statecomb_k<<<A_, 256, 0, stream>>>(statepart, P(46), state, flags);
  mvpart_k<<<dim3(A_, 8), 256, 0, stream>>>(state, P(36), 36, mvp, flags);
  mvcomb_k<2><<<A_, 256, 0, stream>>>(mvp, P(37), 37, msg, flags);
  qkvcomm_k<<<A_ * 768 / 4, 256, 0, stream>>>(msg, P(57), P(38), P(39), qkvc, flags);
  attn4_k<<<A_, 256, 0, stream>>>(qkvc, obar);
  combproj_k<<<A_ * E_ / 4, 256, 0, stream>>>(obar, P(40), P(41), P(46), comb, flags);
  mvpart_k<<<dim3(A_, 8), 256, 0, stream>>>(comb, P(42), 42, mvp, flags);
  mvcomb_k<1><<<A_, 256, 0, stream>>>(mvp, P(43), 43, hh, flags);
  mvpart_k<<<dim3(A_, 8), 256, 0, stream>>>(hh, P(44), 44, mvp, flags);
  mvcomb_k<0><<<A_, 256, 0, stream>>>(mvp, P(45), 45, ck, flags);

  // ---- batched prototype attention ----
  addck_k<<<(A_ * NS_ * E_) / 256, 256, 0, stream>>>(feats_s, ck, xs_all);
  gemm<false, true, true, true, 0, false>(stream, xs_all, 256, P(47), 256, 0, P(48), 0,
                                          qkv_all, 768, NS_, 768, 256, 1.f, -1, 47, 48, flags,
                                          A_, (size_t)NS_ * E_, (size_t)3 * E_ * E_, (size_t)3 * E_,
                                          (size_t)NS_ * 768);
  {
    dim3 g(NWAY_, NS_ / 64, A_ * 2);
    attn_stats_k<<<g, 256, 0, stream>>>(qkv_all, idx, cnt, cstart, ml);
    attn_colsum_k<<<g, 256, 0, stream>>>(qkv_all, idx, cnt, cstart, ml, colsum);
  }
  proto_combine_k<<<dim3(NWAY_, A_), 256, 0, stream>>>(qkv_all, idx, cnt, cstart, colsum, proto_pre);
  proto_outproj_k<<<dim3(NWAY_, A_), 256, 0, stream>>>(proto_pre, P(49), P(50), cnt, protos_all, flags);
  bias2_k<<<A_, 256, 0, stream>>>(ck, P(51), P(52), bias2_all, flags);

  // ---- per-agent classifier chain + logits ----
  float* clsC = R12;
  float* clsC2 = R12 + (size_t)NQ_ * E_;
  for (int a = 0; a < A_; ++a) {
    gemm<false, true, false, false, 1, false>(stream, feats_q + (size_t)a * NQ_ * E_, 256,
                                              P(51), 256, (size_t)a * 2 * E_ * E_, bias2_all + a * E_, 0,
                                              clsC, 256, NQ_, 256, 256, 1.f, -1, 51, -1, flags);
    gemm<false, true, true, false, 1, false>(stream, clsC, 256, P(53), 128, (size_t)a * E_ * 128,
                                             P(54), (size_t)a * 128, clsC2, 128, NQ_, 128, 256, 1.f, -1, 53, 54, flags);
    logits_k<<<NQ_, 64, 0, stream>>>(feats_q + (size_t)a * NQ_ * E_, protos_all + (size_t)a * NWAY_ * E_,
                                     clsC2, P(55), P(56), a, out + (size_t)a * NQ_ * NWAY_, flags);
  }

  // ---- fusion ----
  float* fh1 = R12;
  float* fh2 = R12 + (size_t)NQ_ * E_;
  gemm<false, true, true, false, 0, false>(stream, feats_q, 256, P(58), 256, 0, P(59), 0, fh1, 256, NQ_, 256, 256, 1.f, -1, 58, 59, flags);
  for (int a = 1; a < 4; ++a)
    gemm<false, true, false, false, 0, true>(stream, feats_q + (size_t)a * NQ_ * E_, 256,
                                             P(58), 256, (size_t)a * E_ * 256, nullptr, 0,
                                             fh1, 256, NQ_, 256, 256, 1.f, -1, 58, -1, flags);
  gemm<false, true, false, false, 1, true>(stream, feats_q + (size_t)4 * NQ_ * E_, 256,
                                           P(58), 256, (size_t)4 * E_ * 256, nullptr, 0,
                                           fh1, 256, NQ_, 256, 256, 1.f, -1, 58, -1, flags);
  gemm<false, true, true, false, 1, false>(stream, fh1, 256, P(60), 128, 0, P(61), 0, fh2, 128, NQ_, 128, 256, 1.f, -1, 60, 61, flags);
  fused_k<<<NQ_, 64, 0, stream>>>(fh2, P(62), P(63), out + (size_t)A_ * NQ_ * NWAY_, flags);
}

// Round 7
// 1777.388 us; speedup vs baseline: 3.8924x; 1.2226x over previous
//
#include <hip/hip_runtime.h>
#include <hip/hip_bf16.h>

typedef __hip_bfloat16 bf16;
typedef short s8v __attribute__((ext_vector_type(8)));
typedef short s4v __attribute__((ext_vector_type(4)));
typedef float f4v __attribute__((ext_vector_type(4)));

#define A_  5
#define D_  512
#define E_  256
#define NS_ 2048
#define NQ_ 8192
#define NWAY_ 5
#define QSCALE 0.088388347648318447f

// ---- per-tensor dtype dispatch: flags[i]=1 -> input i is f32, 0 -> bf16 ----
__device__ inline float ldw(const void* p, size_t i, int f32) {
  return f32 ? ((const float*)p)[i] : __bfloat162float(((const bf16*)p)[i]);
}
template<bool DYN>
__device__ inline float ldT(const void* p, size_t i, int f32) {
  if (DYN) return ldw(p, i, f32);
  return ((const float*)p)[i];
}

__device__ inline short f2bf(float v) {
  union { float f; unsigned u; } x; x.f = v;
  unsigned r = x.u + 0x7fffu + ((x.u >> 16) & 1u);
  return (short)(r >> 16);
}

struct Ptrs { const void* p[64]; int sz[64]; };

__global__ void probe_k(Ptrs P, int* flags) {
  int b = blockIdx.x, lane = threadIdx.x;
  if (b == 1 || b == 3) { if (lane == 0) flags[b] = 0; return; }
  const bf16* t = (const bf16*)P.p[b];
  int n = P.sz[b];
  int K = (n >> 1) < 64 ? (n >> 1) : 64;
  bool big = false, eNZ = false, oNZ = false;
  if (lane < K) {
    float e = __bfloat162float(t[2 * lane]);
    float o = __bfloat162float(t[2 * lane + 1]);
    big = !(fabsf(e) <= 1e3f);
    eNZ = (e != 0.f); oNZ = (o != 0.f);
  }
  unsigned long long bb = __ballot(big), eb = __ballot(eNZ), ob = __ballot(oNZ);
  if (lane == 0) flags[b] = (bb != 0ull || (eb == 0ull && ob != 0ull)) ? 1 : 0;
}

// ---- class index lists (parallel; order within class irrelevant: consumers are set-sums) ----
__global__ void czero_k(int* cnt) { if (threadIdx.x < NWAY_) cnt[threadIdx.x] = 0; }
__global__ void cfill_k(const int* __restrict__ y, int* __restrict__ idx, int* __restrict__ cnt) {
  int i = blockIdx.x * 256 + threadIdx.x;
  int c = y[i];
  int pos = atomicAdd(&cnt[c], 1);
  idx[c * NS_ + pos] = i;
}
__global__ void cstart_k(const int* __restrict__ cnt, int* __restrict__ cstart) {
  if (threadIdx.x == 0) { int s = 0; for (int q = 0; q < NWAY_; ++q) { cstart[q] = s; s += cnt[q]; } }
}

// ============ MFMA bf16 GEMM: C[M,N] = act(alpha*A@B (+C) (+bias)) ============
// REQUIRES: M%128==0, N%128==0, K%32==0.
// KSPLIT: A element (m,k) at A[(k>>8)*kstrideA + m*lda + (k&255)] (concat of 256-wide blocks).
#define LSTR 40
template<bool DYNA, bool DYNB, bool DYNBIAS, bool TRB, int ACT, bool ACCUM, bool KSPLIT = false>
__global__ __launch_bounds__(256) void gemm_k(
    const void* __restrict__ A, int lda,
    const void* __restrict__ B, int ldb, size_t offB,
    const void* __restrict__ bias, size_t offBias,
    float* __restrict__ C, int ldc,
    int M, int N, int K, float alpha,
    int ia, int ib, int ibias, const int* __restrict__ flags,
    size_t sA, size_t sB, size_t sBias, size_t sC, size_t kstrideA)
{
  const int fA = DYNA ? flags[ia] : 1;
  const int fB = DYNB ? flags[ib] : 1;
  const int fBi = DYNBIAS ? flags[ibias] : 1;
  const size_t zA = (size_t)blockIdx.z * sA;
  const size_t zB = offB + (size_t)blockIdx.z * sB;
  const size_t zBias = offBias + (size_t)blockIdx.z * sBias;
  float* Cz = C + (size_t)blockIdx.z * sC;
  __shared__ short As[128 * LSTR];
  __shared__ short Bs[128 * LSTR];
  const int tid = threadIdx.x;
  const int bm = blockIdx.y * 128, bn = blockIdx.x * 128;
  const int lane = tid & 63, wid = tid >> 6;
  const int lm = lane & 15, quad = lane >> 4;
  const int wy = (wid >> 1) * 64, wx = (wid & 1) * 64;
  f4v acc[4][4];
  #pragma unroll
  for (int i = 0; i < 4; ++i)
    #pragma unroll
    for (int j = 0; j < 4; ++j) acc[i][j] = (f4v)(0.f);

  const int am = tid >> 1, ah = (tid & 1) * 16;

  for (int k0 = 0; k0 < K; k0 += 32) {
    {
      int kk = k0 + ah;
      size_t base;
      if (KSPLIT) base = zA + (size_t)(kk >> 8) * kstrideA + (size_t)(bm + am) * lda + (kk & 255);
      else base = zA + (size_t)(bm + am) * lda + kk;
      short tmp[16];
      if (fA) {
        const float4* src = (const float4*)((const float*)A + base);
        #pragma unroll
        for (int q = 0; q < 4; ++q) {
          float4 v = src[q];
          tmp[q*4+0] = f2bf(v.x); tmp[q*4+1] = f2bf(v.y);
          tmp[q*4+2] = f2bf(v.z); tmp[q*4+3] = f2bf(v.w);
        }
      } else {
        #pragma unroll
        for (int q = 0; q < 16; ++q) tmp[q] = f2bf(ldw(A, base + q, 0));
      }
      s4v* dst = (s4v*)&As[am * LSTR + ah];
      #pragma unroll
      for (int q = 0; q < 4; ++q) dst[q] = *(s4v*)&tmp[q*4];
    }
    if (TRB) {
      int n = tid >> 1, h = (tid & 1) * 16;
      size_t base = zB + (size_t)(bn + n) * ldb + k0 + h;
      short tmp[16];
      if (fB) {
        const float4* src = (const float4*)((const float*)B + base);
        #pragma unroll
        for (int q = 0; q < 4; ++q) {
          float4 v = src[q];
          tmp[q*4+0] = f2bf(v.x); tmp[q*4+1] = f2bf(v.y);
          tmp[q*4+2] = f2bf(v.z); tmp[q*4+3] = f2bf(v.w);
        }
      } else {
        #pragma unroll
        for (int q = 0; q < 16; ++q) tmp[q] = f2bf(ldw(B, base + q, 0));
      }
      s4v* dst = (s4v*)&Bs[n * LSTR + h];
      #pragma unroll
      for (int q = 0; q < 4; ++q) dst[q] = *(s4v*)&tmp[q*4];
    } else {
      int n = tid & 127, kk = (tid >> 7) * 16;
      short tmp[16];
      #pragma unroll
      for (int j = 0; j < 16; ++j)
        tmp[j] = f2bf(ldT<DYNB>(B, zB + (size_t)(k0 + kk + j) * ldb + bn + n, fB));
      s4v* dst = (s4v*)&Bs[n * LSTR + kk];
      #pragma unroll
      for (int q = 0; q < 4; ++q) dst[q] = *(s4v*)&tmp[q*4];
    }
    __syncthreads();
    s8v af[4], bfr[4];
    #pragma unroll
    for (int mi = 0; mi < 4; ++mi)
      af[mi] = *(const s8v*)&As[(wy + mi*16 + lm) * LSTR + quad * 8];
    #pragma unroll
    for (int ni = 0; ni < 4; ++ni)
      bfr[ni] = *(const s8v*)&Bs[(wx + ni*16 + lm) * LSTR + quad * 8];
    #pragma unroll
    for (int mi = 0; mi < 4; ++mi)
      #pragma unroll
      for (int ni = 0; ni < 4; ++ni)
        acc[mi][ni] = __builtin_amdgcn_mfma_f32_16x16x32_bf16(af[mi], bfr[ni], acc[mi][ni], 0, 0, 0);
    __syncthreads();
  }
  #pragma unroll
  for (int mi = 0; mi < 4; ++mi) {
    #pragma unroll
    for (int r = 0; r < 4; ++r) {
      int row = bm + wy + mi*16 + quad*4 + r;
      #pragma unroll
      for (int ni = 0; ni < 4; ++ni) {
        int col = bn + wx + ni*16 + lm;
        float v = acc[mi][ni][r] * alpha;
        if (ACCUM) v += Cz[(size_t)row * ldc + col];
        if (bias) v += ldT<DYNBIAS>(bias, zBias + col, fBi);
        if (ACT == 1) v = fmaxf(v, 0.f);
        else if (ACT == 2) v = tanhf(v);
        else if (ACT == 3) v = 1.f / (1.f + expf(-v));
        Cz[(size_t)row * ldc + col] = v;
      }
    }
  }
}

template<bool DYNA, bool DYNB, bool DYNBIAS, bool TRB, int ACT, bool ACCUM, bool KSPLIT = false>
static void gemm(hipStream_t s, const void* A, int lda, const void* B, int ldb, size_t offB,
                 const void* bias, size_t offBias, float* C, int ldc, int M, int N, int K,
                 float alpha, int ia, int ib, int ibias, const int* flags,
                 int batch = 1, size_t sA = 0, size_t sB = 0, size_t sBias = 0, size_t sC = 0,
                 size_t kstrideA = 0) {
  dim3 g(N / 128, M / 128, batch), b(256);
  gemm_k<DYNA, DYNB, DYNBIAS, TRB, ACT, ACCUM, KSPLIT><<<g, b, 0, s>>>(
      A, lda, B, ldb, offB, bias, offBias, C, ldc, M, N, K, alpha, ia, ib, ibias, flags,
      sA, sB, sBias, sC, kstrideA);
}

// ---------------- LayerNorm (+relu/sigmoid) ----------------
template<int ACT>
__global__ __launch_bounds__(256) void ln_k(const float* __restrict__ X, const void* __restrict__ g,
                                            const void* __restrict__ be, float* __restrict__ Y, int W,
                                            int ig, int ibe, const int* __restrict__ flags) {
  const int fG = flags[ig], fBe = flags[ibe];
  int row = blockIdx.x;
  const float* x = X + (size_t)row * W;
  float* y = Y + (size_t)row * W;
  __shared__ float red[256];
  int tid = threadIdx.x;
  float s1 = 0.f, s2 = 0.f;
  for (int i = tid; i < W; i += 256) { float v = x[i]; s1 += v; s2 += v * v; }
  red[tid] = s1; __syncthreads();
  for (int o = 128; o > 0; o >>= 1) { if (tid < o) red[tid] += red[tid + o]; __syncthreads(); }
  float mean = red[0] / W; __syncthreads();
  red[tid] = s2; __syncthreads();
  for (int o = 128; o > 0; o >>= 1) { if (tid < o) red[tid] += red[tid + o]; __syncthreads(); }
  float var = fmaxf(red[0] / W - mean * mean, 0.f);
  float rstd = rsqrtf(var + 1e-5f);
  for (int i = tid; i < W; i += 256) {
    float v = (x[i] - mean) * rstd * ldw(g, i, fG) + ldw(be, i, fBe);
    if (ACT == 1) v = fmaxf(v, 0.f);
    else if (ACT == 3) v = 1.f / (1.f + expf(-v));
    y[i] = v;
  }
}

// ================= comm round (parallel micro-kernels) =================
__global__ void statepart_k(const float* __restrict__ fs, float* __restrict__ part) {
  int a = blockIdx.x, g = blockIdx.y, e = threadIdx.x;
  const float* p = fs + ((size_t)a * NS_ + g * 128) * E_ + e;
  float s = 0.f;
  for (int n = 0; n < 128; ++n) s += p[(size_t)n * E_];
  part[((size_t)a * 16 + g) * E_ + e] = s;
}

__global__ void statecomb_k(const float* __restrict__ part, const void* __restrict__ internal,
                            float* __restrict__ state, const int* __restrict__ flags) {
  int a = blockIdx.x, e = threadIdx.x;
  float s = 0.f;
  for (int g = 0; g < 16; ++g) s += part[((size_t)a * 16 + g) * E_ + e];
  state[a * E_ + e] = s * (1.f / NS_) + ldw(internal, (size_t)a * E_ + e, flags[46]);
}

__global__ void mvpart_k(const float* __restrict__ x, const void* __restrict__ W, int iw,
                         float* __restrict__ part, const int* __restrict__ flags) {
  int a = blockIdx.x, g = blockIdx.y, f = threadIdx.x;
  const int fW = flags[iw];
  float s = 0.f;
  size_t wb = (size_t)a * E_ * E_ + f;
  for (int e = g * 32; e < g * 32 + 32; ++e)
    s += x[a * E_ + e] * ldw(W, wb + (size_t)e * E_, fW);
  part[((size_t)a * 8 + g) * E_ + f] = s;
}

template<int ACT>
__global__ void mvcomb_k(const float* __restrict__ part, const void* __restrict__ b, int ibb,
                         float* __restrict__ y, const int* __restrict__ flags) {
  int a = blockIdx.x, f = threadIdx.x;
  float s = 0.f;
  for (int g = 0; g < 8; ++g) s += part[((size_t)a * 8 + g) * E_ + f];
  s += ldw(b, (size_t)a * E_ + f, flags[ibb]);
  if (ACT == 1) s = fmaxf(s, 0.f);
  else if (ACT == 2) s = tanhf(s);
  y[a * E_ + f] = s;
}

__device__ inline float wave_sum64(float v) {
  for (int o = 32; o > 0; o >>= 1) v += __shfl_down(v, o);
  return v;
}

__global__ __launch_bounds__(256) void qkvcomm_k(const float* __restrict__ msg,
                                                 const void* __restrict__ comm_w,
                                                 const void* __restrict__ in_w,
                                                 const void* __restrict__ in_b,
                                                 float* __restrict__ qkvc,
                                                 const int* __restrict__ flags) {
  const int fCW = flags[57], fIW = flags[38], fIB = flags[39];
  int gw = blockIdx.x * 4 + (threadIdx.x >> 6);
  int a = gw / 768, f = gw % 768;
  int lane = threadIdx.x & 63;
  float w[5]; float mx = -1e30f;
  for (int j = 0; j < 5; ++j) { w[j] = ldw(comm_w, a * 5 + j, fCW); mx = fmaxf(mx, w[j]); }
  float sum = 0.f;
  for (int j = 0; j < 5; ++j) { w[j] = __expf(w[j] - mx); sum += w[j]; }
  for (int j = 0; j < 5; ++j) w[j] /= sum;
  int others[4]; { int c = 0; for (int j = 0; j < 5; ++j) if (j != a) others[c++] = j; }
  int e0 = lane * 4;
  float4 wv;
  size_t b = (size_t)a * 768 * E_ + (size_t)f * E_ + e0;
  if (fIW) wv = *(const float4*)((const float*)in_w + b);
  else wv = make_float4(ldw(in_w, b, 0), ldw(in_w, b + 1, 0), ldw(in_w, b + 2, 0), ldw(in_w, b + 3, 0));
  float acc[4];
  #pragma unroll
  for (int t = 0; t < 4; ++t) {
    const float4 mv = *(const float4*)(msg + others[t] * E_ + e0);
    acc[t] = mv.x * wv.x + mv.y * wv.y + mv.z * wv.z + mv.w * wv.w;
  }
  #pragma unroll
  for (int t = 0; t < 4; ++t) acc[t] = wave_sum64(acc[t]);
  if (lane == 0) {
    float bb = ldw(in_b, (size_t)a * 768 + f, fIB);
    #pragma unroll
    for (int t = 0; t < 4; ++t)
      qkvc[((size_t)a * 4 + t) * 768 + f] = acc[t] * w[others[t]] + bb;
  }
}

__global__ __launch_bounds__(256) void attn4_k(const float* __restrict__ qkvc,
                                               float* __restrict__ obar) {
  int a = blockIdx.x, tid = threadIdx.x;
  __shared__ float qkv[4][768];
  __shared__ float attw[4][16];
  for (int i = tid; i < 4 * 768; i += 256) qkv[i / 768][i % 768] = qkvc[(size_t)a * 4 * 768 + i];
  __syncthreads();
  if (tid < 16) {
    int h = tid >> 2, t = tid & 3;
    float sc[4]; float mx = -1e30f;
    for (int t2 = 0; t2 < 4; ++t2) {
      float s = 0.f;
      for (int d = 0; d < 64; ++d) s += qkv[t][h * 64 + d] * qkv[t2][256 + h * 64 + d];
      sc[t2] = s * 0.125f; mx = fmaxf(mx, sc[t2]);
    }
    float ss = 0.f;
    for (int t2 = 0; t2 < 4; ++t2) { sc[t2] = __expf(sc[t2] - mx); ss += sc[t2]; }
    for (int t2 = 0; t2 < 4; ++t2) attw[h][t * 4 + t2] = sc[t2] / ss;
  }
  __syncthreads();
  {
    int e = tid, h = e >> 6;
    float s = 0.f;
    for (int t = 0; t < 4; ++t)
      for (int t2 = 0; t2 < 4; ++t2)
        s += attw[h][t * 4 + t2] * qkv[t2][512 + e];
    obar[a * E_ + e] = s * 0.25f;
  }
}

__global__ __launch_bounds__(256) void combproj_k(const float* __restrict__ obar,
                                                  const void* __restrict__ ow,
                                                  const void* __restrict__ ob,
                                                  const void* __restrict__ internal,
                                                  float* __restrict__ comb,
                                                  const int* __restrict__ flags) {
  const int fOW = flags[40], fOB = flags[41], fIN = flags[46];
  int gw = blockIdx.x * 4 + (threadIdx.x >> 6);
  int a = gw >> 8, f = gw & 255;
  int lane = threadIdx.x & 63;
  int e0 = lane * 4;
  float4 wv;
  size_t b = (size_t)a * E_ * E_ + (size_t)f * E_ + e0;
  if (fOW) wv = *(const float4*)((const float*)ow + b);
  else wv = make_float4(ldw(ow, b, 0), ldw(ow, b + 1, 0), ldw(ow, b + 2, 0), ldw(ow, b + 3, 0));
  const float4 ov = *(const float4*)(obar + a * E_ + e0);
  float s = wave_sum64(ov.x * wv.x + ov.y * wv.y + ov.z * wv.z + ov.w * wv.w);
  if (lane == 0)
    comb[a * E_ + f] = ldw(internal, (size_t)a * E_ + f, fIN) + s + ldw(ob, (size_t)a * E_ + f, fOB);
}

// ---- ckb[a][f] = ck[a] . in_w[a][f][:] + in_b[a][f]  (qkv GEMM bias fold) ----
__global__ __launch_bounds__(256) void ckb_k(const float* __restrict__ ck,
                                             const void* __restrict__ in_w,
                                             const void* __restrict__ in_b,
                                             float* __restrict__ ckb,
                                             const int* __restrict__ flags) {
  const int fW = flags[47], fB = flags[48];
  int gw = blockIdx.x * 4 + (threadIdx.x >> 6);
  int a = gw / 768, f = gw % 768;
  int lane = threadIdx.x & 63;
  int e0 = lane * 4;
  float4 wv;
  size_t b = (size_t)a * 768 * E_ + (size_t)f * E_ + e0;
  if (fW) wv = *(const float4*)((const float*)in_w + b);
  else wv = make_float4(ldw(in_w, b, 0), ldw(in_w, b + 1, 0), ldw(in_w, b + 2, 0), ldw(in_w, b + 3, 0));
  const float4 cv = *(const float4*)(ck + a * E_ + e0);
  float s = wave_sum64(cv.x * wv.x + cv.y * wv.y + cv.z * wv.z + cv.w * wv.w);
  if (lane == 0) ckb[(size_t)a * 768 + f] = s + ldw(in_b, (size_t)a * 768 + f, fB);
}

// ======== MFMA class-block attention ========
#define LS 136
__device__ inline void stage64x128(const float* __restrict__ qkv, const int* __restrict__ myidx,
                                   int row0, int n, int ho, short* dst) {
  int t = threadIdx.x;
  int r = t >> 2, c0 = (t & 3) * 32;
  int rr = row0 + r;
  short tmp[32];
  if (rr < n) {
    const float* s = qkv + (size_t)myidx[rr] * 768 + ho + c0;
    #pragma unroll
    for (int q = 0; q < 8; ++q) {
      float4 v = *(const float4*)(s + q * 4);
      tmp[q*4+0] = f2bf(v.x); tmp[q*4+1] = f2bf(v.y);
      tmp[q*4+2] = f2bf(v.z); tmp[q*4+3] = f2bf(v.w);
    }
  } else {
    #pragma unroll
    for (int q = 0; q < 32; ++q) tmp[q] = 0;
  }
  s8v* d = (s8v*)&dst[r * LS + c0];
  #pragma unroll
  for (int q = 0; q < 4; ++q) d[q] = *(s8v*)&tmp[q*8];
}

__global__ __launch_bounds__(256) void attn_stats_k(
    const float* __restrict__ qkv_all, const int* __restrict__ idx,
    const int* __restrict__ cnt, const int* __restrict__ cstart,
    float* __restrict__ ml)
{
  int c = blockIdx.x, z = blockIdx.z, a = z >> 1, h = z & 1;
  int n = cnt[c];
  int r0 = blockIdx.y * 64;
  if (r0 >= n) return;
  const float* qkv = qkv_all + (size_t)a * NS_ * 768;
  const int* myidx = idx + c * NS_;
  __shared__ short Qs[64 * LS];
  __shared__ short Ks[64 * LS];
  __shared__ float Mw[4][64], Lw[4][64];
  int tid = threadIdx.x, lane = tid & 63, wid = tid >> 6;
  int lm = lane & 15, quad = lane >> 4;
  stage64x128(qkv, myidx, r0, n, h * 128, Qs);
  float m_run[16], l_run[16];
  #pragma unroll
  for (int i = 0; i < 16; ++i) { m_run[i] = -3e38f; l_run[i] = 0.f; }
  for (int j0 = 0; j0 < n; j0 += 64) {
    __syncthreads();
    stage64x128(qkv, myidx, j0, n, 256 + h * 128, Ks);
    __syncthreads();
    f4v acc[4];
    #pragma unroll
    for (int mi = 0; mi < 4; ++mi) acc[mi] = (f4v)(0.f);
    #pragma unroll
    for (int kc = 0; kc < 4; ++kc) {
      s8v bfr = *(const s8v*)&Ks[(wid * 16 + lm) * LS + kc * 32 + quad * 8];
      #pragma unroll
      for (int mi = 0; mi < 4; ++mi) {
        s8v af = *(const s8v*)&Qs[(mi * 16 + lm) * LS + kc * 32 + quad * 8];
        acc[mi] = __builtin_amdgcn_mfma_f32_16x16x32_bf16(af, bfr, acc[mi], 0, 0, 0);
      }
    }
    int col = j0 + wid * 16 + lm;
    bool cv = col < n;
    #pragma unroll
    for (int mi = 0; mi < 4; ++mi) {
      #pragma unroll
      for (int r = 0; r < 4; ++r) {
        float s = cv ? acc[mi][r] * QSCALE : -3e38f;
        float m = s;
        m = fmaxf(m, __shfl_xor(m, 1));
        m = fmaxf(m, __shfl_xor(m, 2));
        m = fmaxf(m, __shfl_xor(m, 4));
        m = fmaxf(m, __shfl_xor(m, 8));
        float p = cv ? __expf(s - m) : 0.f;
        p += __shfl_xor(p, 1); p += __shfl_xor(p, 2);
        p += __shfl_xor(p, 4); p += __shfl_xor(p, 8);
        int ri = mi * 4 + r;
        float mo = m_run[ri];
        float mn = fmaxf(mo, m);
        l_run[ri] = l_run[ri] * __expf(mo - mn) + p * __expf(m - mn);
        m_run[ri] = mn;
      }
    }
  }
  if (lm == 0) {
    #pragma unroll
    for (int mi = 0; mi < 4; ++mi)
      #pragma unroll
      for (int r = 0; r < 4; ++r) {
        int row = mi * 16 + quad * 4 + r;
        Mw[wid][row] = m_run[mi * 4 + r];
        Lw[wid][row] = l_run[mi * 4 + r];
      }
  }
  __syncthreads();
  if (tid < 64 && r0 + tid < n) {
    float m = fmaxf(fmaxf(Mw[0][tid], Mw[1][tid]), fmaxf(Mw[2][tid], Mw[3][tid]));
    float l = Lw[0][tid] * __expf(Mw[0][tid] - m) + Lw[1][tid] * __expf(Mw[1][tid] - m)
            + Lw[2][tid] * __expf(Mw[2][tid] - m) + Lw[3][tid] * __expf(Mw[3][tid] - m);
    size_t p = (size_t)z * NS_ + cstart[c] + r0 + tid;
    ml[p * 2] = m; ml[p * 2 + 1] = l;
  }
}

__global__ __launch_bounds__(256) void attn_colsum_k(
    const float* __restrict__ qkv_all, const int* __restrict__ idx,
    const int* __restrict__ cnt, const int* __restrict__ cstart,
    const float* __restrict__ ml, float* __restrict__ colsum)
{
  int c = blockIdx.x, z = blockIdx.z, a = z >> 1, h = z & 1;
  int n = cnt[c];
  int j0 = blockIdx.y * 64;
  if (j0 >= n) return;
  const float* qkv = qkv_all + (size_t)a * NS_ * 768;
  const int* myidx = idx + c * NS_;
  __shared__ short Qs[64 * LS];
  __shared__ short Ks[64 * LS];
  __shared__ float Msm[64], Lsm[64];
  int tid = threadIdx.x, lane = tid & 63, wid = tid >> 6;
  int lm = lane & 15, quad = lane >> 4;
  stage64x128(qkv, myidx, j0, n, 256 + h * 128, Ks);
  float ca = 0.f;
  for (int i0 = 0; i0 < n; i0 += 64) {
    __syncthreads();
    stage64x128(qkv, myidx, i0, n, h * 128, Qs);
    if (tid < 64) {
      int gi = i0 + tid;
      if (gi < n) {
        size_t p = (size_t)z * NS_ + cstart[c] + gi;
        Msm[tid] = ml[p * 2]; Lsm[tid] = ml[p * 2 + 1];
      } else { Msm[tid] = 0.f; Lsm[tid] = 1.f; }
    }
    __syncthreads();
    f4v acc[4];
    #pragma unroll
    for (int mi = 0; mi < 4; ++mi) acc[mi] = (f4v)(0.f);
    #pragma unroll
    for (int kc = 0; kc < 4; ++kc) {
      s8v bfr = *(const s8v*)&Ks[(wid * 16 + lm) * LS + kc * 32 + quad * 8];
      #pragma unroll
      for (int mi = 0; mi < 4; ++mi) {
        s8v af = *(const s8v*)&Qs[(mi * 16 + lm) * LS + kc * 32 + quad * 8];
        acc[mi] = __builtin_amdgcn_mfma_f32_16x16x32_bf16(af, bfr, acc[mi], 0, 0, 0);
      }
    }
    #pragma unroll
    for (int mi = 0; mi < 4; ++mi) {
      #pragma unroll
      for (int r = 0; r < 4; ++r) {
        int lrow = mi * 16 + quad * 4 + r;
        int gi = i0 + lrow;
        if (gi < n) {
          float m = Msm[lrow];
          float invl = 1.f / Lsm[lrow];
          ca += __expf(acc[mi][r] * QSCALE - m) * invl;
        }
      }
    }
  }
  ca += __shfl_xor(ca, 16);
  ca += __shfl_xor(ca, 32);
  int col = j0 + wid * 16 + lm;
  if (quad == 0 && col < n)
    colsum[(size_t)z * NS_ + cstart[c] + col] = ca;
}

__global__ void proto_combine_k(const float* __restrict__ qkv_all, const int* __restrict__ idx,
                                const int* __restrict__ cnt, const int* __restrict__ cstart,
                                const float* __restrict__ colsum, float* __restrict__ proto_pre) {
  int c = blockIdx.x, a = blockIdx.y;
  int e = threadIdx.x, h = e >> 7, d = e & 127;
  int n = cnt[c];
  const float* qkv = qkv_all + (size_t)a * NS_ * 768;
  const float* csum = colsum + (size_t)(a * 2 + h) * NS_ + cstart[c];
  const int* myidx = idx + c * NS_;
  float s = 0.f;
  for (int k = 0; k < n; ++k)
    s += csum[k] * qkv[(size_t)myidx[k] * 768 + 512 + h * 128 + d];
  proto_pre[((size_t)a * NWAY_ + c) * E_ + e] = (n > 0) ? s / (float)n : 0.f;
}

__global__ void proto_outproj_k(const float* __restrict__ proto_pre, const void* __restrict__ ow,
                                const void* __restrict__ ob, const int* __restrict__ cnt,
                                float* __restrict__ protos_all, const int* __restrict__ flags) {
  int c = blockIdx.x, a = blockIdx.y, e = threadIdx.x;
  const int fW = flags[49], fB = flags[50];
  __shared__ float pp[E_];
  pp[e] = proto_pre[((size_t)a * NWAY_ + c) * E_ + e];
  __syncthreads();
  size_t wb = (size_t)a * E_ * E_ + (size_t)e * E_;
  float s = 0.f;
  for (int k = 0; k < E_; ++k) s += pp[k] * ldw(ow, wb + k, fW);
  float v = s + ldw(ob, (size_t)a * E_ + e, fB);
  protos_all[((size_t)a * NWAY_ + c) * E_ + e] = (cnt[c] > 0) ? v : 0.f;
}

__global__ void bias2_k(const float* __restrict__ ck, const void* __restrict__ w1,
                        const void* __restrict__ b1, float* __restrict__ bias2_all,
                        const int* __restrict__ flags) {
  const int fW = flags[51], fB = flags[52];
  int a = blockIdx.x, n = threadIdx.x;
  __shared__ float c[E_];
  c[n] = ck[a * E_ + n]; __syncthreads();
  size_t wbase = (size_t)a * 2 * E_ * E_ + (size_t)E_ * E_ + n;
  float s = 0.f;
  for (int k = 0; k < E_; ++k) s += c[k] * ldw(w1, wbase + (size_t)k * E_, fW);
  bias2_all[a * E_ + n] = s + ldw(b1, (size_t)a * E_ + n, fB);
}

// ---------------- epilogues ----------------
__global__ __launch_bounds__(64) void logits_k(const float* __restrict__ fq, const float* __restrict__ protos,
                                               const float* __restrict__ c2, const void* __restrict__ w3,
                                               const void* __restrict__ b3, int a, float* __restrict__ out,
                                               const int* __restrict__ flags) {
  const int fW = flags[55], fB = flags[56];
  int i = blockIdx.x, lane = threadIdx.x;
  float4 xv = ((const float4*)(fq + (size_t)i * E_))[lane];
  float qq = wave_sum64(xv.x * xv.x + xv.y * xv.y + xv.z * xv.z + xv.w * xv.w);
  float cpart = c2[(size_t)i * 128 + lane * 2] * ldw(w3, (size_t)a * 128 + lane * 2, fW) +
                c2[(size_t)i * 128 + lane * 2 + 1] * ldw(w3, (size_t)a * 128 + lane * 2 + 1, fW);
  float conf = wave_sum64(cpart);
  if (lane == 0) conf += ldw(b3, a, fB);
  for (int c = 0; c < NWAY_; ++c) {
    float4 pv = ((const float4*)(protos + c * E_))[lane];
    float dt = wave_sum64(xv.x * pv.x + xv.y * pv.y + xv.z * pv.z + xv.w * pv.w);
    float pp = wave_sum64(pv.x * pv.x + pv.y * pv.y + pv.z * pv.z + pv.w * pv.w);
    if (lane == 0) {
      float d2 = fmaxf(qq + pp - 2.f * dt, 1e-12f);
      out[(size_t)i * NWAY_ + c] = -sqrtf(d2) + 0.1f * conf;
    }
  }
}

__global__ __launch_bounds__(64) void fused_k(const float* __restrict__ h2, const void* __restrict__ w3,
                                              const void* __restrict__ b3, float* __restrict__ out,
                                              const int* __restrict__ flags) {
  const int fW = flags[62], fB = flags[63];
  int i = blockIdx.x, lane = threadIdx.x;
  float s = h2[(size_t)i * 128 + lane * 2] * ldw(w3, lane * 2, fW) +
            h2[(size_t)i * 128 + lane * 2 + 1] * ldw(w3, lane * 2 + 1, fW);
  s = wave_sum64(s);
  if (lane == 0) out[i] = s + ldw(b3, 0, fB);
}

// ---------------- host ----------------
extern "C" void kernel_launch(void* const* d_in, const int* in_sizes, int n_in,
                              void* d_out, int out_size, void* d_ws, size_t ws_size,
                              hipStream_t stream) {
  (void)out_size; (void)ws_size;
  #define P(i) ((const void*)d_in[i])
  const int* support_y = (const int*)d_in[1];
  float* out = (float*)d_out;

  int* flags = (int*)d_ws;
  float* W = (float*)((char*)d_ws + 256);
  float* feats_s = W;                                    // A*NS*E
  float* feats_q = feats_s + (size_t)A_ * NS_ * E_;      // A*NQ*E
  float* R12     = feats_q + (size_t)A_ * NQ_ * E_;      // 10.49M floats
  const size_t R12_SZ = (size_t)A_ * NS_ * E_ + (size_t)A_ * NS_ * 768;
  float* t1 = R12;
  float* t2 = R12 + (size_t)NQ_ * 3 * E_;
  float* qkv_all = R12;                                  // A*NS*768 (7.86M)
  float* clsC_all = R12;                                 // A*NQ*256 (= full R12, after protos)

  float* smalls = R12 + R12_SZ;
  float* state      = smalls;
  float* msg        = state + A_ * E_;
  float* ck         = msg + A_ * E_;
  float* protos_all = ck + A_ * E_;
  float* bias2_all  = protos_all + A_ * NWAY_ * E_;
  float* ml         = bias2_all + A_ * E_;
  float* colsum     = ml + (size_t)A_ * 2 * NS_ * 2;
  float* proto_pre  = colsum + (size_t)A_ * 2 * NS_;
  int*   idx        = (int*)(proto_pre + A_ * NWAY_ * E_);
  int*   cnt        = idx + NWAY_ * NS_;
  int*   cstart     = cnt + NWAY_;
  float* statepart  = (float*)(cstart + NWAY_ + 3);   // A*16*E
  float* mvp        = statepart + A_ * 16 * E_;       // A*8*E
  float* qkvc       = mvp + A_ * 8 * E_;              // A*4*768
  float* obar       = qkvc + A_ * 4 * 768;            // A*E
  float* comb       = obar + A_ * E_;                 // A*E
  float* hh         = comb + A_ * E_;                 // A*E
  float* ckb        = hh + A_ * E_;                   // A*768

  Ptrs ps;
  for (int i = 0; i < 64; ++i) {
    ps.p[i] = (i < n_in) ? d_in[i] : nullptr;
    ps.sz[i] = (i < n_in) ? in_sizes[i] : 0;
  }
  probe_k<<<64, 64, 0, stream>>>(ps, flags);
  czero_k<<<1, 64, 0, stream>>>(cnt);
  cfill_k<<<NS_ / 256, 256, 0, stream>>>(support_y, idx, cnt);
  cstart_k<<<1, 64, 0, stream>>>(cnt, cstart);

  auto fe = [&](const void* x, int xi, int N, float* feats) {
    gemm<true, true, true, false, 0, false>(stream, x, 512, P(4), 512, 0, P(5), 0, t1, 512, N, 512, 512, 1.f, xi, 4, 5, flags);
    ln_k<1><<<N, 256, 0, stream>>>(t1, P(6), P(7), t1, 512, 6, 7, flags);
    gemm<false, true, true, false, 0, false>(stream, t1, 512, P(8), 256, 0, P(9), 0, t2, 256, N, 256, 512, 1.f, -1, 8, 9, flags);
    ln_k<1><<<N, 256, 0, stream>>>(t2, P(10), P(11), feats, 256, 10, 11, flags);
    gemm<true, true, true, false, 0, false>(stream, x, 512, P(12), 256, 0, P(13), 0, t2, 256, N, 256, 512, 1.f, xi, 12, 13, flags);
    ln_k<1><<<N, 256, 0, stream>>>(t2, P(14), P(15), t2, 256, 14, 15, flags);
    gemm<false, true, true, false, 2, false>(stream, t2, 256, P(16), 256, 0, P(17), 0, feats + (size_t)N * E_, 256, N, 256, 256, 1.f, -1, 16, 17, flags);
    gemm<true, true, true, false, 1, false>(stream, x, 512, P(18), 768, 0, P(19), 0, t1, 768, N, 768, 512, 1.f, xi, 18, 19, flags);
    gemm<false, true, true, false, 0, false>(stream, t1, 768, P(20), 256, 0, P(21), 0, t2, 256, N, 256, 768, 1.f, -1, 20, 21, flags);
    ln_k<1><<<N, 256, 0, stream>>>(t2, P(22), P(23), feats + (size_t)2 * N * E_, 256, 22, 23, flags);
    gemm<true, true, true, false, 1, false>(stream, x, 512, P(24), 256, 0, P(25), 0, t2, 256, N, 256, 512, 1.f, xi, 24, 25, flags);
    gemm<false, true, true, false, 0, false>(stream, t2, 256, P(26), 256, 0, P(27), 0, t1, 256, N, 256, 256, 1.f, -1, 26, 27, flags);
    ln_k<3><<<N, 256, 0, stream>>>(t1, P(28), P(29), feats + (size_t)3 * N * E_, 256, 28, 29, flags);
    gemm<true, true, true, false, 1, false>(stream, x, 512, P(30), 512, 0, P(31), 0, t1, 512, N, 512, 512, 1.f, xi, 30, 31, flags);
    gemm<false, true, true, false, 1, false>(stream, t1, 512, P(32), 256, 0, P(33), 0, t2, 256, N, 256, 512, 1.f, -1, 32, 33, flags);
    gemm<false, true, true, false, 0, false>(stream, t2, 256, P(34), 256, 0, P(35), 0, feats + (size_t)4 * N * E_, 256, N, 256, 256, 1.f, -1, 34, 35, flags);
  };
  fe(P(0), 0, NS_, feats_s);
  fe(P(2), 2, NQ_, feats_q);

  // ---- comm round ----
  statepart_k<<<dim3(A_, 16), 256, 0, stream>>>(feats_s, statepart);
  statecomb_k<<<A_, 256, 0, stream>>>(statepart, P(46), state, flags);
  mvpart_k<<<dim3(A_, 8), 256, 0, stream>>>(state, P(36), 36, mvp, flags);
  mvcomb_k<2><<<A_, 256, 0, stream>>>(mvp, P(37), 37, msg, flags);
  qkvcomm_k<<<A_ * 768 / 4, 256, 0, stream>>>(msg, P(57), P(38), P(39), qkvc, flags);
  attn4_k<<<A_, 256, 0, stream>>>(qkvc, obar);
  combproj_k<<<A_ * E_ / 4, 256, 0, stream>>>(obar, P(40), P(41), P(46), comb, flags);
  mvpart_k<<<dim3(A_, 8), 256, 0, stream>>>(comb, P(42), 42, mvp, flags);
  mvcomb_k<1><<<A_, 256, 0, stream>>>(mvp, P(43), 43, hh, flags);
  mvpart_k<<<dim3(A_, 8), 256, 0, stream>>>(hh, P(44), 44, mvp, flags);
  mvcomb_k<0><<<A_, 256, 0, stream>>>(mvp, P(45), 45, ck, flags);

  // ---- batched prototype attention (ck folded into qkv bias) ----
  ckb_k<<<A_ * 768 / 4, 256, 0, stream>>>(ck, P(47), P(48), ckb, flags);
  gemm<false, true, false, true, 0, false>(stream, feats_s, 256, P(47), 256, 0, ckb, 0,
                                           qkv_all, 768, NS_, 768, 256, 1.f, -1, 47, -1, flags,
                                           A_, (size_t)NS_ * E_, (size_t)3 * E_ * E_, (size_t)768,
                                           (size_t)NS_ * 768);
  {
    dim3 g(NWAY_, NS_ / 64, A_ * 2);
    attn_stats_k<<<g, 256, 0, stream>>>(qkv_all, idx, cnt, cstart, ml);
    attn_colsum_k<<<g, 256, 0, stream>>>(qkv_all, idx, cnt, cstart, ml, colsum);
  }
  proto_combine_k<<<dim3(NWAY_, A_), 256, 0, stream>>>(qkv_all, idx, cnt, cstart, colsum, proto_pre);
  proto_outproj_k<<<dim3(NWAY_, A_), 256, 0, stream>>>(proto_pre, P(49), P(50), cnt, protos_all, flags);
  bias2_k<<<A_, 256, 0, stream>>>(ck, P(51), P(52), bias2_all, flags);

  // ---- classifier: batched cls1, per-agent cls2 + logits ----
  gemm<false, true, false, false, 1, false>(stream, feats_q, 256, P(51), 256, 0, bias2_all, 0,
                                            clsC_all, 256, NQ_, 256, 256, 1.f, -1, 51, -1, flags,
                                            A_, (size_t)NQ_ * E_, (size_t)2 * E_ * E_, (size_t)E_,
                                            (size_t)NQ_ * 256);
  float* clsC2 = feats_s;   // feats_s free after qkv GEMM; NQ*128 fits
  for (int a = 0; a < A_; ++a) {
    gemm<false, true, true, false, 1, false>(stream, clsC_all + (size_t)a * NQ_ * 256, 256,
                                             P(53), 128, (size_t)a * E_ * 128,
                                             P(54), (size_t)a * 128, clsC2, 128, NQ_, 128, 256, 1.f, -1, 53, 54, flags);
    logits_k<<<NQ_, 64, 0, stream>>>(feats_q + (size_t)a * NQ_ * E_, protos_all + (size_t)a * NWAY_ * E_,
                                     clsC2, P(55), P(56), a, out + (size_t)a * NQ_ * NWAY_, flags);
  }

  // ---- fusion: single K-split GEMM over 5 agent blocks (K=1280) ----
  float* fh1 = R12;
  float* fh2 = R12 + (size_t)NQ_ * E_;
  gemm<false, true, true, false, 1, false, true>(stream, feats_q, 256, P(58), 256, 0, P(59), 0,
                                                 fh1, 256, NQ_, 256, 5 * E_, 1.f, -1, 58, 59, flags,
                                                 1, 0, 0, 0, 0, (size_t)NQ_ * E_);
  gemm<false, true, true, false, 1, false>(stream, fh1, 256, P(60), 128, 0, P(61), 0, fh2, 128, NQ_, 128, 256, 1.f, -1, 60, 61, flags);
  fused_k<<<NQ_, 64, 0, stream>>>(fh2, P(62), P(63), out + (size_t)A_ * NQ_ * NWAY_, flags);
}

// Round 8
// 1223.113 us; speedup vs baseline: 5.6564x; 1.4532x over previous
//
#include <hip/hip_runtime.h>
#include <hip/hip_bf16.h>

typedef __hip_bfloat16 bf16;
typedef short s8v __attribute__((ext_vector_type(8)));
typedef short s4v __attribute__((ext_vector_type(4)));
typedef float f4v __attribute__((ext_vector_type(4)));

#define A_  5
#define D_  512
#define E_  256
#define NS_ 2048
#define NQ_ 8192
#define NM_ 10240   // NS_ + NQ_ combined rows
#define NWAY_ 5
#define QSCALE 0.088388347648318447f
#define FSTR ((size_t)NM_ * E_)   // per-agent stride in featsC

__device__ inline float ldw(const void* p, size_t i, int f32) {
  return f32 ? ((const float*)p)[i] : __bfloat162float(((const bf16*)p)[i]);
}
template<bool DYN>
__device__ inline float ldT(const void* p, size_t i, int f32) {
  if (DYN) return ldw(p, i, f32);
  return ((const float*)p)[i];
}

__device__ inline short f2bf(float v) {
  union { float f; unsigned u; } x; x.f = v;
  unsigned r = x.u + 0x7fffu + ((x.u >> 16) & 1u);
  return (short)(r >> 16);
}

struct Ptrs { const void* p[64]; int sz[64]; };

__global__ void probe_k(Ptrs P, int* flags) {
  int b = blockIdx.x, lane = threadIdx.x;
  if (b == 1 || b == 3) { if (lane == 0) flags[b] = 0; return; }
  const bf16* t = (const bf16*)P.p[b];
  int n = P.sz[b];
  int K = (n >> 1) < 64 ? (n >> 1) : 64;
  bool big = false, eNZ = false, oNZ = false;
  if (lane < K) {
    float e = __bfloat162float(t[2 * lane]);
    float o = __bfloat162float(t[2 * lane + 1]);
    big = !(fabsf(e) <= 1e3f);
    eNZ = (e != 0.f); oNZ = (o != 0.f);
  }
  unsigned long long bb = __ballot(big), eb = __ballot(eNZ), ob = __ballot(oNZ);
  if (lane == 0) flags[b] = (bb != 0ull || (eb == 0ull && ob != 0ull)) ? 1 : 0;
}

// ---- class index lists in one kernel (order within class irrelevant) ----
__global__ void classidx_k(const int* __restrict__ y, int* __restrict__ idx,
                           int* __restrict__ cnt, int* __restrict__ cstart) {
  __shared__ int sc[NWAY_];
  int tid = threadIdx.x;
  if (tid < NWAY_) sc[tid] = 0;
  __syncthreads();
  for (int i = tid; i < NS_; i += 256) {
    int c = y[i];
    int pos = atomicAdd(&sc[c], 1);
    idx[c * NS_ + pos] = i;
  }
  __syncthreads();
  if (tid < NWAY_) cnt[tid] = sc[tid];
  if (tid == 0) { int s = 0; for (int q = 0; q < NWAY_; ++q) { cstart[q] = s; s += sc[q]; } }
}

// ---- stage support_x + query_x into one f32 buffer XC[NM_][512] ----
__global__ void xcopy_k(const void* __restrict__ sx, const void* __restrict__ qx,
                        float* __restrict__ XC, const int* __restrict__ flags) {
  size_t i = ((size_t)blockIdx.x * 256 + threadIdx.x) * 4;
  const size_t SN = (size_t)NS_ * 512;
  if (i < SN) {
    int f = flags[0];
    #pragma unroll
    for (int q = 0; q < 4; ++q) XC[i + q] = ldw(sx, i + q, f);
  } else {
    int f = flags[2];
    size_t j = i - SN;
    #pragma unroll
    for (int q = 0; q < 4; ++q) XC[i + q] = ldw(qx, j + q, f);
  }
}

// ============ MFMA bf16 GEMM ============
#define LSTR 40
template<bool DYNA, bool DYNB, bool DYNBIAS, bool TRB, int ACT, bool ACCUM,
         bool KSPLIT = false, bool OUTBF16 = false>
__global__ __launch_bounds__(256) void gemm_k(
    const void* __restrict__ A, int lda,
    const void* __restrict__ B, int ldb, size_t offB,
    const void* __restrict__ bias, size_t offBias,
    float* __restrict__ C, int ldc,
    int M, int N, int K, float alpha,
    int ia, int ib, int ibias, const int* __restrict__ flags,
    size_t sA, size_t sB, size_t sBias, size_t sC, size_t kstrideA)
{
  const int fA = DYNA ? flags[ia] : 1;
  const int fB = DYNB ? flags[ib] : 1;
  const int fBi = DYNBIAS ? flags[ibias] : 1;
  const size_t zA = (size_t)blockIdx.z * sA;
  const size_t zB = offB + (size_t)blockIdx.z * sB;
  const size_t zBias = offBias + (size_t)blockIdx.z * sBias;
  float* Cz = C + (size_t)blockIdx.z * sC;
  bf16* Cz16 = (bf16*)C + (size_t)blockIdx.z * sC;
  __shared__ short As[128 * LSTR];
  __shared__ short Bs[128 * LSTR];
  const int tid = threadIdx.x;
  const int bm = blockIdx.y * 128, bn = blockIdx.x * 128;
  const int lane = tid & 63, wid = tid >> 6;
  const int lm = lane & 15, quad = lane >> 4;
  const int wy = (wid >> 1) * 64, wx = (wid & 1) * 64;
  f4v acc[4][4];
  #pragma unroll
  for (int i = 0; i < 4; ++i)
    #pragma unroll
    for (int j = 0; j < 4; ++j) acc[i][j] = (f4v)(0.f);

  const int am = tid >> 1, ah = (tid & 1) * 16;

  for (int k0 = 0; k0 < K; k0 += 32) {
    {
      int kk = k0 + ah;
      size_t base;
      if (KSPLIT) base = zA + (size_t)(kk >> 8) * kstrideA + (size_t)(bm + am) * lda + (kk & 255);
      else base = zA + (size_t)(bm + am) * lda + kk;
      short tmp[16];
      if (fA) {
        const float4* src = (const float4*)((const float*)A + base);
        #pragma unroll
        for (int q = 0; q < 4; ++q) {
          float4 v = src[q];
          tmp[q*4+0] = f2bf(v.x); tmp[q*4+1] = f2bf(v.y);
          tmp[q*4+2] = f2bf(v.z); tmp[q*4+3] = f2bf(v.w);
        }
      } else {
        #pragma unroll
        for (int q = 0; q < 16; ++q) tmp[q] = f2bf(ldw(A, base + q, 0));
      }
      s4v* dst = (s4v*)&As[am * LSTR + ah];
      #pragma unroll
      for (int q = 0; q < 4; ++q) dst[q] = *(s4v*)&tmp[q*4];
    }
    if (TRB) {
      int n = tid >> 1, h = (tid & 1) * 16;
      size_t base = zB + (size_t)(bn + n) * ldb + k0 + h;
      short tmp[16];
      if (fB) {
        const float4* src = (const float4*)((const float*)B + base);
        #pragma unroll
        for (int q = 0; q < 4; ++q) {
          float4 v = src[q];
          tmp[q*4+0] = f2bf(v.x); tmp[q*4+1] = f2bf(v.y);
          tmp[q*4+2] = f2bf(v.z); tmp[q*4+3] = f2bf(v.w);
        }
      } else {
        #pragma unroll
        for (int q = 0; q < 16; ++q) tmp[q] = f2bf(ldw(B, base + q, 0));
      }
      s4v* dst = (s4v*)&Bs[n * LSTR + h];
      #pragma unroll
      for (int q = 0; q < 4; ++q) dst[q] = *(s4v*)&tmp[q*4];
    } else {
      int n = tid & 127, kk = (tid >> 7) * 16;
      short tmp[16];
      #pragma unroll
      for (int j = 0; j < 16; ++j)
        tmp[j] = f2bf(ldT<DYNB>(B, zB + (size_t)(k0 + kk + j) * ldb + bn + n, fB));
      s4v* dst = (s4v*)&Bs[n * LSTR + kk];
      #pragma unroll
      for (int q = 0; q < 4; ++q) dst[q] = *(s4v*)&tmp[q*4];
    }
    __syncthreads();
    s8v af[4], bfr[4];
    #pragma unroll
    for (int mi = 0; mi < 4; ++mi)
      af[mi] = *(const s8v*)&As[(wy + mi*16 + lm) * LSTR + quad * 8];
    #pragma unroll
    for (int ni = 0; ni < 4; ++ni)
      bfr[ni] = *(const s8v*)&Bs[(wx + ni*16 + lm) * LSTR + quad * 8];
    #pragma unroll
    for (int mi = 0; mi < 4; ++mi)
      #pragma unroll
      for (int ni = 0; ni < 4; ++ni)
        acc[mi][ni] = __builtin_amdgcn_mfma_f32_16x16x32_bf16(af[mi], bfr[ni], acc[mi][ni], 0, 0, 0);
    __syncthreads();
  }
  #pragma unroll
  for (int mi = 0; mi < 4; ++mi) {
    #pragma unroll
    for (int r = 0; r < 4; ++r) {
      int row = bm + wy + mi*16 + quad*4 + r;
      #pragma unroll
      for (int ni = 0; ni < 4; ++ni) {
        int col = bn + wx + ni*16 + lm;
        float v = acc[mi][ni][r] * alpha;
        if (ACCUM) v += Cz[(size_t)row * ldc + col];
        if (bias) v += ldT<DYNBIAS>(bias, zBias + col, fBi);
        if (ACT == 1) v = fmaxf(v, 0.f);
        else if (ACT == 2) v = tanhf(v);
        else if (ACT == 3) v = 1.f / (1.f + expf(-v));
        if (OUTBF16) Cz16[(size_t)row * ldc + col] = __float2bfloat16(v);
        else Cz[(size_t)row * ldc + col] = v;
      }
    }
  }
}

template<bool DYNA, bool DYNB, bool DYNBIAS, bool TRB, int ACT, bool ACCUM,
         bool KSPLIT = false, bool OUTBF16 = false>
static void gemm(hipStream_t s, const void* A, int lda, const void* B, int ldb, size_t offB,
                 const void* bias, size_t offBias, float* C, int ldc, int M, int N, int K,
                 float alpha, int ia, int ib, int ibias, const int* flags,
                 int batch = 1, size_t sA = 0, size_t sB = 0, size_t sBias = 0, size_t sC = 0,
                 size_t kstrideA = 0) {
  dim3 g(N / 128, M / 128, batch), b(256);
  gemm_k<DYNA, DYNB, DYNBIAS, TRB, ACT, ACCUM, KSPLIT, OUTBF16><<<g, b, 0, s>>>(
      A, lda, B, ldb, offB, bias, offBias, C, ldc, M, N, K, alpha, ia, ib, ibias, flags,
      sA, sB, sBias, sC, kstrideA);
}

// ---------------- LayerNorm (+relu/sigmoid) ----------------
template<int ACT>
__global__ __launch_bounds__(256) void ln_k(const float* __restrict__ X, const void* __restrict__ g,
                                            const void* __restrict__ be, float* __restrict__ Y, int W,
                                            int ig, int ibe, const int* __restrict__ flags) {
  const int fG = flags[ig], fBe = flags[ibe];
  int row = blockIdx.x;
  const float* x = X + (size_t)row * W;
  float* y = Y + (size_t)row * W;
  __shared__ float red[256];
  int tid = threadIdx.x;
  float s1 = 0.f, s2 = 0.f;
  for (int i = tid; i < W; i += 256) { float v = x[i]; s1 += v; s2 += v * v; }
  red[tid] = s1; __syncthreads();
  for (int o = 128; o > 0; o >>= 1) { if (tid < o) red[tid] += red[tid + o]; __syncthreads(); }
  float mean = red[0] / W; __syncthreads();
  red[tid] = s2; __syncthreads();
  for (int o = 128; o > 0; o >>= 1) { if (tid < o) red[tid] += red[tid + o]; __syncthreads(); }
  float var = fmaxf(red[0] / W - mean * mean, 0.f);
  float rstd = rsqrtf(var + 1e-5f);
  for (int i = tid; i < W; i += 256) {
    float v = (x[i] - mean) * rstd * ldw(g, i, fG) + ldw(be, i, fBe);
    if (ACT == 1) v = fmaxf(v, 0.f);
    else if (ACT == 3) v = 1.f / (1.f + expf(-v));
    y[i] = v;
  }
}

// ================= comm round =================
__global__ void statepart_k(const float* __restrict__ featsC, float* __restrict__ part) {
  int a = blockIdx.x, g = blockIdx.y, e = threadIdx.x;
  const float* p = featsC + (size_t)a * FSTR + ((size_t)g * 128) * E_ + e;
  float s = 0.f;
  for (int n = 0; n < 128; ++n) s += p[(size_t)n * E_];
  part[((size_t)a * 16 + g) * E_ + e] = s;
}

__global__ void statecomb_k(const float* __restrict__ part, const void* __restrict__ internal,
                            float* __restrict__ state, const int* __restrict__ flags) {
  int a = blockIdx.x, e = threadIdx.x;
  float s = 0.f;
  for (int g = 0; g < 16; ++g) s += part[((size_t)a * 16 + g) * E_ + e];
  state[a * E_ + e] = s * (1.f / NS_) + ldw(internal, (size_t)a * E_ + e, flags[46]);
}

__global__ void mvpart_k(const float* __restrict__ x, const void* __restrict__ W, int iw,
                         float* __restrict__ part, const int* __restrict__ flags) {
  int a = blockIdx.x, g = blockIdx.y, f = threadIdx.x;
  const int fW = flags[iw];
  float s = 0.f;
  size_t wb = (size_t)a * E_ * E_ + f;
  for (int e = g * 32; e < g * 32 + 32; ++e)
    s += x[a * E_ + e] * ldw(W, wb + (size_t)e * E_, fW);
  part[((size_t)a * 8 + g) * E_ + f] = s;
}

template<int ACT>
__global__ void mvcomb_k(const float* __restrict__ part, const void* __restrict__ b, int ibb,
                         float* __restrict__ y, const int* __restrict__ flags) {
  int a = blockIdx.x, f = threadIdx.x;
  float s = 0.f;
  for (int g = 0; g < 8; ++g) s += part[((size_t)a * 8 + g) * E_ + f];
  s += ldw(b, (size_t)a * E_ + f, flags[ibb]);
  if (ACT == 1) s = fmaxf(s, 0.f);
  else if (ACT == 2) s = tanhf(s);
  y[a * E_ + f] = s;
}

__device__ inline float wave_sum64(float v) {
  for (int o = 32; o > 0; o >>= 1) v += __shfl_down(v, o);
  return v;
}

__global__ __launch_bounds__(256) void qkvcomm_k(const float* __restrict__ msg,
                                                 const void* __restrict__ comm_w,
                                                 const void* __restrict__ in_w,
                                                 const void* __restrict__ in_b,
                                                 float* __restrict__ qkvc,
                                                 const int* __restrict__ flags) {
  const int fCW = flags[57], fIW = flags[38], fIB = flags[39];
  int gw = blockIdx.x * 4 + (threadIdx.x >> 6);
  int a = gw / 768, f = gw % 768;
  int lane = threadIdx.x & 63;
  float w[5]; float mx = -1e30f;
  for (int j = 0; j < 5; ++j) { w[j] = ldw(comm_w, a * 5 + j, fCW); mx = fmaxf(mx, w[j]); }
  float sum = 0.f;
  for (int j = 0; j < 5; ++j) { w[j] = __expf(w[j] - mx); sum += w[j]; }
  for (int j = 0; j < 5; ++j) w[j] /= sum;
  int others[4]; { int c = 0; for (int j = 0; j < 5; ++j) if (j != a) others[c++] = j; }
  int e0 = lane * 4;
  float4 wv;
  size_t b = (size_t)a * 768 * E_ + (size_t)f * E_ + e0;
  if (fIW) wv = *(const float4*)((const float*)in_w + b);
  else wv = make_float4(ldw(in_w, b, 0), ldw(in_w, b + 1, 0), ldw(in_w, b + 2, 0), ldw(in_w, b + 3, 0));
  float acc[4];
  #pragma unroll
  for (int t = 0; t < 4; ++t) {
    const float4 mv = *(const float4*)(msg + others[t] * E_ + e0);
    acc[t] = mv.x * wv.x + mv.y * wv.y + mv.z * wv.z + mv.w * wv.w;
  }
  #pragma unroll
  for (int t = 0; t < 4; ++t) acc[t] = wave_sum64(acc[t]);
  if (lane == 0) {
    float bb = ldw(in_b, (size_t)a * 768 + f, fIB);
    #pragma unroll
    for (int t = 0; t < 4; ++t)
      qkvc[((size_t)a * 4 + t) * 768 + f] = acc[t] * w[others[t]] + bb;
  }
}

__global__ __launch_bounds__(256) void attn4_k(const float* __restrict__ qkvc,
                                               float* __restrict__ obar) {
  int a = blockIdx.x, tid = threadIdx.x;
  __shared__ float qkv[4][768];
  __shared__ float attw[4][16];
  for (int i = tid; i < 4 * 768; i += 256) qkv[i / 768][i % 768] = qkvc[(size_t)a * 4 * 768 + i];
  __syncthreads();
  if (tid < 16) {
    int h = tid >> 2, t = tid & 3;
    float sc[4]; float mx = -1e30f;
    for (int t2 = 0; t2 < 4; ++t2) {
      float s = 0.f;
      for (int d = 0; d < 64; ++d) s += qkv[t][h * 64 + d] * qkv[t2][256 + h * 64 + d];
      sc[t2] = s * 0.125f; mx = fmaxf(mx, sc[t2]);
    }
    float ss = 0.f;
    for (int t2 = 0; t2 < 4; ++t2) { sc[t2] = __expf(sc[t2] - mx); ss += sc[t2]; }
    for (int t2 = 0; t2 < 4; ++t2) attw[h][t * 4 + t2] = sc[t2] / ss;
  }
  __syncthreads();
  {
    int e = tid, h = e >> 6;
    float s = 0.f;
    for (int t = 0; t < 4; ++t)
      for (int t2 = 0; t2 < 4; ++t2)
        s += attw[h][t * 4 + t2] * qkv[t2][512 + e];
    obar[a * E_ + e] = s * 0.25f;
  }
}

__global__ __launch_bounds__(256) void combproj_k(const float* __restrict__ obar,
                                                  const void* __restrict__ ow,
                                                  const void* __restrict__ ob,
                                                  const void* __restrict__ internal,
                                                  float* __restrict__ comb,
                                                  const int* __restrict__ flags) {
  const int fOW = flags[40], fOB = flags[41], fIN = flags[46];
  int gw = blockIdx.x * 4 + (threadIdx.x >> 6);
  int a = gw >> 8, f = gw & 255;
  int lane = threadIdx.x & 63;
  int e0 = lane * 4;
  float4 wv;
  size_t b = (size_t)a * E_ * E_ + (size_t)f * E_ + e0;
  if (fOW) wv = *(const float4*)((const float*)ow + b);
  else wv = make_float4(ldw(ow, b, 0), ldw(ow, b + 1, 0), ldw(ow, b + 2, 0), ldw(ow, b + 3, 0));
  const float4 ov = *(const float4*)(obar + a * E_ + e0);
  float s = wave_sum64(ov.x * wv.x + ov.y * wv.y + ov.z * wv.z + ov.w * wv.w);
  if (lane == 0)
    comb[a * E_ + f] = ldw(internal, (size_t)a * E_ + f, fIN) + s + ldw(ob, (size_t)a * E_ + f, fOB);
}

__global__ __launch_bounds__(256) void ckb_k(const float* __restrict__ ck,
                                             const void* __restrict__ in_w,
                                             const void* __restrict__ in_b,
                                             float* __restrict__ ckb,
                                             const int* __restrict__ flags) {
  const int fW = flags[47], fB = flags[48];
  int gw = blockIdx.x * 4 + (threadIdx.x >> 6);
  int a = gw / 768, f = gw % 768;
  int lane = threadIdx.x & 63;
  int e0 = lane * 4;
  float4 wv;
  size_t b = (size_t)a * 768 * E_ + (size_t)f * E_ + e0;
  if (fW) wv = *(const float4*)((const float*)in_w + b);
  else wv = make_float4(ldw(in_w, b, 0), ldw(in_w, b + 1, 0), ldw(in_w, b + 2, 0), ldw(in_w, b + 3, 0));
  const float4 cv = *(const float4*)(ck + a * E_ + e0);
  float s = wave_sum64(cv.x * wv.x + cv.y * wv.y + cv.z * wv.z + cv.w * wv.w);
  if (lane == 0) ckb[(size_t)a * 768 + f] = s + ldw(in_b, (size_t)a * 768 + f, fB);
}

// ======== MFMA class-block attention ========
#define LS 136
__device__ inline void stage64x128(const float* __restrict__ qkv, const int* __restrict__ myidx,
                                   int row0, int n, int ho, short* dst) {
  int t = threadIdx.x;
  int r = t >> 2, c0 = (t & 3) * 32;
  int rr = row0 + r;
  short tmp[32];
  if (rr < n) {
    const float* s = qkv + (size_t)myidx[rr] * 768 + ho + c0;
    #pragma unroll
    for (int q = 0; q < 8; ++q) {
      float4 v = *(const float4*)(s + q * 4);
      tmp[q*4+0] = f2bf(v.x); tmp[q*4+1] = f2bf(v.y);
      tmp[q*4+2] = f2bf(v.z); tmp[q*4+3] = f2bf(v.w);
    }
  } else {
    #pragma unroll
    for (int q = 0; q < 32; ++q) tmp[q] = 0;
  }
  s8v* d = (s8v*)&dst[r * LS + c0];
  #pragma unroll
  for (int q = 0; q < 4; ++q) d[q] = *(s8v*)&tmp[q*8];
}

__global__ __launch_bounds__(256) void attn_stats_k(
    const float* __restrict__ qkv_all, const int* __restrict__ idx,
    const int* __restrict__ cnt, const int* __restrict__ cstart,
    float* __restrict__ ml)
{
  int c = blockIdx.x, z = blockIdx.z, a = z >> 1, h = z & 1;
  int n = cnt[c];
  int r0 = blockIdx.y * 64;
  if (r0 >= n) return;
  const float* qkv = qkv_all + (size_t)a * NS_ * 768;
  const int* myidx = idx + c * NS_;
  __shared__ short Qs[64 * LS];
  __shared__ short Ks[64 * LS];
  __shared__ float Mw[4][64], Lw[4][64];
  int tid = threadIdx.x, lane = tid & 63, wid = tid >> 6;
  int lm = lane & 15, quad = lane >> 4;
  stage64x128(qkv, myidx, r0, n, h * 128, Qs);
  float m_run[16], l_run[16];
  #pragma unroll
  for (int i = 0; i < 16; ++i) { m_run[i] = -3e38f; l_run[i] = 0.f; }
  for (int j0 = 0; j0 < n; j0 += 64) {
    __syncthreads();
    stage64x128(qkv, myidx, j0, n, 256 + h * 128, Ks);
    __syncthreads();
    f4v acc[4];
    #pragma unroll
    for (int mi = 0; mi < 4; ++mi) acc[mi] = (f4v)(0.f);
    #pragma unroll
    for (int kc = 0; kc < 4; ++kc) {
      s8v bfr = *(const s8v*)&Ks[(wid * 16 + lm) * LS + kc * 32 + quad * 8];
      #pragma unroll
      for (int mi = 0; mi < 4; ++mi) {
        s8v af = *(const s8v*)&Qs[(mi * 16 + lm) * LS + kc * 32 + quad * 8];
        acc[mi] = __builtin_amdgcn_mfma_f32_16x16x32_bf16(af, bfr, acc[mi], 0, 0, 0);
      }
    }
    int col = j0 + wid * 16 + lm;
    bool cv = col < n;
    #pragma unroll
    for (int mi = 0; mi < 4; ++mi) {
      #pragma unroll
      for (int r = 0; r < 4; ++r) {
        float s = cv ? acc[mi][r] * QSCALE : -3e38f;
        float m = s;
        m = fmaxf(m, __shfl_xor(m, 1));
        m = fmaxf(m, __shfl_xor(m, 2));
        m = fmaxf(m, __shfl_xor(m, 4));
        m = fmaxf(m, __shfl_xor(m, 8));
        float p = cv ? __expf(s - m) : 0.f;
        p += __shfl_xor(p, 1); p += __shfl_xor(p, 2);
        p += __shfl_xor(p, 4); p += __shfl_xor(p, 8);
        int ri = mi * 4 + r;
        float mo = m_run[ri];
        float mn = fmaxf(mo, m);
        l_run[ri] = l_run[ri] * __expf(mo - mn) + p * __expf(m - mn);
        m_run[ri] = mn;
      }
    }
  }
  if (lm == 0) {
    #pragma unroll
    for (int mi = 0; mi < 4; ++mi)
      #pragma unroll
      for (int r = 0; r < 4; ++r) {
        int row = mi * 16 + quad * 4 + r;
        Mw[wid][row] = m_run[mi * 4 + r];
        Lw[wid][row] = l_run[mi * 4 + r];
      }
  }
  __syncthreads();
  if (tid < 64 && r0 + tid < n) {
    float m = fmaxf(fmaxf(Mw[0][tid], Mw[1][tid]), fmaxf(Mw[2][tid], Mw[3][tid]));
    float l = Lw[0][tid] * __expf(Mw[0][tid] - m) + Lw[1][tid] * __expf(Mw[1][tid] - m)
            + Lw[2][tid] * __expf(Mw[2][tid] - m) + Lw[3][tid] * __expf(Mw[3][tid] - m);
    size_t p = (size_t)z * NS_ + cstart[c] + r0 + tid;
    ml[p * 2] = m; ml[p * 2 + 1] = l;
  }
}

__global__ __launch_bounds__(256) void attn_colsum_k(
    const float* __restrict__ qkv_all, const int* __restrict__ idx,
    const int* __restrict__ cnt, const int* __restrict__ cstart,
    const float* __restrict__ ml, float* __restrict__ colsum)
{
  int c = blockIdx.x, z = blockIdx.z, a = z >> 1, h = z & 1;
  int n = cnt[c];
  int j0 = blockIdx.y * 64;
  if (j0 >= n) return;
  const float* qkv = qkv_all + (size_t)a * NS_ * 768;
  const int* myidx = idx + c * NS_;
  __shared__ short Qs[64 * LS];
  __shared__ short Ks[64 * LS];
  __shared__ float Msm[64], Lsm[64];
  int tid = threadIdx.x, lane = tid & 63, wid = tid >> 6;
  int lm = lane & 15, quad = lane >> 4;
  stage64x128(qkv, myidx, j0, n, 256 + h * 128, Ks);
  float ca = 0.f;
  for (int i0 = 0; i0 < n; i0 += 64) {
    __syncthreads();
    stage64x128(qkv, myidx, i0, n, h * 128, Qs);
    if (tid < 64) {
      int gi = i0 + tid;
      if (gi < n) {
        size_t p = (size_t)z * NS_ + cstart[c] + gi;
        Msm[tid] = ml[p * 2]; Lsm[tid] = ml[p * 2 + 1];
      } else { Msm[tid] = 0.f; Lsm[tid] = 1.f; }
    }
    __syncthreads();
    f4v acc[4];
    #pragma unroll
    for (int mi = 0; mi < 4; ++mi) acc[mi] = (f4v)(0.f);
    #pragma unroll
    for (int kc = 0; kc < 4; ++kc) {
      s8v bfr = *(const s8v*)&Ks[(wid * 16 + lm) * LS + kc * 32 + quad * 8];
      #pragma unroll
      for (int mi = 0; mi < 4; ++mi) {
        s8v af = *(const s8v*)&Qs[(mi * 16 + lm) * LS + kc * 32 + quad * 8];
        acc[mi] = __builtin_amdgcn_mfma_f32_16x16x32_bf16(af, bfr, acc[mi], 0, 0, 0);
      }
    }
    #pragma unroll
    for (int mi = 0; mi < 4; ++mi) {
      #pragma unroll
      for (int r = 0; r < 4; ++r) {
        int lrow = mi * 16 + quad * 4 + r;
        int gi = i0 + lrow;
        if (gi < n) {
          float m = Msm[lrow];
          float invl = 1.f / Lsm[lrow];
          ca += __expf(acc[mi][r] * QSCALE - m) * invl;
        }
      }
    }
  }
  ca += __shfl_xor(ca, 16);
  ca += __shfl_xor(ca, 32);
  int col = j0 + wid * 16 + lm;
  if (quad == 0 && col < n)
    colsum[(size_t)z * NS_ + cstart[c] + col] = ca;
}

// ---- proto combine: K-chunked 2-stage ----
#define PCH 8
__global__ void proto_part_k(const float* __restrict__ qkv_all, const int* __restrict__ idx,
                             const int* __restrict__ cnt, const int* __restrict__ cstart,
                             const float* __restrict__ colsum, float* __restrict__ part) {
  int c = blockIdx.x, a = blockIdx.y, ch = blockIdx.z;
  int e = threadIdx.x, h = e >> 7, d = e & 127;
  int n = cnt[c];
  int k0 = ch * 256, k1 = min(k0 + 256, n);
  float s = 0.f;
  const float* qkv = qkv_all + (size_t)a * NS_ * 768;
  const float* csum = colsum + (size_t)(a * 2 + h) * NS_ + cstart[c];
  const int* myidx = idx + c * NS_;
  for (int k = k0; k < k1; ++k)
    s += csum[k] * qkv[(size_t)myidx[k] * 768 + 512 + h * 128 + d];
  part[(((size_t)a * NWAY_ + c) * PCH + ch) * E_ + e] = s;
}

__global__ void proto_comb2_k(const float* __restrict__ part, const int* __restrict__ cnt,
                              float* __restrict__ proto_pre) {
  int c = blockIdx.x, a = blockIdx.y, e = threadIdx.x;
  int n = cnt[c];
  float s = 0.f;
  for (int ch = 0; ch < PCH; ++ch)
    s += part[(((size_t)a * NWAY_ + c) * PCH + ch) * E_ + e];
  proto_pre[((size_t)a * NWAY_ + c) * E_ + e] = (n > 0) ? s / (float)n : 0.f;
}

__global__ void proto_outproj_k(const float* __restrict__ proto_pre, const void* __restrict__ ow,
                                const void* __restrict__ ob, const int* __restrict__ cnt,
                                float* __restrict__ protos_all, const int* __restrict__ flags) {
  int c = blockIdx.x, a = blockIdx.y, e = threadIdx.x;
  const int fW = flags[49], fB = flags[50];
  __shared__ float pp[E_];
  pp[e] = proto_pre[((size_t)a * NWAY_ + c) * E_ + e];
  __syncthreads();
  size_t wb = (size_t)a * E_ * E_ + (size_t)e * E_;
  float s = 0.f;
  for (int k = 0; k < E_; ++k) s += pp[k] * ldw(ow, wb + k, fW);
  float v = s + ldw(ob, (size_t)a * E_ + e, fB);
  protos_all[((size_t)a * NWAY_ + c) * E_ + e] = (cnt[c] > 0) ? v : 0.f;
}

__global__ void bias2_k(const float* __restrict__ ck, const void* __restrict__ w1,
                        const void* __restrict__ b1, float* __restrict__ bias2_all,
                        const int* __restrict__ flags) {
  const int fW = flags[51], fB = flags[52];
  int a = blockIdx.x, n = threadIdx.x;
  __shared__ float c[E_];
  c[n] = ck[a * E_ + n]; __syncthreads();
  size_t wbase = (size_t)a * 2 * E_ * E_ + (size_t)E_ * E_ + n;
  float s = 0.f;
  for (int k = 0; k < E_; ++k) s += c[k] * ldw(w1, wbase + (size_t)k * E_, fW);
  bias2_all[a * E_ + n] = s + ldw(b1, (size_t)a * E_ + n, fB);
}

// ---------------- epilogues ----------------
__global__ __launch_bounds__(64) void logits_k(const float* __restrict__ fqbase,
                                               const float* __restrict__ protos_all,
                                               const bf16* __restrict__ c2all,
                                               const void* __restrict__ w3,
                                               const void* __restrict__ b3,
                                               float* __restrict__ out,
                                               const int* __restrict__ flags) {
  const int fW = flags[55], fB = flags[56];
  int i = blockIdx.x, a = blockIdx.y, lane = threadIdx.x;
  const float* fq = fqbase + (size_t)a * FSTR;
  const float* protos = protos_all + (size_t)a * NWAY_ * E_;
  const bf16* c2 = c2all + ((size_t)a * NQ_ + i) * 128;
  float4 xv = ((const float4*)(fq + (size_t)i * E_))[lane];
  float qq = wave_sum64(xv.x * xv.x + xv.y * xv.y + xv.z * xv.z + xv.w * xv.w);
  float cpart = __bfloat162float(c2[lane * 2]) * ldw(w3, (size_t)a * 128 + lane * 2, fW) +
                __bfloat162float(c2[lane * 2 + 1]) * ldw(w3, (size_t)a * 128 + lane * 2 + 1, fW);
  float conf = wave_sum64(cpart);
  if (lane == 0) conf += ldw(b3, a, fB);
  for (int c = 0; c < NWAY_; ++c) {
    float4 pv = ((const float4*)(protos + c * E_))[lane];
    float dt = wave_sum64(xv.x * pv.x + xv.y * pv.y + xv.z * pv.z + xv.w * pv.w);
    float pp = wave_sum64(pv.x * pv.x + pv.y * pv.y + pv.z * pv.z + pv.w * pv.w);
    if (lane == 0) {
      float d2 = fmaxf(qq + pp - 2.f * dt, 1e-12f);
      out[((size_t)a * NQ_ + i) * NWAY_ + c] = -sqrtf(d2) + 0.1f * conf;
    }
  }
}

__global__ __launch_bounds__(64) void fused_k(const float* __restrict__ h2, const void* __restrict__ w3,
                                              const void* __restrict__ b3, float* __restrict__ out,
                                              const int* __restrict__ flags) {
  const int fW = flags[62], fB = flags[63];
  int i = blockIdx.x, lane = threadIdx.x;
  float s = h2[(size_t)i * 128 + lane * 2] * ldw(w3, lane * 2, fW) +
            h2[(size_t)i * 128 + lane * 2 + 1] * ldw(w3, lane * 2 + 1, fW);
  s = wave_sum64(s);
  if (lane == 0) out[i] = s + ldw(b3, 0, fB);
}

// ---------------- host ----------------
extern "C" void kernel_launch(void* const* d_in, const int* in_sizes, int n_in,
                              void* d_out, int out_size, void* d_ws, size_t ws_size,
                              hipStream_t stream) {
  (void)out_size; (void)ws_size;
  #define P(i) ((const void*)d_in[i])
  const int* support_y = (const int*)d_in[1];
  float* out = (float*)d_out;

  int* flags = (int*)d_ws;
  float* W = (float*)((char*)d_ws + 256);
  float* featsC = W;                                     // A × NM_ × E  (13.1M)
  float* R12    = featsC + (size_t)A_ * FSTR;            // 10.49M floats
  float* t1 = R12;                                       // NM_*768 = 7.86M
  float* t2 = R12 + (size_t)NM_ * 3 * E_;                // NM_*256 = 2.62M
  float* qkv_all = R12;                                  // A*NS*768 = 7.86M
  float* clsC_all = R12;                                 // A*NQ*256 = 10.49M

  float* smalls = R12 + (size_t)NM_ * 4 * E_;            // after t1+t2 (10.49M)
  float* state      = smalls;
  float* msg        = state + A_ * E_;
  float* ck         = msg + A_ * E_;
  float* protos_all = ck + A_ * E_;
  float* bias2_all  = protos_all + A_ * NWAY_ * E_;
  float* ml         = bias2_all + A_ * E_;
  float* colsum     = ml + (size_t)A_ * 2 * NS_ * 2;
  float* proto_pre  = colsum + (size_t)A_ * 2 * NS_;
  int*   idx        = (int*)(proto_pre + A_ * NWAY_ * E_);
  int*   cnt        = idx + NWAY_ * NS_;
  int*   cstart     = cnt + NWAY_;
  float* statepart  = (float*)(cstart + NWAY_ + 3);   // A*16*E
  float* mvp        = statepart + A_ * 16 * E_;       // A*8*E
  float* qkvc       = mvp + A_ * 8 * E_;              // A*4*768
  float* obar       = qkvc + A_ * 4 * 768;            // A*E
  float* comb       = obar + A_ * E_;                 // A*E
  float* hh         = comb + A_ * E_;                 // A*E
  float* ckb        = hh + A_ * E_;                   // A*768
  float* ppart      = ckb + A_ * 768;                 // A*NWAY*PCH*E = 51200
  float* XC         = ppart + (size_t)A_ * NWAY_ * PCH * E_;  // NM_*512 = 5.24M
  bf16*  clsC2_all  = (bf16*)XC;                      // A*NQ*128 bf16 (reuse after FE)

  const float* fq_base = featsC + (size_t)NS_ * E_;   // query rows within featsC

  Ptrs ps;
  for (int i = 0; i < 64; ++i) {
    ps.p[i] = (i < n_in) ? d_in[i] : nullptr;
    ps.sz[i] = (i < n_in) ? in_sizes[i] : 0;
  }
  probe_k<<<64, 64, 0, stream>>>(ps, flags);
  classidx_k<<<1, 256, 0, stream>>>(support_y, idx, cnt, cstart);
  xcopy_k<<<(NM_ * 512 / 4) / 256, 256, 0, stream>>>(P(0), P(2), XC, flags);

  // ---- feature extractors, support+query in one pass (M = 10240) ----
  {
    const int N = NM_;
    gemm<false, true, true, false, 0, false>(stream, XC, 512, P(4), 512, 0, P(5), 0, t1, 512, N, 512, 512, 1.f, -1, 4, 5, flags);
    ln_k<1><<<N, 256, 0, stream>>>(t1, P(6), P(7), t1, 512, 6, 7, flags);
    gemm<false, true, true, false, 0, false>(stream, t1, 512, P(8), 256, 0, P(9), 0, t2, 256, N, 256, 512, 1.f, -1, 8, 9, flags);
    ln_k<1><<<N, 256, 0, stream>>>(t2, P(10), P(11), featsC, 256, 10, 11, flags);
    gemm<false, true, true, false, 0, false>(stream, XC, 512, P(12), 256, 0, P(13), 0, t2, 256, N, 256, 512, 1.f, -1, 12, 13, flags);
    ln_k<1><<<N, 256, 0, stream>>>(t2, P(14), P(15), t2, 256, 14, 15, flags);
    gemm<false, true, true, false, 2, false>(stream, t2, 256, P(16), 256, 0, P(17), 0, featsC + FSTR, 256, N, 256, 256, 1.f, -1, 16, 17, flags);
    gemm<false, true, true, false, 1, false>(stream, XC, 512, P(18), 768, 0, P(19), 0, t1, 768, N, 768, 512, 1.f, -1, 18, 19, flags);
    gemm<false, true, true, false, 0, false>(stream, t1, 768, P(20), 256, 0, P(21), 0, t2, 256, N, 256, 768, 1.f, -1, 20, 21, flags);
    ln_k<1><<<N, 256, 0, stream>>>(t2, P(22), P(23), featsC + 2 * FSTR, 256, 22, 23, flags);
    gemm<false, true, true, false, 1, false>(stream, XC, 512, P(24), 256, 0, P(25), 0, t2, 256, N, 256, 512, 1.f, -1, 24, 25, flags);
    gemm<false, true, true, false, 0, false>(stream, t2, 256, P(26), 256, 0, P(27), 0, t1, 256, N, 256, 256, 1.f, -1, 26, 27, flags);
    ln_k<3><<<N, 256, 0, stream>>>(t1, P(28), P(29), featsC + 3 * FSTR, 256, 28, 29, flags);
    gemm<false, true, true, false, 1, false>(stream, XC, 512, P(30), 512, 0, P(31), 0, t1, 512, N, 512, 512, 1.f, -1, 30, 31, flags);
    gemm<false, true, true, false, 1, false>(stream, t1, 512, P(32), 256, 0, P(33), 0, t2, 256, N, 256, 512, 1.f, -1, 32, 33, flags);
    gemm<false, true, true, false, 0, false>(stream, t2, 256, P(34), 256, 0, P(35), 0, featsC + 4 * FSTR, 256, N, 256, 256, 1.f, -1, 34, 35, flags);
  }

  // ---- comm round ----
  statepart_k<<<dim3(A_, 16), 256, 0, stream>>>(featsC, statepart);
  statecomb_k<<<A_, 256, 0, stream>>>(statepart, P(46), state, flags);
  mvpart_k<<<dim3(A_, 8), 256, 0, stream>>>(state, P(36), 36, mvp, flags);
  mvcomb_k<2><<<A_, 256, 0, stream>>>(mvp, P(37), 37, msg, flags);
  qkvcomm_k<<<A_ * 768 / 4, 256, 0, stream>>>(msg, P(57), P(38), P(39), qkvc, flags);
  attn4_k<<<A_, 256, 0, stream>>>(qkvc, obar);
  combproj_k<<<A_ * E_ / 4, 256, 0, stream>>>(obar, P(40), P(41), P(46), comb, flags);
  mvpart_k<<<dim3(A_, 8), 256, 0, stream>>>(comb, P(42), 42, mvp, flags);
  mvcomb_k<1><<<A_, 256, 0, stream>>>(mvp, P(43), 43, hh, flags);
  mvpart_k<<<dim3(A_, 8), 256, 0, stream>>>(hh, P(44), 44, mvp, flags);
  mvcomb_k<0><<<A_, 256, 0, stream>>>(mvp, P(45), 45, ck, flags);

  // ---- batched prototype attention (ck folded into qkv bias) ----
  ckb_k<<<A_ * 768 / 4, 256, 0, stream>>>(ck, P(47), P(48), ckb, flags);
  gemm<false, true, false, true, 0, false>(stream, featsC, 256, P(47), 256, 0, ckb, 0,
                                           qkv_all, 768, NS_, 768, 256, 1.f, -1, 47, -1, flags,
                                           A_, FSTR, (size_t)3 * E_ * E_, (size_t)768,
                                           (size_t)NS_ * 768);
  {
    dim3 g(NWAY_, NS_ / 64, A_ * 2);
    attn_stats_k<<<g, 256, 0, stream>>>(qkv_all, idx, cnt, cstart, ml);
    attn_colsum_k<<<g, 256, 0, stream>>>(qkv_all, idx, cnt, cstart, ml, colsum);
  }
  proto_part_k<<<dim3(NWAY_, A_, PCH), 256, 0, stream>>>(qkv_all, idx, cnt, cstart, colsum, ppart);
  proto_comb2_k<<<dim3(NWAY_, A_), 256, 0, stream>>>(ppart, cnt, proto_pre);
  proto_outproj_k<<<dim3(NWAY_, A_), 256, 0, stream>>>(proto_pre, P(49), P(50), cnt, protos_all, flags);
  bias2_k<<<A_, 256, 0, stream>>>(ck, P(51), P(52), bias2_all, flags);

  // ---- classifier: batched cls1 (f32), batched cls2 (bf16 out), batched logits ----
  gemm<false, true, false, false, 1, false>(stream, fq_base, 256, P(51), 256, 0, bias2_all, 0,
                                            clsC_all, 256, NQ_, 256, 256, 1.f, -1, 51, -1, flags,
                                            A_, FSTR, (size_t)2 * E_ * E_, (size_t)E_,
                                            (size_t)NQ_ * 256);
  gemm<false, true, true, false, 1, false, false, true>(stream, clsC_all, 256, P(53), 128, 0,
                                            P(54), 0, (float*)clsC2_all, 128, NQ_, 128, 256, 1.f, -1, 53, 54, flags,
                                            A_, (size_t)NQ_ * 256, (size_t)E_ * 128, (size_t)128,
                                            (size_t)NQ_ * 128);
  logits_k<<<dim3(NQ_, A_), 64, 0, stream>>>(fq_base, protos_all, clsC2_all, P(55), P(56), out, flags);

  // ---- fusion: single K-split GEMM over 5 agent blocks (K=1280) ----
  float* fh1 = R12;
  float* fh2 = R12 + (size_t)NQ_ * E_;
  gemm<false, true, true, false, 1, false, true>(stream, fq_base, 256, P(58), 256, 0, P(59), 0,
                                                 fh1, 256, NQ_, 256, 5 * E_, 1.f, -1, 58, 59, flags,
                                                 1, 0, 0, 0, 0, FSTR);
  gemm<false, true, true, false, 1, false>(stream, fh1, 256, P(60), 128, 0, P(61), 0, fh2, 128, NQ_, 128, 256, 1.f, -1, 60, 61, flags);
  fused_k<<<NQ_, 64, 0, stream>>>(fh2, P(62), P(63), out + (size_t)A_ * NQ_ * NWAY_, flags);
}

// Round 9
// 1078.922 us; speedup vs baseline: 6.4123x; 1.1336x over previous
//
#include <hip/hip_runtime.h>
#include <hip/hip_bf16.h>

typedef __hip_bfloat16 bf16;
typedef short s8v __attribute__((ext_vector_type(8)));
typedef short s4v __attribute__((ext_vector_type(4)));
typedef float f4v __attribute__((ext_vector_type(4)));

#define A_  5
#define D_  512
#define E_  256
#define NS_ 2048
#define NQ_ 8192
#define NM_ 10240
#define NWAY_ 5
#define QSCALE 0.088388347648318447f
#define FSTR ((size_t)NM_ * E_)

__device__ inline float ldw(const void* p, size_t i, int f32) {
  return f32 ? ((const float*)p)[i] : __bfloat162float(((const bf16*)p)[i]);
}
template<bool DYN>
__device__ inline float ldT(const void* p, size_t i, int f32) {
  if (DYN) return ldw(p, i, f32);
  return ((const float*)p)[i];
}

__device__ inline short f2bf(float v) {
  union { float f; unsigned u; } x; x.f = v;
  unsigned r = x.u + 0x7fffu + ((x.u >> 16) & 1u);
  return (short)(r >> 16);
}

struct Ptrs { const void* p[64]; int sz[64]; };

__global__ void probe_k(Ptrs P, int* flags) {
  int b = blockIdx.x, lane = threadIdx.x;
  if (b == 1 || b == 3) { if (lane == 0) flags[b] = 0; return; }
  const bf16* t = (const bf16*)P.p[b];
  int n = P.sz[b];
  int K = (n >> 1) < 64 ? (n >> 1) : 64;
  bool big = false, eNZ = false, oNZ = false;
  if (lane < K) {
    float e = __bfloat162float(t[2 * lane]);
    float o = __bfloat162float(t[2 * lane + 1]);
    big = !(fabsf(e) <= 1e3f);
    eNZ = (e != 0.f); oNZ = (o != 0.f);
  }
  unsigned long long bb = __ballot(big), eb = __ballot(eNZ), ob = __ballot(oNZ);
  if (lane == 0) flags[b] = (bb != 0ull || (eb == 0ull && ob != 0ull)) ? 1 : 0;
}

__global__ void classidx_k(const int* __restrict__ y, int* __restrict__ idx,
                           int* __restrict__ cnt, int* __restrict__ cstart) {
  __shared__ int sc[NWAY_];
  int tid = threadIdx.x;
  if (tid < NWAY_) sc[tid] = 0;
  __syncthreads();
  for (int i = tid; i < NS_; i += 256) {
    int c = y[i];
    int pos = atomicAdd(&sc[c], 1);
    idx[c * NS_ + pos] = i;
  }
  __syncthreads();
  if (tid < NWAY_) cnt[tid] = sc[tid];
  if (tid == 0) { int s = 0; for (int q = 0; q < NWAY_; ++q) { cstart[q] = s; s += sc[q]; } }
}

// ---- stage support_x + query_x into one bf16 buffer XC[NM_][512] ----
__global__ void xcopy_k(const void* __restrict__ sx, const void* __restrict__ qx,
                        short* __restrict__ XC, const int* __restrict__ flags) {
  size_t i = ((size_t)blockIdx.x * 256 + threadIdx.x) * 4;
  const size_t SN = (size_t)NS_ * 512;
  if (i < SN) {
    int f = flags[0];
    #pragma unroll
    for (int q = 0; q < 4; ++q) XC[i + q] = f2bf(ldw(sx, i + q, f));
  } else {
    int f = flags[2];
    size_t j = i - SN;
    #pragma unroll
    for (int q = 0; q < 4; ++q) XC[i + q] = f2bf(ldw(qx, j + q, f));
  }
}

// ---- concat 5 layer-1 weights into Wcat[2304][512] bf16 (TRB layout) + bias cat ----
__global__ void wcat_k(Ptrs P, short* __restrict__ Wcat, float* __restrict__ bcat,
                       const int* __restrict__ flags) {
  int n = blockIdx.x * 256 + threadIdx.x;   // grid.x = 9 -> 2304
  int k = blockIdx.y;                        // 512
  int iw, ib, nl, Nloc;
  if (n < 512)       { iw = 4;  ib = 5;  nl = n;        Nloc = 512; }
  else if (n < 768)  { iw = 12; ib = 13; nl = n - 512;  Nloc = 256; }
  else if (n < 1536) { iw = 18; ib = 19; nl = n - 768;  Nloc = 768; }
  else if (n < 1792) { iw = 24; ib = 25; nl = n - 1536; Nloc = 256; }
  else               { iw = 30; ib = 31; nl = n - 1792; Nloc = 512; }
  Wcat[(size_t)n * 512 + k] = f2bf(ldw(P.p[iw], (size_t)k * Nloc + nl, flags[iw]));
  if (k == 0) bcat[n] = ldw(P.p[ib], nl, flags[ib]);
}

// ============ MFMA bf16 GEMM ============
// AMODE/BMODE: 0 = f32 static, 1 = runtime dtype (flags), 2 = bf16 pre-converted.
#define LSTR 40
template<int AMODE, int BMODE, bool DYNBIAS, bool TRB, int ACT, bool ACCUM,
         bool KSPLIT = false, bool OUTBF16 = false, bool DOMAP = false>
__global__ __launch_bounds__(256) void gemm_k(
    const void* __restrict__ A, int lda,
    const void* __restrict__ B, int ldb, size_t offB,
    const void* __restrict__ bias, size_t offBias,
    float* __restrict__ C, int ldc,
    int M, int N, int K, float alpha,
    int ia, int ib, int ibias, const int* __restrict__ flags,
    size_t sA, size_t sB, size_t sBias, size_t sC, size_t kstrideA,
    unsigned long long amap)
{
  const int fA = (AMODE == 1) ? flags[ia] : 1;
  const int fB = (BMODE == 1) ? flags[ib] : 1;
  const int fBi = DYNBIAS ? flags[ibias] : 1;
  const size_t zA = (size_t)blockIdx.z * sA;
  const size_t zB = offB + (size_t)blockIdx.z * sB;
  const size_t zBias = offBias + (size_t)blockIdx.z * sBias;
  float* Cz = C + (size_t)blockIdx.z * sC;
  bf16* Cz16 = (bf16*)C + (size_t)blockIdx.z * sC;
  __shared__ short As[128 * LSTR];
  __shared__ short Bs[128 * LSTR];
  const int tid = threadIdx.x;
  const int bm = blockIdx.y * 128, bn = blockIdx.x * 128;
  const int lane = tid & 63, wid = tid >> 6;
  const int lm = lane & 15, quad = lane >> 4;
  const int wy = (wid >> 1) * 64, wx = (wid & 1) * 64;
  f4v acc[4][4];
  #pragma unroll
  for (int i = 0; i < 4; ++i)
    #pragma unroll
    for (int j = 0; j < 4; ++j) acc[i][j] = (f4v)(0.f);

  const int am = tid >> 1, ah = (tid & 1) * 16;

  for (int k0 = 0; k0 < K; k0 += 32) {
    {
      int kk = k0 + ah;
      size_t base;
      if (KSPLIT) base = zA + (size_t)(kk >> 8) * kstrideA + (size_t)(bm + am) * lda + (kk & 255);
      else base = zA + (size_t)(bm + am) * lda + kk;
      if (AMODE == 2) {
        const bf16* ap = (const bf16*)A + base;
        *(s8v*)&As[am * LSTR + ah] = *(const s8v*)ap;
        *(s8v*)&As[am * LSTR + ah + 8] = *(const s8v*)(ap + 8);
      } else {
        short tmp[16];
        if (fA) {
          const float4* src = (const float4*)((const float*)A + base);
          #pragma unroll
          for (int q = 0; q < 4; ++q) {
            float4 v = src[q];
            tmp[q*4+0] = f2bf(v.x); tmp[q*4+1] = f2bf(v.y);
            tmp[q*4+2] = f2bf(v.z); tmp[q*4+3] = f2bf(v.w);
          }
        } else {
          #pragma unroll
          for (int q = 0; q < 16; ++q) tmp[q] = f2bf(ldw(A, base + q, 0));
        }
        s4v* dst = (s4v*)&As[am * LSTR + ah];
        #pragma unroll
        for (int q = 0; q < 4; ++q) dst[q] = *(s4v*)&tmp[q*4];
      }
    }
    if (TRB) {
      int n = tid >> 1, h = (tid & 1) * 16;
      size_t base = zB + (size_t)(bn + n) * ldb + k0 + h;
      if (BMODE == 2) {
        const bf16* bp = (const bf16*)B + base;
        *(s8v*)&Bs[n * LSTR + h] = *(const s8v*)bp;
        *(s8v*)&Bs[n * LSTR + h + 8] = *(const s8v*)(bp + 8);
      } else {
        short tmp[16];
        if (fB) {
          const float4* src = (const float4*)((const float*)B + base);
          #pragma unroll
          for (int q = 0; q < 4; ++q) {
            float4 v = src[q];
            tmp[q*4+0] = f2bf(v.x); tmp[q*4+1] = f2bf(v.y);
            tmp[q*4+2] = f2bf(v.z); tmp[q*4+3] = f2bf(v.w);
          }
        } else {
          #pragma unroll
          for (int q = 0; q < 16; ++q) tmp[q] = f2bf(ldw(B, base + q, 0));
        }
        s4v* dst = (s4v*)&Bs[n * LSTR + h];
        #pragma unroll
        for (int q = 0; q < 4; ++q) dst[q] = *(s4v*)&tmp[q*4];
      }
    } else {
      int n = tid & 127, kk = (tid >> 7) * 16;
      short tmp[16];
      #pragma unroll
      for (int j = 0; j < 16; ++j) {
        size_t bi = zB + (size_t)(k0 + kk + j) * ldb + bn + n;
        if (BMODE == 2) tmp[j] = ((const short*)B)[bi];
        else tmp[j] = f2bf(ldT<BMODE == 1>(B, bi, fB));
      }
      s4v* dst = (s4v*)&Bs[n * LSTR + kk];
      #pragma unroll
      for (int q = 0; q < 4; ++q) dst[q] = *(s4v*)&tmp[q*4];
    }
    __syncthreads();
    s8v af[4], bfr[4];
    #pragma unroll
    for (int mi = 0; mi < 4; ++mi)
      af[mi] = *(const s8v*)&As[(wy + mi*16 + lm) * LSTR + quad * 8];
    #pragma unroll
    for (int ni = 0; ni < 4; ++ni)
      bfr[ni] = *(const s8v*)&Bs[(wx + ni*16 + lm) * LSTR + quad * 8];
    #pragma unroll
    for (int mi = 0; mi < 4; ++mi)
      #pragma unroll
      for (int ni = 0; ni < 4; ++ni)
        acc[mi][ni] = __builtin_amdgcn_mfma_f32_16x16x32_bf16(af[mi], bfr[ni], acc[mi][ni], 0, 0, 0);
    __syncthreads();
  }
  const int actc = DOMAP ? (int)((amap >> ((bn >> 7) * 2)) & 3ULL) : ACT;
  #pragma unroll
  for (int mi = 0; mi < 4; ++mi) {
    #pragma unroll
    for (int r = 0; r < 4; ++r) {
      int row = bm + wy + mi*16 + quad*4 + r;
      #pragma unroll
      for (int ni = 0; ni < 4; ++ni) {
        int col = bn + wx + ni*16 + lm;
        float v = acc[mi][ni][r] * alpha;
        if (ACCUM) v += Cz[(size_t)row * ldc + col];
        if (bias) v += ldT<DYNBIAS>(bias, zBias + col, fBi);
        if (actc == 1) v = fmaxf(v, 0.f);
        else if (actc == 2) v = tanhf(v);
        else if (actc == 3) v = 1.f / (1.f + expf(-v));
        if (OUTBF16) Cz16[(size_t)row * ldc + col] = __float2bfloat16(v);
        else Cz[(size_t)row * ldc + col] = v;
      }
    }
  }
}

template<int AMODE, int BMODE, bool DYNBIAS, bool TRB, int ACT, bool ACCUM,
         bool KSPLIT = false, bool OUTBF16 = false, bool DOMAP = false>
static void gemm(hipStream_t s, const void* A, int lda, const void* B, int ldb, size_t offB,
                 const void* bias, size_t offBias, float* C, int ldc, int M, int N, int K,
                 float alpha, int ia, int ib, int ibias, const int* flags,
                 int batch = 1, size_t sA = 0, size_t sB = 0, size_t sBias = 0, size_t sC = 0,
                 size_t kstrideA = 0, unsigned long long amap = 0) {
  dim3 g(N / 128, M / 128, batch), b(256);
  gemm_k<AMODE, BMODE, DYNBIAS, TRB, ACT, ACCUM, KSPLIT, OUTBF16, DOMAP><<<g, b, 0, s>>>(
      A, lda, B, ldb, offB, bias, offBias, C, ldc, M, N, K, alpha, ia, ib, ibias, flags,
      sA, sB, sBias, sC, kstrideA, amap);
}

// ---------------- LayerNorm (+relu/sigmoid), bf16/f32 in/out, strided ----------------
template<int ACT, bool INBF, bool OUTBF>
__global__ __launch_bounds__(256) void ln_k(const void* __restrict__ X, const void* __restrict__ g,
                                            const void* __restrict__ be, void* __restrict__ Y,
                                            int W, int ldx, int ldy,
                                            int ig, int ibe, const int* __restrict__ flags) {
  const int fG = flags[ig], fBe = flags[ibe];
  int row = blockIdx.x;
  const float* xf = (const float*)X + (size_t)row * ldx;
  const bf16* xb = (const bf16*)X + (size_t)row * ldx;
  float* yf = (float*)Y + (size_t)row * ldy;
  bf16* yb = (bf16*)Y + (size_t)row * ldy;
  __shared__ float red[256];
  int tid = threadIdx.x;
  float s1 = 0.f, s2 = 0.f;
  for (int i = tid; i < W; i += 256) {
    float v = INBF ? __bfloat162float(xb[i]) : xf[i];
    s1 += v; s2 += v * v;
  }
  red[tid] = s1; __syncthreads();
  for (int o = 128; o > 0; o >>= 1) { if (tid < o) red[tid] += red[tid + o]; __syncthreads(); }
  float mean = red[0] / W; __syncthreads();
  red[tid] = s2; __syncthreads();
  for (int o = 128; o > 0; o >>= 1) { if (tid < o) red[tid] += red[tid + o]; __syncthreads(); }
  float var = fmaxf(red[0] / W - mean * mean, 0.f);
  float rstd = rsqrtf(var + 1e-5f);
  for (int i = tid; i < W; i += 256) {
    float x = INBF ? __bfloat162float(xb[i]) : xf[i];
    float v = (x - mean) * rstd * ldw(g, i, fG) + ldw(be, i, fBe);
    if (ACT == 1) v = fmaxf(v, 0.f);
    else if (ACT == 3) v = 1.f / (1.f + expf(-v));
    if (OUTBF) yb[i] = __float2bfloat16(v);
    else yf[i] = v;
  }
}

// ================= comm round =================
__global__ void statepart_k(const float* __restrict__ featsC, float* __restrict__ part) {
  int a = blockIdx.x, g = blockIdx.y, e = threadIdx.x;
  const float* p = featsC + (size_t)a * FSTR + ((size_t)g * 128) * E_ + e;
  float s = 0.f;
  for (int n = 0; n < 128; ++n) s += p[(size_t)n * E_];
  part[((size_t)a * 16 + g) * E_ + e] = s;
}

__global__ void statecomb_k(const float* __restrict__ part, const void* __restrict__ internal,
                            float* __restrict__ state, const int* __restrict__ flags) {
  int a = blockIdx.x, e = threadIdx.x;
  float s = 0.f;
  for (int g = 0; g < 16; ++g) s += part[((size_t)a * 16 + g) * E_ + e];
  state[a * E_ + e] = s * (1.f / NS_) + ldw(internal, (size_t)a * E_ + e, flags[46]);
}

__global__ void mvpart_k(const float* __restrict__ x, const void* __restrict__ W, int iw,
                         float* __restrict__ part, const int* __restrict__ flags) {
  int a = blockIdx.x, g = blockIdx.y, f = threadIdx.x;
  const int fW = flags[iw];
  float s = 0.f;
  size_t wb = (size_t)a * E_ * E_ + f;
  for (int e = g * 32; e < g * 32 + 32; ++e)
    s += x[a * E_ + e] * ldw(W, wb + (size_t)e * E_, fW);
  part[((size_t)a * 8 + g) * E_ + f] = s;
}

template<int ACT>
__global__ void mvcomb_k(const float* __restrict__ part, const void* __restrict__ b, int ibb,
                         float* __restrict__ y, const int* __restrict__ flags) {
  int a = blockIdx.x, f = threadIdx.x;
  float s = 0.f;
  for (int g = 0; g < 8; ++g) s += part[((size_t)a * 8 + g) * E_ + f];
  s += ldw(b, (size_t)a * E_ + f, flags[ibb]);
  if (ACT == 1) s = fmaxf(s, 0.f);
  else if (ACT == 2) s = tanhf(s);
  y[a * E_ + f] = s;
}

__device__ inline float wave_sum64(float v) {
  for (int o = 32; o > 0; o >>= 1) v += __shfl_down(v, o);
  return v;
}

__global__ __launch_bounds__(256) void qkvcomm_k(const float* __restrict__ msg,
                                                 const void* __restrict__ comm_w,
                                                 const void* __restrict__ in_w,
                                                 const void* __restrict__ in_b,
                                                 float* __restrict__ qkvc,
                                                 const int* __restrict__ flags) {
  const int fCW = flags[57], fIW = flags[38], fIB = flags[39];
  int gw = blockIdx.x * 4 + (threadIdx.x >> 6);
  int a = gw / 768, f = gw % 768;
  int lane = threadIdx.x & 63;
  float w[5]; float mx = -1e30f;
  for (int j = 0; j < 5; ++j) { w[j] = ldw(comm_w, a * 5 + j, fCW); mx = fmaxf(mx, w[j]); }
  float sum = 0.f;
  for (int j = 0; j < 5; ++j) { w[j] = __expf(w[j] - mx); sum += w[j]; }
  for (int j = 0; j < 5; ++j) w[j] /= sum;
  int others[4]; { int c = 0; for (int j = 0; j < 5; ++j) if (j != a) others[c++] = j; }
  int e0 = lane * 4;
  float4 wv;
  size_t b = (size_t)a * 768 * E_ + (size_t)f * E_ + e0;
  if (fIW) wv = *(const float4*)((const float*)in_w + b);
  else wv = make_float4(ldw(in_w, b, 0), ldw(in_w, b + 1, 0), ldw(in_w, b + 2, 0), ldw(in_w, b + 3, 0));
  float acc[4];
  #pragma unroll
  for (int t = 0; t < 4; ++t) {
    const float4 mv = *(const float4*)(msg + others[t] * E_ + e0);
    acc[t] = mv.x * wv.x + mv.y * wv.y + mv.z * wv.z + mv.w * wv.w;
  }
  #pragma unroll
  for (int t = 0; t < 4; ++t) acc[t] = wave_sum64(acc[t]);
  if (lane == 0) {
    float bb = ldw(in_b, (size_t)a * 768 + f, fIB);
    #pragma unroll
    for (int t = 0; t < 4; ++t)
      qkvc[((size_t)a * 4 + t) * 768 + f] = acc[t] * w[others[t]] + bb;
  }
}

__global__ __launch_bounds__(256) void attn4_k(const float* __restrict__ qkvc,
                                               float* __restrict__ obar) {
  int a = blockIdx.x, tid = threadIdx.x;
  __shared__ float qkv[4][768];
  __shared__ float attw[4][16];
  for (int i = tid; i < 4 * 768; i += 256) qkv[i / 768][i % 768] = qkvc[(size_t)a * 4 * 768 + i];
  __syncthreads();
  if (tid < 16) {
    int h = tid >> 2, t = tid & 3;
    float sc[4]; float mx = -1e30f;
    for (int t2 = 0; t2 < 4; ++t2) {
      float s = 0.f;
      for (int d = 0; d < 64; ++d) s += qkv[t][h * 64 + d] * qkv[t2][256 + h * 64 + d];
      sc[t2] = s * 0.125f; mx = fmaxf(mx, sc[t2]);
    }
    float ss = 0.f;
    for (int t2 = 0; t2 < 4; ++t2) { sc[t2] = __expf(sc[t2] - mx); ss += sc[t2]; }
    for (int t2 = 0; t2 < 4; ++t2) attw[h][t * 4 + t2] = sc[t2] / ss;
  }
  __syncthreads();
  {
    int e = tid, h = e >> 6;
    float s = 0.f;
    for (int t = 0; t < 4; ++t)
      for (int t2 = 0; t2 < 4; ++t2)
        s += attw[h][t * 4 + t2] * qkv[t2][512 + e];
    obar[a * E_ + e] = s * 0.25f;
  }
}

__global__ __launch_bounds__(256) void combproj_k(const float* __restrict__ obar,
                                                  const void* __restrict__ ow,
                                                  const void* __restrict__ ob,
                                                  const void* __restrict__ internal,
                                                  float* __restrict__ comb,
                                                  const int* __restrict__ flags) {
  const int fOW = flags[40], fOB = flags[41], fIN = flags[46];
  int gw = blockIdx.x * 4 + (threadIdx.x >> 6);
  int a = gw >> 8, f = gw & 255;
  int lane = threadIdx.x & 63;
  int e0 = lane * 4;
  float4 wv;
  size_t b = (size_t)a * E_ * E_ + (size_t)f * E_ + e0;
  if (fOW) wv = *(const float4*)((const float*)ow + b);
  else wv = make_float4(ldw(ow, b, 0), ldw(ow, b + 1, 0), ldw(ow, b + 2, 0), ldw(ow, b + 3, 0));
  const float4 ov = *(const float4*)(obar + a * E_ + e0);
  float s = wave_sum64(ov.x * wv.x + ov.y * wv.y + ov.z * wv.z + ov.w * wv.w);
  if (lane == 0)
    comb[a * E_ + f] = ldw(internal, (size_t)a * E_ + f, fIN) + s + ldw(ob, (size_t)a * E_ + f, fOB);
}

__global__ __launch_bounds__(256) void ckb_k(const float* __restrict__ ck,
                                             const void* __restrict__ in_w,
                                             const void* __restrict__ in_b,
                                             float* __restrict__ ckb,
                                             const int* __restrict__ flags) {
  const int fW = flags[47], fB = flags[48];
  int gw = blockIdx.x * 4 + (threadIdx.x >> 6);
  int a = gw / 768, f = gw % 768;
  int lane = threadIdx.x & 63;
  int e0 = lane * 4;
  float4 wv;
  size_t b = (size_t)a * 768 * E_ + (size_t)f * E_ + e0;
  if (fW) wv = *(const float4*)((const float*)in_w + b);
  else wv = make_float4(ldw(in_w, b, 0), ldw(in_w, b + 1, 0), ldw(in_w, b + 2, 0), ldw(in_w, b + 3, 0));
  const float4 cv = *(const float4*)(ck + a * E_ + e0);
  float s = wave_sum64(cv.x * wv.x + cv.y * wv.y + cv.z * wv.z + cv.w * wv.w);
  if (lane == 0) ckb[(size_t)a * 768 + f] = s + ldw(in_b, (size_t)a * 768 + f, fB);
}

// ======== MFMA class-block attention ========
#define LS 136
__device__ inline void stage64x128(const float* __restrict__ qkv, const int* __restrict__ myidx,
                                   int row0, int n, int ho, short* dst) {
  int t = threadIdx.x;
  int r = t >> 2, c0 = (t & 3) * 32;
  int rr = row0 + r;
  short tmp[32];
  if (rr < n) {
    const float* s = qkv + (size_t)myidx[rr] * 768 + ho + c0;
    #pragma unroll
    for (int q = 0; q < 8; ++q) {
      float4 v = *(const float4*)(s + q * 4);
      tmp[q*4+0] = f2bf(v.x); tmp[q*4+1] = f2bf(v.y);
      tmp[q*4+2] = f2bf(v.z); tmp[q*4+3] = f2bf(v.w);
    }
  } else {
    #pragma unroll
    for (int q = 0; q < 32; ++q) tmp[q] = 0;
  }
  s8v* d = (s8v*)&dst[r * LS + c0];
  #pragma unroll
  for (int q = 0; q < 4; ++q) d[q] = *(s8v*)&tmp[q*8];
}

__global__ __launch_bounds__(256) void attn_stats_k(
    const float* __restrict__ qkv_all, const int* __restrict__ idx,
    const int* __restrict__ cnt, const int* __restrict__ cstart,
    float* __restrict__ ml)
{
  int c = blockIdx.x, z = blockIdx.z, a = z >> 1, h = z & 1;
  int n = cnt[c];
  int r0 = blockIdx.y * 64;
  if (r0 >= n) return;
  const float* qkv = qkv_all + (size_t)a * NS_ * 768;
  const int* myidx = idx + c * NS_;
  __shared__ short Qs[64 * LS];
  __shared__ short Ks[64 * LS];
  __shared__ float Mw[4][64], Lw[4][64];
  int tid = threadIdx.x, lane = tid & 63, wid = tid >> 6;
  int lm = lane & 15, quad = lane >> 4;
  stage64x128(qkv, myidx, r0, n, h * 128, Qs);
  float m_run[16], l_run[16];
  #pragma unroll
  for (int i = 0; i < 16; ++i) { m_run[i] = -3e38f; l_run[i] = 0.f; }
  for (int j0 = 0; j0 < n; j0 += 64) {
    __syncthreads();
    stage64x128(qkv, myidx, j0, n, 256 + h * 128, Ks);
    __syncthreads();
    f4v acc[4];
    #pragma unroll
    for (int mi = 0; mi < 4; ++mi) acc[mi] = (f4v)(0.f);
    #pragma unroll
    for (int kc = 0; kc < 4; ++kc) {
      s8v bfr = *(const s8v*)&Ks[(wid * 16 + lm) * LS + kc * 32 + quad * 8];
      #pragma unroll
      for (int mi = 0; mi < 4; ++mi) {
        s8v af = *(const s8v*)&Qs[(mi * 16 + lm) * LS + kc * 32 + quad * 8];
        acc[mi] = __builtin_amdgcn_mfma_f32_16x16x32_bf16(af, bfr, acc[mi], 0, 0, 0);
      }
    }
    int col = j0 + wid * 16 + lm;
    bool cv = col < n;
    #pragma unroll
    for (int mi = 0; mi < 4; ++mi) {
      #pragma unroll
      for (int r = 0; r < 4; ++r) {
        float s = cv ? acc[mi][r] * QSCALE : -3e38f;
        float m = s;
        m = fmaxf(m, __shfl_xor(m, 1));
        m = fmaxf(m, __shfl_xor(m, 2));
        m = fmaxf(m, __shfl_xor(m, 4));
        m = fmaxf(m, __shfl_xor(m, 8));
        float p = cv ? __expf(s - m) : 0.f;
        p += __shfl_xor(p, 1); p += __shfl_xor(p, 2);
        p += __shfl_xor(p, 4); p += __shfl_xor(p, 8);
        int ri = mi * 4 + r;
        float mo = m_run[ri];
        float mn = fmaxf(mo, m);
        l_run[ri] = l_run[ri] * __expf(mo - mn) + p * __expf(m - mn);
        m_run[ri] = mn;
      }
    }
  }
  if (lm == 0) {
    #pragma unroll
    for (int mi = 0; mi < 4; ++mi)
      #pragma unroll
      for (int r = 0; r < 4; ++r) {
        int row = mi * 16 + quad * 4 + r;
        Mw[wid][row] = m_run[mi * 4 + r];
        Lw[wid][row] = l_run[mi * 4 + r];
      }
  }
  __syncthreads();
  if (tid < 64 && r0 + tid < n) {
    float m = fmaxf(fmaxf(Mw[0][tid], Mw[1][tid]), fmaxf(Mw[2][tid], Mw[3][tid]));
    float l = Lw[0][tid] * __expf(Mw[0][tid] - m) + Lw[1][tid] * __expf(Mw[1][tid] - m)
            + Lw[2][tid] * __expf(Mw[2][tid] - m) + Lw[3][tid] * __expf(Mw[3][tid] - m);
    size_t p = (size_t)z * NS_ + cstart[c] + r0 + tid;
    ml[p * 2] = m; ml[p * 2 + 1] = l;
  }
}

__global__ __launch_bounds__(256) void attn_colsum_k(
    const float* __restrict__ qkv_all, const int* __restrict__ idx,
    const int* __restrict__ cnt, const int* __restrict__ cstart,
    const float* __restrict__ ml, float* __restrict__ colsum)
{
  int c = blockIdx.x, z = blockIdx.z, a = z >> 1, h = z & 1;
  int n = cnt[c];
  int j0 = blockIdx.y * 64;
  if (j0 >= n) return;
  const float* qkv = qkv_all + (size_t)a * NS_ * 768;
  const int* myidx = idx + c * NS_;
  __shared__ short Qs[64 * LS];
  __shared__ short Ks[64 * LS];
  __shared__ float Msm[64], Lsm[64];
  int tid = threadIdx.x, lane = tid & 63, wid = tid >> 6;
  int lm = lane & 15, quad = lane >> 4;
  stage64x128(qkv, myidx, j0, n, 256 + h * 128, Ks);
  float ca = 0.f;
  for (int i0 = 0; i0 < n; i0 += 64) {
    __syncthreads();
    stage64x128(qkv, myidx, i0, n, h * 128, Qs);
    if (tid < 64) {
      int gi = i0 + tid;
      if (gi < n) {
        size_t p = (size_t)z * NS_ + cstart[c] + gi;
        Msm[tid] = ml[p * 2]; Lsm[tid] = ml[p * 2 + 1];
      } else { Msm[tid] = 0.f; Lsm[tid] = 1.f; }
    }
    __syncthreads();
    f4v acc[4];
    #pragma unroll
    for (int mi = 0; mi < 4; ++mi) acc[mi] = (f4v)(0.f);
    #pragma unroll
    for (int kc = 0; kc < 4; ++kc) {
      s8v bfr = *(const s8v*)&Ks[(wid * 16 + lm) * LS + kc * 32 + quad * 8];
      #pragma unroll
      for (int mi = 0; mi < 4; ++mi) {
        s8v af = *(const s8v*)&Qs[(mi * 16 + lm) * LS + kc * 32 + quad * 8];
        acc[mi] = __builtin_amdgcn_mfma_f32_16x16x32_bf16(af, bfr, acc[mi], 0, 0, 0);
      }
    }
    #pragma unroll
    for (int mi = 0; mi < 4; ++mi) {
      #pragma unroll
      for (int r = 0; r < 4; ++r) {
        int lrow = mi * 16 + quad * 4 + r;
        int gi = i0 + lrow;
        if (gi < n) {
          float m = Msm[lrow];
          float invl = 1.f / Lsm[lrow];
          ca += __expf(acc[mi][r] * QSCALE - m) * invl;
        }
      }
    }
  }
  ca += __shfl_xor(ca, 16);
  ca += __shfl_xor(ca, 32);
  int col = j0 + wid * 16 + lm;
  if (quad == 0 && col < n)
    colsum[(size_t)z * NS_ + cstart[c] + col] = ca;
}

// ---- proto combine: K-chunked 2-stage ----
#define PCH 8
__global__ void proto_part_k(const float* __restrict__ qkv_all, const int* __restrict__ idx,
                             const int* __restrict__ cnt, const int* __restrict__ cstart,
                             const float* __restrict__ colsum, float* __restrict__ part) {
  int c = blockIdx.x, a = blockIdx.y, ch = blockIdx.z;
  int e = threadIdx.x, h = e >> 7, d = e & 127;
  int n = cnt[c];
  int k0 = ch * 256, k1 = min(k0 + 256, n);
  float s = 0.f;
  const float* qkv = qkv_all + (size_t)a * NS_ * 768;
  const float* csum = colsum + (size_t)(a * 2 + h) * NS_ + cstart[c];
  const int* myidx = idx + c * NS_;
  for (int k = k0; k < k1; ++k)
    s += csum[k] * qkv[(size_t)myidx[k] * 768 + 512 + h * 128 + d];
  part[(((size_t)a * NWAY_ + c) * PCH + ch) * E_ + e] = s;
}

__global__ void proto_comb2_k(const float* __restrict__ part, const int* __restrict__ cnt,
                              float* __restrict__ proto_pre) {
  int c = blockIdx.x, a = blockIdx.y, e = threadIdx.x;
  int n = cnt[c];
  float s = 0.f;
  for (int ch = 0; ch < PCH; ++ch)
    s += part[(((size_t)a * NWAY_ + c) * PCH + ch) * E_ + e];
  proto_pre[((size_t)a * NWAY_ + c) * E_ + e] = (n > 0) ? s / (float)n : 0.f;
}

__global__ void proto_outproj_k(const float* __restrict__ proto_pre, const void* __restrict__ ow,
                                const void* __restrict__ ob, const int* __restrict__ cnt,
                                float* __restrict__ protos_all, const int* __restrict__ flags) {
  int c = blockIdx.x, a = blockIdx.y, e = threadIdx.x;
  const int fW = flags[49], fB = flags[50];
  __shared__ float pp[E_];
  pp[e] = proto_pre[((size_t)a * NWAY_ + c) * E_ + e];
  __syncthreads();
  size_t wb = (size_t)a * E_ * E_ + (size_t)e * E_;
  float s = 0.f;
  for (int k = 0; k < E_; ++k) s += pp[k] * ldw(ow, wb + k, fW);
  float v = s + ldw(ob, (size_t)a * E_ + e, fB);
  protos_all[((size_t)a * NWAY_ + c) * E_ + e] = (cnt[c] > 0) ? v : 0.f;
}

__global__ void bias2_k(const float* __restrict__ ck, const void* __restrict__ w1,
                        const void* __restrict__ b1, float* __restrict__ bias2_all,
                        const int* __restrict__ flags) {
  const int fW = flags[51], fB = flags[52];
  int a = blockIdx.x, n = threadIdx.x;
  __shared__ float c[E_];
  c[n] = ck[a * E_ + n]; __syncthreads();
  size_t wbase = (size_t)a * 2 * E_ * E_ + (size_t)E_ * E_ + n;
  float s = 0.f;
  for (int k = 0; k < E_; ++k) s += c[k] * ldw(w1, wbase + (size_t)k * E_, fW);
  bias2_all[a * E_ + n] = s + ldw(b1, (size_t)a * E_ + n, fB);
}

// ---------------- epilogues ----------------
__global__ __launch_bounds__(64) void logits_k(const float* __restrict__ fqbase,
                                               const float* __restrict__ protos_all,
                                               const bf16* __restrict__ c2all,
                                               const void* __restrict__ w3,
                                               const void* __restrict__ b3,
                                               float* __restrict__ out,
                                               const int* __restrict__ flags) {
  const int fW = flags[55], fB = flags[56];
  int i = blockIdx.x, a = blockIdx.y, lane = threadIdx.x;
  const float* fq = fqbase + (size_t)a * FSTR;
  const float* protos = protos_all + (size_t)a * NWAY_ * E_;
  const bf16* c2 = c2all + ((size_t)a * NQ_ + i) * 128;
  float4 xv = ((const float4*)(fq + (size_t)i * E_))[lane];
  float qq = wave_sum64(xv.x * xv.x + xv.y * xv.y + xv.z * xv.z + xv.w * xv.w);
  float cpart = __bfloat162float(c2[lane * 2]) * ldw(w3, (size_t)a * 128 + lane * 2, fW) +
                __bfloat162float(c2[lane * 2 + 1]) * ldw(w3, (size_t)a * 128 + lane * 2 + 1, fW);
  float conf = wave_sum64(cpart);
  if (lane == 0) conf += ldw(b3, a, fB);
  for (int c = 0; c < NWAY_; ++c) {
    float4 pv = ((const float4*)(protos + c * E_))[lane];
    float dt = wave_sum64(xv.x * pv.x + xv.y * pv.y + xv.z * pv.z + xv.w * pv.w);
    float pp = wave_sum64(pv.x * pv.x + pv.y * pv.y + pv.z * pv.z + pv.w * pv.w);
    if (lane == 0) {
      float d2 = fmaxf(qq + pp - 2.f * dt, 1e-12f);
      out[((size_t)a * NQ_ + i) * NWAY_ + c] = -sqrtf(d2) + 0.1f * conf;
    }
  }
}

__global__ __launch_bounds__(64) void fused_k(const float* __restrict__ h2, const void* __restrict__ w3,
                                              const void* __restrict__ b3, float* __restrict__ out,
                                              const int* __restrict__ flags) {
  const int fW = flags[62], fB = flags[63];
  int i = blockIdx.x, lane = threadIdx.x;
  float s = h2[(size_t)i * 128 + lane * 2] * ldw(w3, lane * 2, fW) +
            h2[(size_t)i * 128 + lane * 2 + 1] * ldw(w3, lane * 2 + 1, fW);
  s = wave_sum64(s);
  if (lane == 0) out[i] = s + ldw(b3, 0, fB);
}

// ---------------- host ----------------
extern "C" void kernel_launch(void* const* d_in, const int* in_sizes, int n_in,
                              void* d_out, int out_size, void* d_ws, size_t ws_size,
                              hipStream_t stream) {
  (void)out_size; (void)ws_size;
  #define P(i) ((const void*)d_in[i])
  const int* support_y = (const int*)d_in[1];
  float* out = (float*)d_out;

  int* flags = (int*)d_ws;
  char* base = (char*)d_ws + 256;
  // featsC f32 [A][NM][E]                                      52,428,800 B
  float* featsC = (float*)base;
  // R region 47,185,920 B: t1cat bf16 [NM][2304] -> qkv_all f32 -> clsC_all f32 -> fh1/fh2
  char* R = base + (size_t)A_ * FSTR * 4;
  short* t1cat   = (short*)R;
  float* qkv_all = (float*)R;
  float* clsC_all = (float*)R;
  // XCR region 10,485,760 B: XC bf16 [NM][512] -> tmp2 bf16 + b4 bf16 -> clsC2_all bf16
  char* XCR = R + (size_t)NM_ * 2304 * 2;
  short* XC   = (short*)XCR;
  short* tmp2 = (short*)XCR;
  short* b4   = (short*)(XCR + (size_t)NM_ * 256 * 2);
  short* clsC2_all = (short*)XCR;
  // smalls
  char* S = XCR + (size_t)NM_ * 512 * 2;
  float* state      = (float*)S;
  float* msg        = state + A_ * E_;
  float* ck         = msg + A_ * E_;
  float* protos_all = ck + A_ * E_;
  float* bias2_all  = protos_all + A_ * NWAY_ * E_;
  float* ml         = bias2_all + A_ * E_;
  float* colsum     = ml + (size_t)A_ * 2 * NS_ * 2;
  float* proto_pre  = colsum + (size_t)A_ * 2 * NS_;
  int*   idx        = (int*)(proto_pre + A_ * NWAY_ * E_);
  int*   cnt        = idx + NWAY_ * NS_;
  int*   cstart     = cnt + NWAY_;
  float* statepart  = (float*)(cstart + NWAY_ + 3);
  float* mvp        = statepart + A_ * 16 * E_;
  float* qkvc       = mvp + A_ * 8 * E_;
  float* obar       = qkvc + A_ * 4 * 768;
  float* comb       = obar + A_ * E_;
  float* hh         = comb + A_ * E_;
  float* ckb        = hh + A_ * E_;
  float* ppart      = ckb + A_ * 768;
  float* bcat       = ppart + (size_t)A_ * NWAY_ * PCH * E_;
  short* Wcat       = (short*)(bcat + 2304);

  const float* fq_base = featsC + (size_t)NS_ * E_;

  Ptrs ps;
  for (int i = 0; i < 64; ++i) {
    ps.p[i] = (i < n_in) ? d_in[i] : nullptr;
    ps.sz[i] = (i < n_in) ? in_sizes[i] : 0;
  }
  probe_k<<<64, 64, 0, stream>>>(ps, flags);
  classidx_k<<<1, 256, 0, stream>>>(support_y, idx, cnt, cstart);
  xcopy_k<<<(NM_ * 512 / 4) / 256, 256, 0, stream>>>(P(0), P(2), XC, flags);
  wcat_k<<<dim3(9, 512), 256, 0, stream>>>(ps, Wcat, bcat, flags);

  // ---- FE: mega layer-1 GEMM (N = 2304), per-tile act map: tiles 6..17 relu ----
  gemm<2, 2, false, true, 0, false, false, true, true>(
      stream, XC, 512, Wcat, 512, 0, bcat, 0, (float*)t1cat, 2304,
      NM_, 2304, 512, 1.f, -1, -1, -1, flags, 1, 0, 0, 0, 0, 0, 0x555555000ULL);
  // fe0: LN in-place (cols 0-511) -> GEMM2 -> LN(relu) -> featsC[0]
  ln_k<1, true, true><<<NM_, 256, 0, stream>>>(t1cat, P(6), P(7), t1cat, 512, 2304, 2304, 6, 7, flags);
  gemm<2, 1, true, false, 0, false, false, true>(stream, t1cat, 2304, P(8), 256, 0, P(9), 0,
                                                 (float*)tmp2, 256, NM_, 256, 512, 1.f, -1, 8, 9, flags);
  ln_k<1, true, false><<<NM_, 256, 0, stream>>>(tmp2, P(10), P(11), featsC, 256, 256, 256, 10, 11, flags);
  // fe1: LN in-place (cols 512-767) -> GEMM2(tanh) -> featsC[1]
  ln_k<1, true, true><<<NM_, 256, 0, stream>>>(t1cat + 512, P(14), P(15), t1cat + 512, 256, 2304, 2304, 14, 15, flags);
  gemm<2, 1, true, false, 2, false>(stream, t1cat + 512, 2304, P(16), 256, 0, P(17), 0,
                                    featsC + FSTR, 256, NM_, 256, 256, 1.f, -1, 16, 17, flags);
  // fe2: GEMM2 (K=768) -> LN(relu) -> featsC[2]
  gemm<2, 1, true, false, 0, false, false, true>(stream, t1cat + 768, 2304, P(20), 256, 0, P(21), 0,
                                                 (float*)tmp2, 256, NM_, 256, 768, 1.f, -1, 20, 21, flags);
  ln_k<1, true, false><<<NM_, 256, 0, stream>>>(tmp2, P(22), P(23), featsC + 2 * FSTR, 256, 256, 256, 22, 23, flags);
  // fe3: GEMM2 (K=256) -> LN(sigmoid) -> featsC[3]
  gemm<2, 1, true, false, 0, false, false, true>(stream, t1cat + 1536, 2304, P(26), 256, 0, P(27), 0,
                                                 (float*)tmp2, 256, NM_, 256, 256, 1.f, -1, 26, 27, flags);
  ln_k<3, true, false><<<NM_, 256, 0, stream>>>(tmp2, P(28), P(29), featsC + 3 * FSTR, 256, 256, 256, 28, 29, flags);
  // fe4: GEMM2(relu, K=512) -> b4 -> GEMM3 -> featsC[4]
  gemm<2, 1, true, false, 1, false, false, true>(stream, t1cat + 1792, 2304, P(32), 256, 0, P(33), 0,
                                                 (float*)b4, 256, NM_, 256, 512, 1.f, -1, 32, 33, flags);
  gemm<2, 1, true, false, 0, false>(stream, b4, 256, P(34), 256, 0, P(35), 0,
                                    featsC + 4 * FSTR, 256, NM_, 256, 256, 1.f, -1, 34, 35, flags);

  // ---- comm round ----
  statepart_k<<<dim3(A_, 16), 256, 0, stream>>>(featsC, statepart);
  statecomb_k<<<A_, 256, 0, stream>>>(statepart, P(46), state, flags);
  mvpart_k<<<dim3(A_, 8), 256, 0, stream>>>(state, P(36), 36, mvp, flags);
  mvcomb_k<2><<<A_, 256, 0, stream>>>(mvp, P(37), 37, msg, flags);
  qkvcomm_k<<<A_ * 768 / 4, 256, 0, stream>>>(msg, P(57), P(38), P(39), qkvc, flags);
  attn4_k<<<A_, 256, 0, stream>>>(qkvc, obar);
  combproj_k<<<A_ * E_ / 4, 256, 0, stream>>>(obar, P(40), P(41), P(46), comb, flags);
  mvpart_k<<<dim3(A_, 8), 256, 0, stream>>>(comb, P(42), 42, mvp, flags);
  mvcomb_k<1><<<A_, 256, 0, stream>>>(mvp, P(43), 43, hh, flags);
  mvpart_k<<<dim3(A_, 8), 256, 0, stream>>>(hh, P(44), 44, mvp, flags);
  mvcomb_k<0><<<A_, 256, 0, stream>>>(mvp, P(45), 45, ck, flags);

  // ---- batched prototype attention ----
  ckb_k<<<A_ * 768 / 4, 256, 0, stream>>>(ck, P(47), P(48), ckb, flags);
  gemm<0, 1, false, true, 0, false>(stream, featsC, 256, P(47), 256, 0, ckb, 0,
                                    qkv_all, 768, NS_, 768, 256, 1.f, -1, 47, -1, flags,
                                    A_, FSTR, (size_t)3 * E_ * E_, (size_t)768, (size_t)NS_ * 768);
  {
    dim3 g(NWAY_, NS_ / 64, A_ * 2);
    attn_stats_k<<<g, 256, 0, stream>>>(qkv_all, idx, cnt, cstart, ml);
    attn_colsum_k<<<g, 256, 0, stream>>>(qkv_all, idx, cnt, cstart, ml, colsum);
  }
  proto_part_k<<<dim3(NWAY_, A_, PCH), 256, 0, stream>>>(qkv_all, idx, cnt, cstart, colsum, ppart);
  proto_comb2_k<<<dim3(NWAY_, A_), 256, 0, stream>>>(ppart, cnt, proto_pre);
  proto_outproj_k<<<dim3(NWAY_, A_), 256, 0, stream>>>(proto_pre, P(49), P(50), cnt, protos_all, flags);
  bias2_k<<<A_, 256, 0, stream>>>(ck, P(51), P(52), bias2_all, flags);

  // ---- classifier ----
  gemm<0, 1, false, false, 1, false>(stream, fq_base, 256, P(51), 256, 0, bias2_all, 0,
                                     clsC_all, 256, NQ_, 256, 256, 1.f, -1, 51, -1, flags,
                                     A_, FSTR, (size_t)2 * E_ * E_, (size_t)E_, (size_t)NQ_ * 256);
  gemm<0, 1, true, false, 1, false, false, true>(stream, clsC_all, 256, P(53), 128, 0,
                                     P(54), 0, (float*)clsC2_all, 128, NQ_, 128, 256, 1.f, -1, 53, 54, flags,
                                     A_, (size_t)NQ_ * 256, (size_t)E_ * 128, (size_t)128, (size_t)NQ_ * 128);
  logits_k<<<dim3(NQ_, A_), 64, 0, stream>>>(fq_base, protos_all, (const bf16*)clsC2_all, P(55), P(56), out, flags);

  // ---- fusion ----
  float* fh1 = (float*)R;
  float* fh2 = fh1 + (size_t)NQ_ * E_;
  gemm<0, 1, true, false, 1, false, true>(stream, fq_base, 256, P(58), 256, 0, P(59), 0,
                                          fh1, 256, NQ_, 256, 5 * E_, 1.f, -1, 58, 59, flags,
                                          1, 0, 0, 0, 0, FSTR);
  gemm<0, 1, true, false, 1, false>(stream, fh1, 256, P(60), 128, 0, P(61), 0, fh2, 128, NQ_, 128, 256, 1.f, -1, 60, 61, flags);
  fused_k<<<NQ_, 64, 0, stream>>>(fh2, P(62), P(63), out + (size_t)A_ * NQ_ * NWAY_, flags);
}

// Round 10
// 987.324 us; speedup vs baseline: 7.0072x; 1.0928x over previous
//
#include <hip/hip_runtime.h>
#include <hip/hip_bf16.h>

typedef __hip_bfloat16 bf16;
typedef short s8v __attribute__((ext_vector_type(8)));
typedef short s4v __attribute__((ext_vector_type(4)));
typedef float f4v __attribute__((ext_vector_type(4)));

#define A_  5
#define D_  512
#define E_  256
#define NS_ 2048
#define NQ_ 8192
#define NM_ 10240
#define NWAY_ 5
#define QSCALE 0.088388347648318447f
#define FSTR ((size_t)NM_ * E_)

__device__ inline float ldw(const void* p, size_t i, int f32) {
  return f32 ? ((const float*)p)[i] : __bfloat162float(((const bf16*)p)[i]);
}
template<bool DYN>
__device__ inline float ldT(const void* p, size_t i, int f32) {
  if (DYN) return ldw(p, i, f32);
  return ((const float*)p)[i];
}

__device__ inline short f2bf(float v) {
  union { float f; unsigned u; } x; x.f = v;
  unsigned r = x.u + 0x7fffu + ((x.u >> 16) & 1u);
  return (short)(r >> 16);
}
__device__ inline float bf2f(short s) {
  union { unsigned u; float f; } x; x.u = ((unsigned)(unsigned short)s) << 16;
  return x.f;
}

struct Ptrs { const void* p[64]; int sz[64]; };

__global__ void probe_k(Ptrs P, int* flags) {
  int b = blockIdx.x, lane = threadIdx.x;
  if (b == 1 || b == 3) { if (lane == 0) flags[b] = 0; return; }
  const bf16* t = (const bf16*)P.p[b];
  int n = P.sz[b];
  int K = (n >> 1) < 64 ? (n >> 1) : 64;
  bool big = false, eNZ = false, oNZ = false;
  if (lane < K) {
    float e = __bfloat162float(t[2 * lane]);
    float o = __bfloat162float(t[2 * lane + 1]);
    big = !(fabsf(e) <= 1e3f);
    eNZ = (e != 0.f); oNZ = (o != 0.f);
  }
  unsigned long long bb = __ballot(big), eb = __ballot(eNZ), ob = __ballot(oNZ);
  if (lane == 0) flags[b] = (bb != 0ull || (eb == 0ull && ob != 0ull)) ? 1 : 0;
}

__global__ void classidx_k(const int* __restrict__ y, int* __restrict__ idx,
                           int* __restrict__ cnt, int* __restrict__ cstart) {
  __shared__ int sc[NWAY_];
  int tid = threadIdx.x;
  if (tid < NWAY_) sc[tid] = 0;
  __syncthreads();
  for (int i = tid; i < NS_; i += 256) {
    int c = y[i];
    int pos = atomicAdd(&sc[c], 1);
    idx[c * NS_ + pos] = i;
  }
  __syncthreads();
  if (tid < NWAY_) cnt[tid] = sc[tid];
  if (tid == 0) { int s = 0; for (int q = 0; q < NWAY_; ++q) { cstart[q] = s; s += sc[q]; } }
}

__global__ void xcopy_k(const void* __restrict__ sx, const void* __restrict__ qx,
                        short* __restrict__ XC, const int* __restrict__ flags) {
  size_t i = ((size_t)blockIdx.x * 256 + threadIdx.x) * 4;
  const size_t SN = (size_t)NS_ * 512;
  if (i < SN) {
    int f = flags[0];
    #pragma unroll
    for (int q = 0; q < 4; ++q) XC[i + q] = f2bf(ldw(sx, i + q, f));
  } else {
    int f = flags[2];
    size_t j = i - SN;
    #pragma unroll
    for (int q = 0; q < 4; ++q) XC[i + q] = f2bf(ldw(qx, j + q, f));
  }
}

// ---- concat 5 layer-1 weights into Wcat[2304][512] bf16 (TRB layout) + bias cat ----
__global__ void wcat_k(Ptrs P, short* __restrict__ Wcat, float* __restrict__ bcat,
                       const int* __restrict__ flags) {
  int n = blockIdx.x * 256 + threadIdx.x;
  int k = blockIdx.y;
  int iw, ib, nl, Nloc;
  if (n < 512)       { iw = 4;  ib = 5;  nl = n;        Nloc = 512; }
  else if (n < 768)  { iw = 12; ib = 13; nl = n - 512;  Nloc = 256; }
  else if (n < 1536) { iw = 18; ib = 19; nl = n - 768;  Nloc = 768; }
  else if (n < 1792) { iw = 24; ib = 25; nl = n - 1536; Nloc = 256; }
  else               { iw = 30; ib = 31; nl = n - 1792; Nloc = 512; }
  Wcat[(size_t)n * 512 + k] = f2bf(ldw(P.p[iw], (size_t)k * Nloc + nl, flags[iw]));
  if (k == 0) bcat[n] = ldw(P.p[ib], nl, flags[ib]);
}

// ---- Bcat2[a][n][k] bf16 (n<256: cls_w1 rows0-255 col n; n>=256: f_w1 block a col n-256) ----
__global__ void wcls_k(const void* __restrict__ cw1, const void* __restrict__ fw1,
                       short* __restrict__ B2, const int* __restrict__ flags) {
  int n = blockIdx.x, a = blockIdx.y, k = threadIdx.x;  // grid (512, A_), block 256
  float v;
  if (n < 256) v = ldw(cw1, ((size_t)a * 512 + k) * 256 + n, flags[51]);
  else v = ldw(fw1, ((size_t)(a * 256 + k)) * 256 + (n - 256), flags[58]);
  B2[((size_t)a * 512 + n) * 256 + k] = f2bf(v);
}

// ============ MFMA bf16 GEMM ============
// AMODE/BMODE: 0 = f32 static, 1 = runtime dtype (flags), 2 = bf16 pre-converted.
#define LSTR 40
template<int AMODE, int BMODE, bool DYNBIAS, bool TRB, int ACT, bool ACCUM,
         bool KSPLIT = false, bool OUTBF16 = false, bool DOMAP = false>
__global__ __launch_bounds__(256) void gemm_k(
    const void* __restrict__ A, int lda,
    const void* __restrict__ B, int ldb, size_t offB,
    const void* __restrict__ bias, size_t offBias,
    float* __restrict__ C, int ldc,
    int M, int N, int K, float alpha,
    int ia, int ib, int ibias, const int* __restrict__ flags,
    size_t sA, size_t sB, size_t sBias, size_t sC, size_t kstrideA,
    unsigned long long amap)
{
  const int fA = (AMODE == 1) ? flags[ia] : 1;
  const int fB = (BMODE == 1) ? flags[ib] : 1;
  const int fBi = DYNBIAS ? flags[ibias] : 1;
  const size_t zA = (size_t)blockIdx.z * sA;
  const size_t zB = offB + (size_t)blockIdx.z * sB;
  const size_t zBias = offBias + (size_t)blockIdx.z * sBias;
  float* Cz = C + (size_t)blockIdx.z * sC;
  bf16* Cz16 = (bf16*)C + (size_t)blockIdx.z * sC;
  __shared__ short As[128 * LSTR];
  __shared__ short Bs[128 * LSTR];
  const int tid = threadIdx.x;
  const int bm = blockIdx.y * 128, bn = blockIdx.x * 128;
  const int lane = tid & 63, wid = tid >> 6;
  const int lm = lane & 15, quad = lane >> 4;
  const int wy = (wid >> 1) * 64, wx = (wid & 1) * 64;
  f4v acc[4][4];
  #pragma unroll
  for (int i = 0; i < 4; ++i)
    #pragma unroll
    for (int j = 0; j < 4; ++j) acc[i][j] = (f4v)(0.f);

  const int am = tid >> 1, ah = (tid & 1) * 16;

  for (int k0 = 0; k0 < K; k0 += 32) {
    {
      int kk = k0 + ah;
      size_t base;
      if (KSPLIT) base = zA + (size_t)(kk >> 8) * kstrideA + (size_t)(bm + am) * lda + (kk & 255);
      else base = zA + (size_t)(bm + am) * lda + kk;
      if (AMODE == 2) {
        const bf16* ap = (const bf16*)A + base;
        *(s8v*)&As[am * LSTR + ah] = *(const s8v*)ap;
        *(s8v*)&As[am * LSTR + ah + 8] = *(const s8v*)(ap + 8);
      } else {
        short tmp[16];
        if (fA) {
          const float4* src = (const float4*)((const float*)A + base);
          #pragma unroll
          for (int q = 0; q < 4; ++q) {
            float4 v = src[q];
            tmp[q*4+0] = f2bf(v.x); tmp[q*4+1] = f2bf(v.y);
            tmp[q*4+2] = f2bf(v.z); tmp[q*4+3] = f2bf(v.w);
          }
        } else {
          #pragma unroll
          for (int q = 0; q < 16; ++q) tmp[q] = f2bf(ldw(A, base + q, 0));
        }
        s4v* dst = (s4v*)&As[am * LSTR + ah];
        #pragma unroll
        for (int q = 0; q < 4; ++q) dst[q] = *(s4v*)&tmp[q*4];
      }
    }
    if (TRB) {
      int n = tid >> 1, h = (tid & 1) * 16;
      size_t base = zB + (size_t)(bn + n) * ldb + k0 + h;
      if (BMODE == 2) {
        const bf16* bp = (const bf16*)B + base;
        *(s8v*)&Bs[n * LSTR + h] = *(const s8v*)bp;
        *(s8v*)&Bs[n * LSTR + h + 8] = *(const s8v*)(bp + 8);
      } else {
        short tmp[16];
        if (fB) {
          const float4* src = (const float4*)((const float*)B + base);
          #pragma unroll
          for (int q = 0; q < 4; ++q) {
            float4 v = src[q];
            tmp[q*4+0] = f2bf(v.x); tmp[q*4+1] = f2bf(v.y);
            tmp[q*4+2] = f2bf(v.z); tmp[q*4+3] = f2bf(v.w);
          }
        } else {
          #pragma unroll
          for (int q = 0; q < 16; ++q) tmp[q] = f2bf(ldw(B, base + q, 0));
        }
        s4v* dst = (s4v*)&Bs[n * LSTR + h];
        #pragma unroll
        for (int q = 0; q < 4; ++q) dst[q] = *(s4v*)&tmp[q*4];
      }
    } else {
      int n = tid & 127, kk = (tid >> 7) * 16;
      short tmp[16];
      #pragma unroll
      for (int j = 0; j < 16; ++j) {
        size_t bi = zB + (size_t)(k0 + kk + j) * ldb + bn + n;
        if (BMODE == 2) tmp[j] = ((const short*)B)[bi];
        else tmp[j] = f2bf(ldT<BMODE == 1>(B, bi, fB));
      }
      s4v* dst = (s4v*)&Bs[n * LSTR + kk];
      #pragma unroll
      for (int q = 0; q < 4; ++q) dst[q] = *(s4v*)&tmp[q*4];
    }
    __syncthreads();
    s8v af[4], bfr[4];
    #pragma unroll
    for (int mi = 0; mi < 4; ++mi)
      af[mi] = *(const s8v*)&As[(wy + mi*16 + lm) * LSTR + quad * 8];
    #pragma unroll
    for (int ni = 0; ni < 4; ++ni)
      bfr[ni] = *(const s8v*)&Bs[(wx + ni*16 + lm) * LSTR + quad * 8];
    #pragma unroll
    for (int mi = 0; mi < 4; ++mi)
      #pragma unroll
      for (int ni = 0; ni < 4; ++ni)
        acc[mi][ni] = __builtin_amdgcn_mfma_f32_16x16x32_bf16(af[mi], bfr[ni], acc[mi][ni], 0, 0, 0);
    __syncthreads();
  }
  const int actc = DOMAP ? (int)((amap >> ((bn >> 7) * 2)) & 3ULL) : ACT;
  #pragma unroll
  for (int mi = 0; mi < 4; ++mi) {
    #pragma unroll
    for (int r = 0; r < 4; ++r) {
      int row = bm + wy + mi*16 + quad*4 + r;
      #pragma unroll
      for (int ni = 0; ni < 4; ++ni) {
        int col = bn + wx + ni*16 + lm;
        float v = acc[mi][ni][r] * alpha;
        if (ACCUM) v += Cz[(size_t)row * ldc + col];
        if (bias) v += ldT<DYNBIAS>(bias, zBias + col, fBi);
        if (actc == 1) v = fmaxf(v, 0.f);
        else if (actc == 2) v = tanhf(v);
        else if (actc == 3) v = 1.f / (1.f + expf(-v));
        if (OUTBF16) Cz16[(size_t)row * ldc + col] = __float2bfloat16(v);
        else Cz[(size_t)row * ldc + col] = v;
      }
    }
  }
}

template<int AMODE, int BMODE, bool DYNBIAS, bool TRB, int ACT, bool ACCUM,
         bool KSPLIT = false, bool OUTBF16 = false, bool DOMAP = false>
static void gemm(hipStream_t s, const void* A, int lda, const void* B, int ldb, size_t offB,
                 const void* bias, size_t offBias, float* C, int ldc, int M, int N, int K,
                 float alpha, int ia, int ib, int ibias, const int* flags,
                 int batch = 1, size_t sA = 0, size_t sB = 0, size_t sBias = 0, size_t sC = 0,
                 size_t kstrideA = 0, unsigned long long amap = 0) {
  dim3 g(N / 128, M / 128, batch), b(256);
  gemm_k<AMODE, BMODE, DYNBIAS, TRB, ACT, ACCUM, KSPLIT, OUTBF16, DOMAP><<<g, b, 0, s>>>(
      A, lda, B, ldb, offB, bias, offBias, C, ldc, M, N, K, alpha, ia, ib, ibias, flags,
      sA, sB, sBias, sC, kstrideA, amap);
}

// ---------------- LayerNorm (+relu/sigmoid), bf16/f32 in/out, strided ----------------
template<int ACT, bool INBF, bool OUTBF>
__global__ __launch_bounds__(256) void ln_k(const void* __restrict__ X, const void* __restrict__ g,
                                            const void* __restrict__ be, void* __restrict__ Y,
                                            int W, int ldx, int ldy,
                                            int ig, int ibe, const int* __restrict__ flags) {
  const int fG = flags[ig], fBe = flags[ibe];
  int row = blockIdx.x;
  const float* xf = (const float*)X + (size_t)row * ldx;
  const bf16* xb = (const bf16*)X + (size_t)row * ldx;
  float* yf = (float*)Y + (size_t)row * ldy;
  bf16* yb = (bf16*)Y + (size_t)row * ldy;
  __shared__ float red[256];
  int tid = threadIdx.x;
  float s1 = 0.f, s2 = 0.f;
  for (int i = tid; i < W; i += 256) {
    float v = INBF ? __bfloat162float(xb[i]) : xf[i];
    s1 += v; s2 += v * v;
  }
  red[tid] = s1; __syncthreads();
  for (int o = 128; o > 0; o >>= 1) { if (tid < o) red[tid] += red[tid + o]; __syncthreads(); }
  float mean = red[0] / W; __syncthreads();
  red[tid] = s2; __syncthreads();
  for (int o = 128; o > 0; o >>= 1) { if (tid < o) red[tid] += red[tid + o]; __syncthreads(); }
  float var = fmaxf(red[0] / W - mean * mean, 0.f);
  float rstd = rsqrtf(var + 1e-5f);
  for (int i = tid; i < W; i += 256) {
    float x = INBF ? __bfloat162float(xb[i]) : xf[i];
    float v = (x - mean) * rstd * ldw(g, i, fG) + ldw(be, i, fBe);
    if (ACT == 1) v = fmaxf(v, 0.f);
    else if (ACT == 3) v = 1.f / (1.f + expf(-v));
    if (OUTBF) yb[i] = __float2bfloat16(v);
    else yf[i] = v;
  }
}

// ================= comm round =================
__global__ void statepart_k(const short* __restrict__ featsC, float* __restrict__ part) {
  int a = blockIdx.x, g = blockIdx.y, e = threadIdx.x;
  const short* p = featsC + (size_t)a * FSTR + ((size_t)g * 128) * E_ + e;
  float s = 0.f;
  for (int n = 0; n < 128; ++n) s += bf2f(p[(size_t)n * E_]);
  part[((size_t)a * 16 + g) * E_ + e] = s;
}

__global__ void statecomb_k(const float* __restrict__ part, const void* __restrict__ internal,
                            float* __restrict__ state, const int* __restrict__ flags) {
  int a = blockIdx.x, e = threadIdx.x;
  float s = 0.f;
  for (int g = 0; g < 16; ++g) s += part[((size_t)a * 16 + g) * E_ + e];
  state[a * E_ + e] = s * (1.f / NS_) + ldw(internal, (size_t)a * E_ + e, flags[46]);
}

__global__ void mvpart_k(const float* __restrict__ x, const void* __restrict__ W, int iw,
                         float* __restrict__ part, const int* __restrict__ flags) {
  int a = blockIdx.x, g = blockIdx.y, f = threadIdx.x;
  const int fW = flags[iw];
  float s = 0.f;
  size_t wb = (size_t)a * E_ * E_ + f;
  for (int e = g * 32; e < g * 32 + 32; ++e)
    s += x[a * E_ + e] * ldw(W, wb + (size_t)e * E_, fW);
  part[((size_t)a * 8 + g) * E_ + f] = s;
}

template<int ACT>
__global__ void mvcomb_k(const float* __restrict__ part, const void* __restrict__ b, int ibb,
                         float* __restrict__ y, const int* __restrict__ flags) {
  int a = blockIdx.x, f = threadIdx.x;
  float s = 0.f;
  for (int g = 0; g < 8; ++g) s += part[((size_t)a * 8 + g) * E_ + f];
  s += ldw(b, (size_t)a * E_ + f, flags[ibb]);
  if (ACT == 1) s = fmaxf(s, 0.f);
  else if (ACT == 2) s = tanhf(s);
  y[a * E_ + f] = s;
}

__device__ inline float wave_sum64(float v) {
  for (int o = 32; o > 0; o >>= 1) v += __shfl_down(v, o);
  return v;
}

__global__ __launch_bounds__(256) void qkvcomm_k(const float* __restrict__ msg,
                                                 const void* __restrict__ comm_w,
                                                 const void* __restrict__ in_w,
                                                 const void* __restrict__ in_b,
                                                 float* __restrict__ qkvc,
                                                 const int* __restrict__ flags) {
  const int fCW = flags[57], fIW = flags[38], fIB = flags[39];
  int gw = blockIdx.x * 4 + (threadIdx.x >> 6);
  int a = gw / 768, f = gw % 768;
  int lane = threadIdx.x & 63;
  float w[5]; float mx = -1e30f;
  for (int j = 0; j < 5; ++j) { w[j] = ldw(comm_w, a * 5 + j, fCW); mx = fmaxf(mx, w[j]); }
  float sum = 0.f;
  for (int j = 0; j < 5; ++j) { w[j] = __expf(w[j] - mx); sum += w[j]; }
  for (int j = 0; j < 5; ++j) w[j] /= sum;
  int others[4]; { int c = 0; for (int j = 0; j < 5; ++j) if (j != a) others[c++] = j; }
  int e0 = lane * 4;
  float4 wv;
  size_t b = (size_t)a * 768 * E_ + (size_t)f * E_ + e0;
  if (fIW) wv = *(const float4*)((const float*)in_w + b);
  else wv = make_float4(ldw(in_w, b, 0), ldw(in_w, b + 1, 0), ldw(in_w, b + 2, 0), ldw(in_w, b + 3, 0));
  float acc[4];
  #pragma unroll
  for (int t = 0; t < 4; ++t) {
    const float4 mv = *(const float4*)(msg + others[t] * E_ + e0);
    acc[t] = mv.x * wv.x + mv.y * wv.y + mv.z * wv.z + mv.w * wv.w;
  }
  #pragma unroll
  for (int t = 0; t < 4; ++t) acc[t] = wave_sum64(acc[t]);
  if (lane == 0) {
    float bb = ldw(in_b, (size_t)a * 768 + f, fIB);
    #pragma unroll
    for (int t = 0; t < 4; ++t)
      qkvc[((size_t)a * 4 + t) * 768 + f] = acc[t] * w[others[t]] + bb;
  }
}

__global__ __launch_bounds__(256) void attn4_k(const float* __restrict__ qkvc,
                                               float* __restrict__ obar) {
  int a = blockIdx.x, tid = threadIdx.x;
  __shared__ float qkv[4][768];
  __shared__ float attw[4][16];
  for (int i = tid; i < 4 * 768; i += 256) qkv[i / 768][i % 768] = qkvc[(size_t)a * 4 * 768 + i];
  __syncthreads();
  if (tid < 16) {
    int h = tid >> 2, t = tid & 3;
    float sc[4]; float mx = -1e30f;
    for (int t2 = 0; t2 < 4; ++t2) {
      float s = 0.f;
      for (int d = 0; d < 64; ++d) s += qkv[t][h * 64 + d] * qkv[t2][256 + h * 64 + d];
      sc[t2] = s * 0.125f; mx = fmaxf(mx, sc[t2]);
    }
    float ss = 0.f;
    for (int t2 = 0; t2 < 4; ++t2) { sc[t2] = __expf(sc[t2] - mx); ss += sc[t2]; }
    for (int t2 = 0; t2 < 4; ++t2) attw[h][t * 4 + t2] = sc[t2] / ss;
  }
  __syncthreads();
  {
    int e = tid, h = e >> 6;
    float s = 0.f;
    for (int t = 0; t < 4; ++t)
      for (int t2 = 0; t2 < 4; ++t2)
        s += attw[h][t * 4 + t2] * qkv[t2][512 + e];
    obar[a * E_ + e] = s * 0.25f;
  }
}

__global__ __launch_bounds__(256) void combproj_k(const float* __restrict__ obar,
                                                  const void* __restrict__ ow,
                                                  const void* __restrict__ ob,
                                                  const void* __restrict__ internal,
                                                  float* __restrict__ comb,
                                                  const int* __restrict__ flags) {
  const int fOW = flags[40], fOB = flags[41], fIN = flags[46];
  int gw = blockIdx.x * 4 + (threadIdx.x >> 6);
  int a = gw >> 8, f = gw & 255;
  int lane = threadIdx.x & 63;
  int e0 = lane * 4;
  float4 wv;
  size_t b = (size_t)a * E_ * E_ + (size_t)f * E_ + e0;
  if (fOW) wv = *(const float4*)((const float*)ow + b);
  else wv = make_float4(ldw(ow, b, 0), ldw(ow, b + 1, 0), ldw(ow, b + 2, 0), ldw(ow, b + 3, 0));
  const float4 ov = *(const float4*)(obar + a * E_ + e0);
  float s = wave_sum64(ov.x * wv.x + ov.y * wv.y + ov.z * wv.z + ov.w * wv.w);
  if (lane == 0)
    comb[a * E_ + f] = ldw(internal, (size_t)a * E_ + f, fIN) + s + ldw(ob, (size_t)a * E_ + f, fOB);
}

__global__ __launch_bounds__(256) void ckb_k(const float* __restrict__ ck,
                                             const void* __restrict__ in_w,
                                             const void* __restrict__ in_b,
                                             float* __restrict__ ckb,
                                             const int* __restrict__ flags) {
  const int fW = flags[47], fB = flags[48];
  int gw = blockIdx.x * 4 + (threadIdx.x >> 6);
  int a = gw / 768, f = gw % 768;
  int lane = threadIdx.x & 63;
  int e0 = lane * 4;
  float4 wv;
  size_t b = (size_t)a * 768 * E_ + (size_t)f * E_ + e0;
  if (fW) wv = *(const float4*)((const float*)in_w + b);
  else wv = make_float4(ldw(in_w, b, 0), ldw(in_w, b + 1, 0), ldw(in_w, b + 2, 0), ldw(in_w, b + 3, 0));
  const float4 cv = *(const float4*)(ck + a * E_ + e0);
  float s = wave_sum64(cv.x * wv.x + cv.y * wv.y + cv.z * wv.z + cv.w * wv.w);
  if (lane == 0) ckb[(size_t)a * 768 + f] = s + ldw(in_b, (size_t)a * 768 + f, fB);
}

// ======== MFMA class-block attention (qkv_all is bf16) ========
#define LS 136
__device__ inline void stage64x128(const short* __restrict__ qkv, const int* __restrict__ myidx,
                                   int row0, int n, int ho, short* dst) {
  int t = threadIdx.x;
  int r = t >> 2, c0 = (t & 3) * 32;
  int rr = row0 + r;
  s8v v0 = (s8v)(short)0, v1 = v0, v2 = v0, v3 = v0;
  if (rr < n) {
    const s8v* s = (const s8v*)(qkv + (size_t)myidx[rr] * 768 + ho + c0);
    v0 = s[0]; v1 = s[1]; v2 = s[2]; v3 = s[3];
  }
  s8v* d = (s8v*)&dst[r * LS + c0];
  d[0] = v0; d[1] = v1; d[2] = v2; d[3] = v3;
}

__global__ __launch_bounds__(256) void attn_stats_k(
    const short* __restrict__ qkv_all, const int* __restrict__ idx,
    const int* __restrict__ cnt, const int* __restrict__ cstart,
    float* __restrict__ ml)
{
  int c = blockIdx.x, z = blockIdx.z, a = z >> 1, h = z & 1;
  int n = cnt[c];
  int r0 = blockIdx.y * 64;
  if (r0 >= n) return;
  const short* qkv = qkv_all + (size_t)a * NS_ * 768;
  const int* myidx = idx + c * NS_;
  __shared__ short Qs[64 * LS];
  __shared__ short Ks[64 * LS];
  __shared__ float Mw[4][64], Lw[4][64];
  int tid = threadIdx.x, lane = tid & 63, wid = tid >> 6;
  int lm = lane & 15, quad = lane >> 4;
  stage64x128(qkv, myidx, r0, n, h * 128, Qs);
  float m_run[16], l_run[16];
  #pragma unroll
  for (int i = 0; i < 16; ++i) { m_run[i] = -3e38f; l_run[i] = 0.f; }
  for (int j0 = 0; j0 < n; j0 += 64) {
    __syncthreads();
    stage64x128(qkv, myidx, j0, n, 256 + h * 128, Ks);
    __syncthreads();
    f4v acc[4];
    #pragma unroll
    for (int mi = 0; mi < 4; ++mi) acc[mi] = (f4v)(0.f);
    #pragma unroll
    for (int kc = 0; kc < 4; ++kc) {
      s8v bfr = *(const s8v*)&Ks[(wid * 16 + lm) * LS + kc * 32 + quad * 8];
      #pragma unroll
      for (int mi = 0; mi < 4; ++mi) {
        s8v af = *(const s8v*)&Qs[(mi * 16 + lm) * LS + kc * 32 + quad * 8];
        acc[mi] = __builtin_amdgcn_mfma_f32_16x16x32_bf16(af, bfr, acc[mi], 0, 0, 0);
      }
    }
    int col = j0 + wid * 16 + lm;
    bool cv = col < n;
    #pragma unroll
    for (int mi = 0; mi < 4; ++mi) {
      #pragma unroll
      for (int r = 0; r < 4; ++r) {
        float s = cv ? acc[mi][r] * QSCALE : -3e38f;
        float m = s;
        m = fmaxf(m, __shfl_xor(m, 1));
        m = fmaxf(m, __shfl_xor(m, 2));
        m = fmaxf(m, __shfl_xor(m, 4));
        m = fmaxf(m, __shfl_xor(m, 8));
        float p = cv ? __expf(s - m) : 0.f;
        p += __shfl_xor(p, 1); p += __shfl_xor(p, 2);
        p += __shfl_xor(p, 4); p += __shfl_xor(p, 8);
        int ri = mi * 4 + r;
        float mo = m_run[ri];
        float mn = fmaxf(mo, m);
        l_run[ri] = l_run[ri] * __expf(mo - mn) + p * __expf(m - mn);
        m_run[ri] = mn;
      }
    }
  }
  if (lm == 0) {
    #pragma unroll
    for (int mi = 0; mi < 4; ++mi)
      #pragma unroll
      for (int r = 0; r < 4; ++r) {
        int row = mi * 16 + quad * 4 + r;
        Mw[wid][row] = m_run[mi * 4 + r];
        Lw[wid][row] = l_run[mi * 4 + r];
      }
  }
  __syncthreads();
  if (tid < 64 && r0 + tid < n) {
    float m = fmaxf(fmaxf(Mw[0][tid], Mw[1][tid]), fmaxf(Mw[2][tid], Mw[3][tid]));
    float l = Lw[0][tid] * __expf(Mw[0][tid] - m) + Lw[1][tid] * __expf(Mw[1][tid] - m)
            + Lw[2][tid] * __expf(Mw[2][tid] - m) + Lw[3][tid] * __expf(Mw[3][tid] - m);
    size_t p = (size_t)z * NS_ + cstart[c] + r0 + tid;
    ml[p * 2] = m; ml[p * 2 + 1] = l;
  }
}

__global__ __launch_bounds__(256) void attn_colsum_k(
    const short* __restrict__ qkv_all, const int* __restrict__ idx,
    const int* __restrict__ cnt, const int* __restrict__ cstart,
    const float* __restrict__ ml, float* __restrict__ colsum)
{
  int c = blockIdx.x, z = blockIdx.z, a = z >> 1, h = z & 1;
  int n = cnt[c];
  int j0 = blockIdx.y * 64;
  if (j0 >= n) return;
  const short* qkv = qkv_all + (size_t)a * NS_ * 768;
  const int* myidx = idx + c * NS_;
  __shared__ short Qs[64 * LS];
  __shared__ short Ks[64 * LS];
  __shared__ float Msm[64], Lsm[64];
  int tid = threadIdx.x, lane = tid & 63, wid = tid >> 6;
  int lm = lane & 15, quad = lane >> 4;
  stage64x128(qkv, myidx, j0, n, 256 + h * 128, Ks);
  float ca = 0.f;
  for (int i0 = 0; i0 < n; i0 += 64) {
    __syncthreads();
    stage64x128(qkv, myidx, i0, n, h * 128, Qs);
    if (tid < 64) {
      int gi = i0 + tid;
      if (gi < n) {
        size_t p = (size_t)z * NS_ + cstart[c] + gi;
        Msm[tid] = ml[p * 2]; Lsm[tid] = ml[p * 2 + 1];
      } else { Msm[tid] = 0.f; Lsm[tid] = 1.f; }
    }
    __syncthreads();
    f4v acc[4];
    #pragma unroll
    for (int mi = 0; mi < 4; ++mi) acc[mi] = (f4v)(0.f);
    #pragma unroll
    for (int kc = 0; kc < 4; ++kc) {
      s8v bfr = *(const s8v*)&Ks[(wid * 16 + lm) * LS + kc * 32 + quad * 8];
      #pragma unroll
      for (int mi = 0; mi < 4; ++mi) {
        s8v af = *(const s8v*)&Qs[(mi * 16 + lm) * LS + kc * 32 + quad * 8];
        acc[mi] = __builtin_amdgcn_mfma_f32_16x16x32_bf16(af, bfr, acc[mi], 0, 0, 0);
      }
    }
    #pragma unroll
    for (int mi = 0; mi < 4; ++mi) {
      #pragma unroll
      for (int r = 0; r < 4; ++r) {
        int lrow = mi * 16 + quad * 4 + r;
        int gi = i0 + lrow;
        if (gi < n) {
          float m = Msm[lrow];
          float invl = 1.f / Lsm[lrow];
          ca += __expf(acc[mi][r] * QSCALE - m) * invl;
        }
      }
    }
  }
  ca += __shfl_xor(ca, 16);
  ca += __shfl_xor(ca, 32);
  int col = j0 + wid * 16 + lm;
  if (quad == 0 && col < n)
    colsum[(size_t)z * NS_ + cstart[c] + col] = ca;
}

// ---- proto combine: K-chunked 2-stage ----
#define PCH 8
__global__ void proto_part_k(const short* __restrict__ qkv_all, const int* __restrict__ idx,
                             const int* __restrict__ cnt, const int* __restrict__ cstart,
                             const float* __restrict__ colsum, float* __restrict__ part) {
  int c = blockIdx.x, a = blockIdx.y, ch = blockIdx.z;
  int e = threadIdx.x, h = e >> 7, d = e & 127;
  int n = cnt[c];
  int k0 = ch * 256, k1 = min(k0 + 256, n);
  float s = 0.f;
  const short* qkv = qkv_all + (size_t)a * NS_ * 768;
  const float* csum = colsum + (size_t)(a * 2 + h) * NS_ + cstart[c];
  const int* myidx = idx + c * NS_;
  for (int k = k0; k < k1; ++k)
    s += csum[k] * bf2f(qkv[(size_t)myidx[k] * 768 + 512 + h * 128 + d]);
  part[(((size_t)a * NWAY_ + c) * PCH + ch) * E_ + e] = s;
}

__global__ void proto_comb2_k(const float* __restrict__ part, const int* __restrict__ cnt,
                              float* __restrict__ proto_pre) {
  int c = blockIdx.x, a = blockIdx.y, e = threadIdx.x;
  int n = cnt[c];
  float s = 0.f;
  for (int ch = 0; ch < PCH; ++ch)
    s += part[(((size_t)a * NWAY_ + c) * PCH + ch) * E_ + e];
  proto_pre[((size_t)a * NWAY_ + c) * E_ + e] = (n > 0) ? s / (float)n : 0.f;
}

__global__ void proto_outproj_k(const float* __restrict__ proto_pre, const void* __restrict__ ow,
                                const void* __restrict__ ob, const int* __restrict__ cnt,
                                float* __restrict__ protos_all, const int* __restrict__ flags) {
  int c = blockIdx.x, a = blockIdx.y, e = threadIdx.x;
  const int fW = flags[49], fB = flags[50];
  __shared__ float pp[E_];
  pp[e] = proto_pre[((size_t)a * NWAY_ + c) * E_ + e];
  __syncthreads();
  size_t wb = (size_t)a * E_ * E_ + (size_t)e * E_;
  float s = 0.f;
  for (int k = 0; k < E_; ++k) s += pp[k] * ldw(ow, wb + k, fW);
  float v = s + ldw(ob, (size_t)a * E_ + e, fB);
  protos_all[((size_t)a * NWAY_ + c) * E_ + e] = (cnt[c] > 0) ? v : 0.f;
}

// ---- biascat2[a][0:256] = ck@w1[256:512] + b1; [256:512] = 0 ----
__global__ void bias2_k(const float* __restrict__ ck, const void* __restrict__ w1,
                        const void* __restrict__ b1, float* __restrict__ biascat2,
                        const int* __restrict__ flags) {
  const int fW = flags[51], fB = flags[52];
  int a = blockIdx.x, n = threadIdx.x;
  __shared__ float c[E_];
  c[n] = ck[a * E_ + n]; __syncthreads();
  size_t wbase = (size_t)a * 2 * E_ * E_ + (size_t)E_ * E_ + n;
  float s = 0.f;
  for (int k = 0; k < E_; ++k) s += c[k] * ldw(w1, wbase + (size_t)k * E_, fW);
  biascat2[(size_t)a * 512 + n] = s + ldw(b1, (size_t)a * E_ + n, fB);
  biascat2[(size_t)a * 512 + 256 + n] = 0.f;
}

// ---- fusion combine: fh1 = relu(sum_a U[a][:,256:512] + f_b1) ----
__global__ void fcomb_k(const short* __restrict__ U, const void* __restrict__ b1,
                        short* __restrict__ fh1, const int* __restrict__ flags) {
  int i = blockIdx.x, n = threadIdx.x;
  const int fB = flags[59];
  float s = 0.f;
  #pragma unroll
  for (int a = 0; a < A_; ++a)
    s += bf2f(U[((size_t)a * NQ_ + i) * 512 + 256 + n]);
  s += ldw(b1, n, fB);
  fh1[(size_t)i * 256 + n] = f2bf(fmaxf(s, 0.f));
}

// ---------------- epilogues ----------------
__global__ __launch_bounds__(64) void logits_k(const short* __restrict__ fqbase,
                                               const float* __restrict__ protos_all,
                                               const bf16* __restrict__ c2all,
                                               const void* __restrict__ w3,
                                               const void* __restrict__ b3,
                                               float* __restrict__ out,
                                               const int* __restrict__ flags) {
  const int fW = flags[55], fB = flags[56];
  int i = blockIdx.x, a = blockIdx.y, lane = threadIdx.x;
  const short* fq = fqbase + (size_t)a * FSTR + (size_t)i * E_ + lane * 4;
  const float* protos = protos_all + (size_t)a * NWAY_ * E_;
  const bf16* c2 = c2all + ((size_t)a * NQ_ + i) * 128;
  s4v xv4 = *(const s4v*)fq;
  float x0 = bf2f(xv4[0]), x1 = bf2f(xv4[1]), x2 = bf2f(xv4[2]), x3 = bf2f(xv4[3]);
  float qq = wave_sum64(x0 * x0 + x1 * x1 + x2 * x2 + x3 * x3);
  float cpart = __bfloat162float(c2[lane * 2]) * ldw(w3, (size_t)a * 128 + lane * 2, fW) +
                __bfloat162float(c2[lane * 2 + 1]) * ldw(w3, (size_t)a * 128 + lane * 2 + 1, fW);
  float conf = wave_sum64(cpart);
  if (lane == 0) conf += ldw(b3, a, fB);
  for (int c = 0; c < NWAY_; ++c) {
    float4 pv = ((const float4*)(protos + c * E_))[lane];
    float dt = wave_sum64(x0 * pv.x + x1 * pv.y + x2 * pv.z + x3 * pv.w);
    float pp = wave_sum64(pv.x * pv.x + pv.y * pv.y + pv.z * pv.z + pv.w * pv.w);
    if (lane == 0) {
      float d2 = fmaxf(qq + pp - 2.f * dt, 1e-12f);
      out[((size_t)a * NQ_ + i) * NWAY_ + c] = -sqrtf(d2) + 0.1f * conf;
    }
  }
}

__global__ __launch_bounds__(64) void fused_k(const float* __restrict__ h2, const void* __restrict__ w3,
                                              const void* __restrict__ b3, float* __restrict__ out,
                                              const int* __restrict__ flags) {
  const int fW = flags[62], fB = flags[63];
  int i = blockIdx.x, lane = threadIdx.x;
  float s = h2[(size_t)i * 128 + lane * 2] * ldw(w3, lane * 2, fW) +
            h2[(size_t)i * 128 + lane * 2 + 1] * ldw(w3, lane * 2 + 1, fW);
  s = wave_sum64(s);
  if (lane == 0) out[i] = s + ldw(b3, 0, fB);
}

// ---------------- host ----------------
extern "C" void kernel_launch(void* const* d_in, const int* in_sizes, int n_in,
                              void* d_out, int out_size, void* d_ws, size_t ws_size,
                              hipStream_t stream) {
  (void)out_size; (void)ws_size;
  #define P(i) ((const void*)d_in[i])
  const int* support_y = (const int*)d_in[1];
  float* out = (float*)d_out;

  int* flags = (int*)d_ws;
  char* base = (char*)d_ws + 256;
  // featsC bf16 [A][NM][E] = 26,214,400 B
  short* featsC = (short*)base;
  // R region 57,671,680 B
  char* R = base + (size_t)A_ * FSTR * 2;
  short* t1cat   = (short*)R;                          // [NM][2304] bf16 (FE phase)
  short* qkv_all = (short*)R;                          // [A][NS][768] bf16 (15.7 MB)
  short* U       = (short*)(R + (size_t)15728640);     // [A][NQ][512] bf16 (41.9 MB)
  short* fh1     = (short*)R;                          // [NQ][256] bf16 (post-proto)
  float* fh2     = (float*)(R + (size_t)8388608);      // [NQ][128] f32
  // XCR region 10,485,760 B
  char* XCR = R + (size_t)57671680;
  short* XC   = (short*)XCR;
  short* tmp2 = (short*)XCR;
  short* b4   = (short*)(XCR + (size_t)NM_ * 256 * 2);
  short* clsC2_all = (short*)XCR;
  // smalls
  char* S = XCR + (size_t)10485760;
  float* state      = (float*)S;
  float* msg        = state + A_ * E_;
  float* ck         = msg + A_ * E_;
  float* protos_all = ck + A_ * E_;
  float* biascat2   = protos_all + A_ * NWAY_ * E_;    // A*512
  float* ml         = biascat2 + A_ * 512;
  float* colsum     = ml + (size_t)A_ * 2 * NS_ * 2;
  float* proto_pre  = colsum + (size_t)A_ * 2 * NS_;
  int*   idx        = (int*)(proto_pre + A_ * NWAY_ * E_);
  int*   cnt        = idx + NWAY_ * NS_;
  int*   cstart     = cnt + NWAY_;
  float* statepart  = (float*)(cstart + NWAY_ + 3);
  float* mvp        = statepart + A_ * 16 * E_;
  float* qkvc       = mvp + A_ * 8 * E_;
  float* obar       = qkvc + A_ * 4 * 768;
  float* comb       = obar + A_ * E_;
  float* hh         = comb + A_ * E_;
  float* ckb        = hh + A_ * E_;
  float* ppart      = ckb + A_ * 768;
  float* bcat       = ppart + (size_t)A_ * NWAY_ * PCH * E_;
  short* Wcat       = (short*)(bcat + 2304);                    // [2304][512] bf16
  short* Bcat2      = Wcat + (size_t)2304 * 512;                // [A][512][256] bf16

  const short* fq_base = featsC + (size_t)NS_ * E_;

  Ptrs ps;
  for (int i = 0; i < 64; ++i) {
    ps.p[i] = (i < n_in) ? d_in[i] : nullptr;
    ps.sz[i] = (i < n_in) ? in_sizes[i] : 0;
  }
  probe_k<<<64, 64, 0, stream>>>(ps, flags);
  classidx_k<<<1, 256, 0, stream>>>(support_y, idx, cnt, cstart);
  xcopy_k<<<(NM_ * 512 / 4) / 256, 256, 0, stream>>>(P(0), P(2), XC, flags);
  wcat_k<<<dim3(9, 512), 256, 0, stream>>>(ps, Wcat, bcat, flags);
  wcls_k<<<dim3(512, A_), 256, 0, stream>>>(P(51), P(58), Bcat2, flags);

  // ---- FE: mega layer-1 GEMM (N = 2304), per-tile act map: tiles 6..17 relu ----
  gemm<2, 2, false, true, 0, false, false, true, true>(
      stream, XC, 512, Wcat, 512, 0, bcat, 0, (float*)t1cat, 2304,
      NM_, 2304, 512, 1.f, -1, -1, -1, flags, 1, 0, 0, 0, 0, 0, 0x555555000ULL);
  ln_k<1, true, true><<<NM_, 256, 0, stream>>>(t1cat, P(6), P(7), t1cat, 512, 2304, 2304, 6, 7, flags);
  gemm<2, 1, true, false, 0, false, false, true>(stream, t1cat, 2304, P(8), 256, 0, P(9), 0,
                                                 (float*)tmp2, 256, NM_, 256, 512, 1.f, -1, 8, 9, flags);
  ln_k<1, true, true><<<NM_, 256, 0, stream>>>(tmp2, P(10), P(11), featsC, 256, 256, 256, 10, 11, flags);
  ln_k<1, true, true><<<NM_, 256, 0, stream>>>(t1cat + 512, P(14), P(15), t1cat + 512, 256, 2304, 2304, 14, 15, flags);
  gemm<2, 1, true, false, 2, false, false, true>(stream, t1cat + 512, 2304, P(16), 256, 0, P(17), 0,
                                                 (float*)(featsC + FSTR), 256, NM_, 256, 256, 1.f, -1, 16, 17, flags);
  gemm<2, 1, true, false, 0, false, false, true>(stream, t1cat + 768, 2304, P(20), 256, 0, P(21), 0,
                                                 (float*)tmp2, 256, NM_, 256, 768, 1.f, -1, 20, 21, flags);
  ln_k<1, true, true><<<NM_, 256, 0, stream>>>(tmp2, P(22), P(23), featsC + 2 * FSTR, 256, 256, 256, 22, 23, flags);
  gemm<2, 1, true, false, 0, false, false, true>(stream, t1cat + 1536, 2304, P(26), 256, 0, P(27), 0,
                                                 (float*)tmp2, 256, NM_, 256, 256, 1.f, -1, 26, 27, flags);
  ln_k<3, true, true><<<NM_, 256, 0, stream>>>(tmp2, P(28), P(29), featsC + 3 * FSTR, 256, 256, 256, 28, 29, flags);
  gemm<2, 1, true, false, 1, false, false, true>(stream, t1cat + 1792, 2304, P(32), 256, 0, P(33), 0,
                                                 (float*)b4, 256, NM_, 256, 512, 1.f, -1, 32, 33, flags);
  gemm<2, 1, true, false, 0, false, false, true>(stream, b4, 256, P(34), 256, 0, P(35), 0,
                                                 (float*)(featsC + 4 * FSTR), 256, NM_, 256, 256, 1.f, -1, 34, 35, flags);

  // ---- comm round ----
  statepart_k<<<dim3(A_, 16), 256, 0, stream>>>(featsC, statepart);
  statecomb_k<<<A_, 256, 0, stream>>>(statepart, P(46), state, flags);
  mvpart_k<<<dim3(A_, 8), 256, 0, stream>>>(state, P(36), 36, mvp, flags);
  mvcomb_k<2><<<A_, 256, 0, stream>>>(mvp, P(37), 37, msg, flags);
  qkvcomm_k<<<A_ * 768 / 4, 256, 0, stream>>>(msg, P(57), P(38), P(39), qkvc, flags);
  attn4_k<<<A_, 256, 0, stream>>>(qkvc, obar);
  combproj_k<<<A_ * E_ / 4, 256, 0, stream>>>(obar, P(40), P(41), P(46), comb, flags);
  mvpart_k<<<dim3(A_, 8), 256, 0, stream>>>(comb, P(42), 42, mvp, flags);
  mvcomb_k<1><<<A_, 256, 0, stream>>>(mvp, P(43), 43, hh, flags);
  mvpart_k<<<dim3(A_, 8), 256, 0, stream>>>(hh, P(44), 44, mvp, flags);
  mvcomb_k<0><<<A_, 256, 0, stream>>>(mvp, P(45), 45, ck, flags);

  // ---- batched prototype attention (ck folded into qkv bias; qkv bf16) ----
  ckb_k<<<A_ * 768 / 4, 256, 0, stream>>>(ck, P(47), P(48), ckb, flags);
  gemm<2, 1, false, true, 0, false, false, true>(stream, featsC, 256, P(47), 256, 0, ckb, 0,
                                    (float*)qkv_all, 768, NS_, 768, 256, 1.f, -1, 47, -1, flags,
                                    A_, FSTR, (size_t)3 * E_ * E_, (size_t)768, (size_t)NS_ * 768);
  {
    dim3 g(NWAY_, NS_ / 64, A_ * 2);
    attn_stats_k<<<g, 256, 0, stream>>>(qkv_all, idx, cnt, cstart, ml);
    attn_colsum_k<<<g, 256, 0, stream>>>(qkv_all, idx, cnt, cstart, ml, colsum);
  }
  proto_part_k<<<dim3(NWAY_, A_, PCH), 256, 0, stream>>>(qkv_all, idx, cnt, cstart, colsum, ppart);
  proto_comb2_k<<<dim3(NWAY_, A_), 256, 0, stream>>>(ppart, cnt, proto_pre);
  proto_outproj_k<<<dim3(NWAY_, A_), 256, 0, stream>>>(proto_pre, P(49), P(50), cnt, protos_all, flags);
  bias2_k<<<A_, 256, 0, stream>>>(ck, P(51), P(52), biascat2, flags);

  // ---- combined cls1 + fusion-partial GEMM: U[a] = act_map(fq[a] @ [cls_w1|f_w1] + [bias2|0]) ----
  gemm<2, 2, false, true, 0, false, false, true, true>(
      stream, fq_base, 256, Bcat2, 256, 0, biascat2, 0, (float*)U, 512,
      NQ_, 512, 256, 1.f, -1, -1, -1, flags,
      A_, FSTR, (size_t)512 * 256, (size_t)512, (size_t)NQ_ * 512, 0, 0x5ULL);
  // fusion: sum partials + bias + relu -> fh1 bf16 (after proto_part: fh1 overlays qkv_all)
  fcomb_k<<<NQ_, 256, 0, stream>>>(U, P(59), fh1, flags);

  // ---- cls2 (A = U cols 0..255, lda=512) + logits ----
  gemm<2, 1, true, false, 1, false, false, true>(stream, U, 512, P(53), 128, 0,
                                     P(54), 0, (float*)clsC2_all, 128, NQ_, 128, 256, 1.f, -1, 53, 54, flags,
                                     A_, (size_t)NQ_ * 512, (size_t)E_ * 128, (size_t)128, (size_t)NQ_ * 128);
  logits_k<<<dim3(NQ_, A_), 64, 0, stream>>>(fq_base, protos_all, (const bf16*)clsC2_all, P(55), P(56), out, flags);

  // ---- fusion layer-2 + output ----
  gemm<2, 1, true, false, 1, false>(stream, fh1, 256, P(60), 128, 0, P(61), 0, fh2, 128, NQ_, 128, 256, 1.f, -1, 60, 61, flags);
  fused_k<<<NQ_, 64, 0, stream>>>(fh2, P(62), P(63), out + (size_t)A_ * NQ_ * NWAY_, flags);
}

// Round 11
// 961.543 us; speedup vs baseline: 7.1951x; 1.0268x over previous
//
#include <hip/hip_runtime.h>
#include <hip/hip_bf16.h>

typedef __hip_bfloat16 bf16;
typedef short s8v __attribute__((ext_vector_type(8)));
typedef short s4v __attribute__((ext_vector_type(4)));
typedef float f4v __attribute__((ext_vector_type(4)));

#define A_  5
#define D_  512
#define E_  256
#define NS_ 2048
#define NQ_ 8192
#define NM_ 10240
#define NWAY_ 5
#define QSCALE 0.088388347648318447f
#define FSTR ((size_t)NM_ * E_)

__device__ inline float ldw(const void* p, size_t i, int f32) {
  return f32 ? ((const float*)p)[i] : __bfloat162float(((const bf16*)p)[i]);
}
template<bool DYN>
__device__ inline float ldT(const void* p, size_t i, int f32) {
  if (DYN) return ldw(p, i, f32);
  return ((const float*)p)[i];
}

__device__ inline short f2bf(float v) {
  union { float f; unsigned u; } x; x.f = v;
  unsigned r = x.u + 0x7fffu + ((x.u >> 16) & 1u);
  return (short)(r >> 16);
}
__device__ inline float bf2f(short s) {
  union { unsigned u; float f; } x; x.u = ((unsigned)(unsigned short)s) << 16;
  return x.f;
}

struct Ptrs { const void* p[64]; int sz[64]; };

__global__ void probe_k(Ptrs P, int* flags) {
  int b = blockIdx.x, lane = threadIdx.x;
  if (b == 1 || b == 3) { if (lane == 0) flags[b] = 0; return; }
  const bf16* t = (const bf16*)P.p[b];
  int n = P.sz[b];
  int K = (n >> 1) < 64 ? (n >> 1) : 64;
  bool big = false, eNZ = false, oNZ = false;
  if (lane < K) {
    float e = __bfloat162float(t[2 * lane]);
    float o = __bfloat162float(t[2 * lane + 1]);
    big = !(fabsf(e) <= 1e3f);
    eNZ = (e != 0.f); oNZ = (o != 0.f);
  }
  unsigned long long bb = __ballot(big), eb = __ballot(eNZ), ob = __ballot(oNZ);
  if (lane == 0) flags[b] = (bb != 0ull || (eb == 0ull && ob != 0ull)) ? 1 : 0;
}

__global__ void classidx_k(const int* __restrict__ y, int* __restrict__ idx,
                           int* __restrict__ cnt, int* __restrict__ cstart) {
  __shared__ int sc[NWAY_];
  int tid = threadIdx.x;
  if (tid < NWAY_) sc[tid] = 0;
  __syncthreads();
  for (int i = tid; i < NS_; i += 256) {
    int c = y[i];
    int pos = atomicAdd(&sc[c], 1);
    idx[c * NS_ + pos] = i;
  }
  __syncthreads();
  if (tid < NWAY_) cnt[tid] = sc[tid];
  if (tid == 0) { int s = 0; for (int q = 0; q < NWAY_; ++q) { cstart[q] = s; s += sc[q]; } }
}

__global__ void xcopy_k(const void* __restrict__ sx, const void* __restrict__ qx,
                        short* __restrict__ XC, const int* __restrict__ flags) {
  size_t i = ((size_t)blockIdx.x * 256 + threadIdx.x) * 4;
  const size_t SN = (size_t)NS_ * 512;
  if (i < SN) {
    int f = flags[0];
    #pragma unroll
    for (int q = 0; q < 4; ++q) XC[i + q] = f2bf(ldw(sx, i + q, f));
  } else {
    int f = flags[2];
    size_t j = i - SN;
    #pragma unroll
    for (int q = 0; q < 4; ++q) XC[i + q] = f2bf(ldw(qx, j + q, f));
  }
}

// ---- concat 5 layer-1 weights into Wcat[2304][512] bf16 (TRB layout) + bias cat ----
__global__ void wcat_k(Ptrs P, short* __restrict__ Wcat, float* __restrict__ bcat,
                       const int* __restrict__ flags) {
  int n = blockIdx.x * 256 + threadIdx.x;
  int k = blockIdx.y;
  int iw, ib, nl, Nloc;
  if (n < 512)       { iw = 4;  ib = 5;  nl = n;        Nloc = 512; }
  else if (n < 768)  { iw = 12; ib = 13; nl = n - 512;  Nloc = 256; }
  else if (n < 1536) { iw = 18; ib = 19; nl = n - 768;  Nloc = 768; }
  else if (n < 1792) { iw = 24; ib = 25; nl = n - 1536; Nloc = 256; }
  else               { iw = 30; ib = 31; nl = n - 1792; Nloc = 512; }
  Wcat[(size_t)n * 512 + k] = f2bf(ldw(P.p[iw], (size_t)k * Nloc + nl, flags[iw]));
  if (k == 0) bcat[n] = ldw(P.p[ib], nl, flags[ib]);
}

// ---- Bcat2[a][n][k] bf16 ----
__global__ void wcls_k(const void* __restrict__ cw1, const void* __restrict__ fw1,
                       short* __restrict__ B2, const int* __restrict__ flags) {
  int n = blockIdx.x, a = blockIdx.y, k = threadIdx.x;
  float v;
  if (n < 256) v = ldw(cw1, ((size_t)a * 512 + k) * 256 + n, flags[51]);
  else v = ldw(fw1, ((size_t)(a * 256 + k)) * 256 + (n - 256), flags[58]);
  B2[((size_t)a * 512 + n) * 256 + k] = f2bf(v);
}

// ============ MFMA bf16 GEMM, software-pipelined staging ============
// AMODE/BMODE: 0 = f32 static, 1 = runtime dtype (flags), 2 = bf16 pre-converted.
#define LSTR 40
template<int AMODE, int BMODE, bool DYNBIAS, bool TRB, int ACT, bool ACCUM,
         bool KSPLIT = false, bool OUTBF16 = false, bool DOMAP = false>
__global__ __launch_bounds__(256) void gemm_k(
    const void* __restrict__ A, int lda,
    const void* __restrict__ B, int ldb, size_t offB,
    const void* __restrict__ bias, size_t offBias,
    float* __restrict__ C, int ldc,
    int M, int N, int K, float alpha,
    int ia, int ib, int ibias, const int* __restrict__ flags,
    size_t sA, size_t sB, size_t sBias, size_t sC, size_t kstrideA,
    unsigned long long amap)
{
  const int fA = (AMODE == 1) ? flags[ia] : 1;
  const int fB = (BMODE == 1) ? flags[ib] : 1;
  const int fBi = DYNBIAS ? flags[ibias] : 1;
  const size_t zA = (size_t)blockIdx.z * sA;
  const size_t zB = offB + (size_t)blockIdx.z * sB;
  const size_t zBias = offBias + (size_t)blockIdx.z * sBias;
  float* Cz = C + (size_t)blockIdx.z * sC;
  bf16* Cz16 = (bf16*)C + (size_t)blockIdx.z * sC;
  __shared__ short As[128 * LSTR];
  __shared__ short Bs[128 * LSTR];
  const int tid = threadIdx.x;
  const int bm = blockIdx.y * 128, bn = blockIdx.x * 128;
  const int lane = tid & 63, wid = tid >> 6;
  const int lm = lane & 15, quad = lane >> 4;
  const int wy = (wid >> 1) * 64, wx = (wid & 1) * 64;
  f4v acc[4][4];
  #pragma unroll
  for (int i = 0; i < 4; ++i)
    #pragma unroll
    for (int j = 0; j < 4; ++j) acc[i][j] = (f4v)(0.f);

  const int am = tid >> 1, ah = (tid & 1) * 16;

  // ---- prefetch registers ----
  s8v a_s0, a_s1;      // AMODE==2
  float a_f[16];       // f32 / runtime paths
  s8v b_s0, b_s1;      // BMODE==2 && TRB
  float b_f[16];       // f32 / runtime / strided paths
  short b_h[16];       // BMODE==2 && !TRB

  auto loadA = [&](int k0) {
    int kk = k0 + ah;
    size_t base;
    if (KSPLIT) base = zA + (size_t)(kk >> 8) * kstrideA + (size_t)(bm + am) * lda + (kk & 255);
    else base = zA + (size_t)(bm + am) * lda + kk;
    if constexpr (AMODE == 2) {
      const bf16* ap = (const bf16*)A + base;
      a_s0 = *(const s8v*)ap;
      a_s1 = *(const s8v*)(ap + 8);
    } else {
      if (fA) {
        const float4* src = (const float4*)((const float*)A + base);
        #pragma unroll
        for (int q = 0; q < 4; ++q) {
          float4 v = src[q];
          a_f[q*4] = v.x; a_f[q*4+1] = v.y; a_f[q*4+2] = v.z; a_f[q*4+3] = v.w;
        }
      } else {
        #pragma unroll
        for (int q = 0; q < 16; ++q) a_f[q] = ldw(A, base + q, 0);
      }
    }
  };
  auto storeA = [&]() {
    if constexpr (AMODE == 2) {
      *(s8v*)&As[am * LSTR + ah] = a_s0;
      *(s8v*)&As[am * LSTR + ah + 8] = a_s1;
    } else {
      short tmp[16];
      #pragma unroll
      for (int q = 0; q < 16; ++q) tmp[q] = f2bf(a_f[q]);
      s4v* dst = (s4v*)&As[am * LSTR + ah];
      #pragma unroll
      for (int q = 0; q < 4; ++q) dst[q] = *(s4v*)&tmp[q*4];
    }
  };
  auto loadB = [&](int k0) {
    if constexpr (TRB) {
      int n = tid >> 1, h = (tid & 1) * 16;
      size_t base = zB + (size_t)(bn + n) * ldb + k0 + h;
      if constexpr (BMODE == 2) {
        const bf16* bp = (const bf16*)B + base;
        b_s0 = *(const s8v*)bp;
        b_s1 = *(const s8v*)(bp + 8);
      } else {
        if (fB) {
          const float4* src = (const float4*)((const float*)B + base);
          #pragma unroll
          for (int q = 0; q < 4; ++q) {
            float4 v = src[q];
            b_f[q*4] = v.x; b_f[q*4+1] = v.y; b_f[q*4+2] = v.z; b_f[q*4+3] = v.w;
          }
        } else {
          #pragma unroll
          for (int q = 0; q < 16; ++q) b_f[q] = ldw(B, base + q, 0);
        }
      }
    } else {
      int n = tid & 127, kk2 = (tid >> 7) * 16;
      #pragma unroll
      for (int j = 0; j < 16; ++j) {
        size_t bi = zB + (size_t)(k0 + kk2 + j) * ldb + bn + n;
        if constexpr (BMODE == 2) b_h[j] = ((const short*)B)[bi];
        else b_f[j] = ldT<BMODE == 1>(B, bi, fB);
      }
    }
  };
  auto storeB = [&]() {
    if constexpr (TRB) {
      int n = tid >> 1, h = (tid & 1) * 16;
      if constexpr (BMODE == 2) {
        *(s8v*)&Bs[n * LSTR + h] = b_s0;
        *(s8v*)&Bs[n * LSTR + h + 8] = b_s1;
      } else {
        short tmp[16];
        #pragma unroll
        for (int q = 0; q < 16; ++q) tmp[q] = f2bf(b_f[q]);
        s4v* dst = (s4v*)&Bs[n * LSTR + h];
        #pragma unroll
        for (int q = 0; q < 4; ++q) dst[q] = *(s4v*)&tmp[q*4];
      }
    } else {
      int n = tid & 127, kk2 = (tid >> 7) * 16;
      short tmp[16];
      #pragma unroll
      for (int j = 0; j < 16; ++j) tmp[j] = (BMODE == 2) ? b_h[j] : f2bf(b_f[j]);
      s4v* dst = (s4v*)&Bs[n * LSTR + kk2];
      #pragma unroll
      for (int q = 0; q < 4; ++q) dst[q] = *(s4v*)&tmp[q*4];
    }
  };

  loadA(0);
  loadB(0);
  for (int k0 = 0; k0 < K; k0 += 32) {
    storeA();
    storeB();
    __syncthreads();
    if (k0 + 32 < K) { loadA(k0 + 32); loadB(k0 + 32); }  // in-flight across MFMA
    s8v af[4], bfr[4];
    #pragma unroll
    for (int mi = 0; mi < 4; ++mi)
      af[mi] = *(const s8v*)&As[(wy + mi*16 + lm) * LSTR + quad * 8];
    #pragma unroll
    for (int ni = 0; ni < 4; ++ni)
      bfr[ni] = *(const s8v*)&Bs[(wx + ni*16 + lm) * LSTR + quad * 8];
    #pragma unroll
    for (int mi = 0; mi < 4; ++mi)
      #pragma unroll
      for (int ni = 0; ni < 4; ++ni)
        acc[mi][ni] = __builtin_amdgcn_mfma_f32_16x16x32_bf16(af[mi], bfr[ni], acc[mi][ni], 0, 0, 0);
    __syncthreads();
  }
  const int actc = DOMAP ? (int)((amap >> ((bn >> 7) * 2)) & 3ULL) : ACT;
  #pragma unroll
  for (int mi = 0; mi < 4; ++mi) {
    #pragma unroll
    for (int r = 0; r < 4; ++r) {
      int row = bm + wy + mi*16 + quad*4 + r;
      #pragma unroll
      for (int ni = 0; ni < 4; ++ni) {
        int col = bn + wx + ni*16 + lm;
        float v = acc[mi][ni][r] * alpha;
        if (ACCUM) v += Cz[(size_t)row * ldc + col];
        if (bias) v += ldT<DYNBIAS>(bias, zBias + col, fBi);
        if (actc == 1) v = fmaxf(v, 0.f);
        else if (actc == 2) v = tanhf(v);
        else if (actc == 3) v = 1.f / (1.f + expf(-v));
        if (OUTBF16) Cz16[(size_t)row * ldc + col] = __float2bfloat16(v);
        else Cz[(size_t)row * ldc + col] = v;
      }
    }
  }
}

template<int AMODE, int BMODE, bool DYNBIAS, bool TRB, int ACT, bool ACCUM,
         bool KSPLIT = false, bool OUTBF16 = false, bool DOMAP = false>
static void gemm(hipStream_t s, const void* A, int lda, const void* B, int ldb, size_t offB,
                 const void* bias, size_t offBias, float* C, int ldc, int M, int N, int K,
                 float alpha, int ia, int ib, int ibias, const int* flags,
                 int batch = 1, size_t sA = 0, size_t sB = 0, size_t sBias = 0, size_t sC = 0,
                 size_t kstrideA = 0, unsigned long long amap = 0) {
  dim3 g(N / 128, M / 128, batch), b(256);
  gemm_k<AMODE, BMODE, DYNBIAS, TRB, ACT, ACCUM, KSPLIT, OUTBF16, DOMAP><<<g, b, 0, s>>>(
      A, lda, B, ldb, offB, bias, offBias, C, ldc, M, N, K, alpha, ia, ib, ibias, flags,
      sA, sB, sBias, sC, kstrideA, amap);
}

// ---------------- LayerNorm (+relu/sigmoid), bf16/f32 in/out, strided ----------------
template<int ACT, bool INBF, bool OUTBF>
__global__ __launch_bounds__(256) void ln_k(const void* __restrict__ X, const void* __restrict__ g,
                                            const void* __restrict__ be, void* __restrict__ Y,
                                            int W, int ldx, int ldy,
                                            int ig, int ibe, const int* __restrict__ flags) {
  const int fG = flags[ig], fBe = flags[ibe];
  int row = blockIdx.x;
  const float* xf = (const float*)X + (size_t)row * ldx;
  const bf16* xb = (const bf16*)X + (size_t)row * ldx;
  float* yf = (float*)Y + (size_t)row * ldy;
  bf16* yb = (bf16*)Y + (size_t)row * ldy;
  __shared__ float red[256];
  int tid = threadIdx.x;
  float s1 = 0.f, s2 = 0.f;
  for (int i = tid; i < W; i += 256) {
    float v = INBF ? __bfloat162float(xb[i]) : xf[i];
    s1 += v; s2 += v * v;
  }
  red[tid] = s1; __syncthreads();
  for (int o = 128; o > 0; o >>= 1) { if (tid < o) red[tid] += red[tid + o]; __syncthreads(); }
  float mean = red[0] / W; __syncthreads();
  red[tid] = s2; __syncthreads();
  for (int o = 128; o > 0; o >>= 1) { if (tid < o) red[tid] += red[tid + o]; __syncthreads(); }
  float var = fmaxf(red[0] / W - mean * mean, 0.f);
  float rstd = rsqrtf(var + 1e-5f);
  for (int i = tid; i < W; i += 256) {
    float x = INBF ? __bfloat162float(xb[i]) : xf[i];
    float v = (x - mean) * rstd * ldw(g, i, fG) + ldw(be, i, fBe);
    if (ACT == 1) v = fmaxf(v, 0.f);
    else if (ACT == 3) v = 1.f / (1.f + expf(-v));
    if (OUTBF) yb[i] = __float2bfloat16(v);
    else yf[i] = v;
  }
}

// ================= comm round =================
__global__ void statepart_k(const short* __restrict__ featsC, float* __restrict__ part) {
  int a = blockIdx.x, g = blockIdx.y, e = threadIdx.x;
  const short* p = featsC + (size_t)a * FSTR + ((size_t)g * 128) * E_ + e;
  float s = 0.f;
  for (int n = 0; n < 128; ++n) s += bf2f(p[(size_t)n * E_]);
  part[((size_t)a * 16 + g) * E_ + e] = s;
}

__global__ void statecomb_k(const float* __restrict__ part, const void* __restrict__ internal,
                            float* __restrict__ state, const int* __restrict__ flags) {
  int a = blockIdx.x, e = threadIdx.x;
  float s = 0.f;
  for (int g = 0; g < 16; ++g) s += part[((size_t)a * 16 + g) * E_ + e];
  state[a * E_ + e] = s * (1.f / NS_) + ldw(internal, (size_t)a * E_ + e, flags[46]);
}

__global__ void mvpart_k(const float* __restrict__ x, const void* __restrict__ W, int iw,
                         float* __restrict__ part, const int* __restrict__ flags) {
  int a = blockIdx.x, g = blockIdx.y, f = threadIdx.x;
  const int fW = flags[iw];
  float s = 0.f;
  size_t wb = (size_t)a * E_ * E_ + f;
  for (int e = g * 32; e < g * 32 + 32; ++e)
    s += x[a * E_ + e] * ldw(W, wb + (size_t)e * E_, fW);
  part[((size_t)a * 8 + g) * E_ + f] = s;
}

template<int ACT>
__global__ void mvcomb_k(const float* __restrict__ part, const void* __restrict__ b, int ibb,
                         float* __restrict__ y, const int* __restrict__ flags) {
  int a = blockIdx.x, f = threadIdx.x;
  float s = 0.f;
  for (int g = 0; g < 8; ++g) s += part[((size_t)a * 8 + g) * E_ + f];
  s += ldw(b, (size_t)a * E_ + f, flags[ibb]);
  if (ACT == 1) s = fmaxf(s, 0.f);
  else if (ACT == 2) s = tanhf(s);
  y[a * E_ + f] = s;
}

__device__ inline float wave_sum64(float v) {
  for (int o = 32; o > 0; o >>= 1) v += __shfl_down(v, o);
  return v;
}

__global__ __launch_bounds__(256) void qkvcomm_k(const float* __restrict__ msg,
                                                 const void* __restrict__ comm_w,
                                                 const void* __restrict__ in_w,
                                                 const void* __restrict__ in_b,
                                                 float* __restrict__ qkvc,
                                                 const int* __restrict__ flags) {
  const int fCW = flags[57], fIW = flags[38], fIB = flags[39];
  int gw = blockIdx.x * 4 + (threadIdx.x >> 6);
  int a = gw / 768, f = gw % 768;
  int lane = threadIdx.x & 63;
  float w[5]; float mx = -1e30f;
  for (int j = 0; j < 5; ++j) { w[j] = ldw(comm_w, a * 5 + j, fCW); mx = fmaxf(mx, w[j]); }
  float sum = 0.f;
  for (int j = 0; j < 5; ++j) { w[j] = __expf(w[j] - mx); sum += w[j]; }
  for (int j = 0; j < 5; ++j) w[j] /= sum;
  int others[4]; { int c = 0; for (int j = 0; j < 5; ++j) if (j != a) others[c++] = j; }
  int e0 = lane * 4;
  float4 wv;
  size_t b = (size_t)a * 768 * E_ + (size_t)f * E_ + e0;
  if (fIW) wv = *(const float4*)((const float*)in_w + b);
  else wv = make_float4(ldw(in_w, b, 0), ldw(in_w, b + 1, 0), ldw(in_w, b + 2, 0), ldw(in_w, b + 3, 0));
  float acc[4];
  #pragma unroll
  for (int t = 0; t < 4; ++t) {
    const float4 mv = *(const float4*)(msg + others[t] * E_ + e0);
    acc[t] = mv.x * wv.x + mv.y * wv.y + mv.z * wv.z + mv.w * wv.w;
  }
  #pragma unroll
  for (int t = 0; t < 4; ++t) acc[t] = wave_sum64(acc[t]);
  if (lane == 0) {
    float bb = ldw(in_b, (size_t)a * 768 + f, fIB);
    #pragma unroll
    for (int t = 0; t < 4; ++t)
      qkvc[((size_t)a * 4 + t) * 768 + f] = acc[t] * w[others[t]] + bb;
  }
}

__global__ __launch_bounds__(256) void attn4_k(const float* __restrict__ qkvc,
                                               float* __restrict__ obar) {
  int a = blockIdx.x, tid = threadIdx.x;
  __shared__ float qkv[4][768];
  __shared__ float attw[4][16];
  for (int i = tid; i < 4 * 768; i += 256) qkv[i / 768][i % 768] = qkvc[(size_t)a * 4 * 768 + i];
  __syncthreads();
  if (tid < 16) {
    int h = tid >> 2, t = tid & 3;
    float sc[4]; float mx = -1e30f;
    for (int t2 = 0; t2 < 4; ++t2) {
      float s = 0.f;
      for (int d = 0; d < 64; ++d) s += qkv[t][h * 64 + d] * qkv[t2][256 + h * 64 + d];
      sc[t2] = s * 0.125f; mx = fmaxf(mx, sc[t2]);
    }
    float ss = 0.f;
    for (int t2 = 0; t2 < 4; ++t2) { sc[t2] = __expf(sc[t2] - mx); ss += sc[t2]; }
    for (int t2 = 0; t2 < 4; ++t2) attw[h][t * 4 + t2] = sc[t2] / ss;
  }
  __syncthreads();
  {
    int e = tid, h = e >> 6;
    float s = 0.f;
    for (int t = 0; t < 4; ++t)
      for (int t2 = 0; t2 < 4; ++t2)
        s += attw[h][t * 4 + t2] * qkv[t2][512 + e];
    obar[a * E_ + e] = s * 0.25f;
  }
}

__global__ __launch_bounds__(256) void combproj_k(const float* __restrict__ obar,
                                                  const void* __restrict__ ow,
                                                  const void* __restrict__ ob,
                                                  const void* __restrict__ internal,
                                                  float* __restrict__ comb,
                                                  const int* __restrict__ flags) {
  const int fOW = flags[40], fOB = flags[41], fIN = flags[46];
  int gw = blockIdx.x * 4 + (threadIdx.x >> 6);
  int a = gw >> 8, f = gw & 255;
  int lane = threadIdx.x & 63;
  int e0 = lane * 4;
  float4 wv;
  size_t b = (size_t)a * E_ * E_ + (size_t)f * E_ + e0;
  if (fOW) wv = *(const float4*)((const float*)ow + b);
  else wv = make_float4(ldw(ow, b, 0), ldw(ow, b + 1, 0), ldw(ow, b + 2, 0), ldw(ow, b + 3, 0));
  const float4 ov = *(const float4*)(obar + a * E_ + e0);
  float s = wave_sum64(ov.x * wv.x + ov.y * wv.y + ov.z * wv.z + ov.w * wv.w);
  if (lane == 0)
    comb[a * E_ + f] = ldw(internal, (size_t)a * E_ + f, fIN) + s + ldw(ob, (size_t)a * E_ + f, fOB);
}

__global__ __launch_bounds__(256) void ckb_k(const float* __restrict__ ck,
                                             const void* __restrict__ in_w,
                                             const void* __restrict__ in_b,
                                             float* __restrict__ ckb,
                                             const int* __restrict__ flags) {
  const int fW = flags[47], fB = flags[48];
  int gw = blockIdx.x * 4 + (threadIdx.x >> 6);
  int a = gw / 768, f = gw % 768;
  int lane = threadIdx.x & 63;
  int e0 = lane * 4;
  float4 wv;
  size_t b = (size_t)a * 768 * E_ + (size_t)f * E_ + e0;
  if (fW) wv = *(const float4*)((const float*)in_w + b);
  else wv = make_float4(ldw(in_w, b, 0), ldw(in_w, b + 1, 0), ldw(in_w, b + 2, 0), ldw(in_w, b + 3, 0));
  const float4 cv = *(const float4*)(ck + a * E_ + e0);
  float s = wave_sum64(cv.x * wv.x + cv.y * wv.y + cv.z * wv.z + cv.w * wv.w);
  if (lane == 0) ckb[(size_t)a * 768 + f] = s + ldw(in_b, (size_t)a * 768 + f, fB);
}

// ======== MFMA class-block attention (qkv_all is bf16) ========
#define LS 136
__device__ inline void stage64x128(const short* __restrict__ qkv, const int* __restrict__ myidx,
                                   int row0, int n, int ho, short* dst) {
  int t = threadIdx.x;
  int r = t >> 2, c0 = (t & 3) * 32;
  int rr = row0 + r;
  s8v v0 = (s8v)(short)0, v1 = v0, v2 = v0, v3 = v0;
  if (rr < n) {
    const s8v* s = (const s8v*)(qkv + (size_t)myidx[rr] * 768 + ho + c0);
    v0 = s[0]; v1 = s[1]; v2 = s[2]; v3 = s[3];
  }
  s8v* d = (s8v*)&dst[r * LS + c0];
  d[0] = v0; d[1] = v1; d[2] = v2; d[3] = v3;
}

__global__ __launch_bounds__(256) void attn_stats_k(
    const short* __restrict__ qkv_all, const int* __restrict__ idx,
    const int* __restrict__ cnt, const int* __restrict__ cstart,
    float* __restrict__ ml)
{
  int c = blockIdx.x, z = blockIdx.z, a = z >> 1, h = z & 1;
  int n = cnt[c];
  int r0 = blockIdx.y * 64;
  if (r0 >= n) return;
  const short* qkv = qkv_all + (size_t)a * NS_ * 768;
  const int* myidx = idx + c * NS_;
  __shared__ short Qs[64 * LS];
  __shared__ short Ks[64 * LS];
  __shared__ float Mw[4][64], Lw[4][64];
  int tid = threadIdx.x, lane = tid & 63, wid = tid >> 6;
  int lm = lane & 15, quad = lane >> 4;
  stage64x128(qkv, myidx, r0, n, h * 128, Qs);
  float m_run[16], l_run[16];
  #pragma unroll
  for (int i = 0; i < 16; ++i) { m_run[i] = -3e38f; l_run[i] = 0.f; }
  for (int j0 = 0; j0 < n; j0 += 64) {
    __syncthreads();
    stage64x128(qkv, myidx, j0, n, 256 + h * 128, Ks);
    __syncthreads();
    f4v acc[4];
    #pragma unroll
    for (int mi = 0; mi < 4; ++mi) acc[mi] = (f4v)(0.f);
    #pragma unroll
    for (int kc = 0; kc < 4; ++kc) {
      s8v bfr = *(const s8v*)&Ks[(wid * 16 + lm) * LS + kc * 32 + quad * 8];
      #pragma unroll
      for (int mi = 0; mi < 4; ++mi) {
        s8v af = *(const s8v*)&Qs[(mi * 16 + lm) * LS + kc * 32 + quad * 8];
        acc[mi] = __builtin_amdgcn_mfma_f32_16x16x32_bf16(af, bfr, acc[mi], 0, 0, 0);
      }
    }
    int col = j0 + wid * 16 + lm;
    bool cv = col < n;
    #pragma unroll
    for (int mi = 0; mi < 4; ++mi) {
      #pragma unroll
      for (int r = 0; r < 4; ++r) {
        float s = cv ? acc[mi][r] * QSCALE : -3e38f;
        float m = s;
        m = fmaxf(m, __shfl_xor(m, 1));
        m = fmaxf(m, __shfl_xor(m, 2));
        m = fmaxf(m, __shfl_xor(m, 4));
        m = fmaxf(m, __shfl_xor(m, 8));
        float p = cv ? __expf(s - m) : 0.f;
        p += __shfl_xor(p, 1); p += __shfl_xor(p, 2);
        p += __shfl_xor(p, 4); p += __shfl_xor(p, 8);
        int ri = mi * 4 + r;
        float mo = m_run[ri];
        float mn = fmaxf(mo, m);
        l_run[ri] = l_run[ri] * __expf(mo - mn) + p * __expf(m - mn);
        m_run[ri] = mn;
      }
    }
  }
  if (lm == 0) {
    #pragma unroll
    for (int mi = 0; mi < 4; ++mi)
      #pragma unroll
      for (int r = 0; r < 4; ++r) {
        int row = mi * 16 + quad * 4 + r;
        Mw[wid][row] = m_run[mi * 4 + r];
        Lw[wid][row] = l_run[mi * 4 + r];
      }
  }
  __syncthreads();
  if (tid < 64 && r0 + tid < n) {
    float m = fmaxf(fmaxf(Mw[0][tid], Mw[1][tid]), fmaxf(Mw[2][tid], Mw[3][tid]));
    float l = Lw[0][tid] * __expf(Mw[0][tid] - m) + Lw[1][tid] * __expf(Mw[1][tid] - m)
            + Lw[2][tid] * __expf(Mw[2][tid] - m) + Lw[3][tid] * __expf(Mw[3][tid] - m);
    size_t p = (size_t)z * NS_ + cstart[c] + r0 + tid;
    ml[p * 2] = m; ml[p * 2 + 1] = l;
  }
}

__global__ __launch_bounds__(256) void attn_colsum_k(
    const short* __restrict__ qkv_all, const int* __restrict__ idx,
    const int* __restrict__ cnt, const int* __restrict__ cstart,
    const float* __restrict__ ml, float* __restrict__ colsum)
{
  int c = blockIdx.x, z = blockIdx.z, a = z >> 1, h = z & 1;
  int n = cnt[c];
  int j0 = blockIdx.y * 64;
  if (j0 >= n) return;
  const short* qkv = qkv_all + (size_t)a * NS_ * 768;
  const int* myidx = idx + c * NS_;
  __shared__ short Qs[64 * LS];
  __shared__ short Ks[64 * LS];
  __shared__ float Msm[64], Lsm[64];
  int tid = threadIdx.x, lane = tid & 63, wid = tid >> 6;
  int lm = lane & 15, quad = lane >> 4;
  stage64x128(qkv, myidx, j0, n, 256 + h * 128, Ks);
  float ca = 0.f;
  for (int i0 = 0; i0 < n; i0 += 64) {
    __syncthreads();
    stage64x128(qkv, myidx, i0, n, h * 128, Qs);
    if (tid < 64) {
      int gi = i0 + tid;
      if (gi < n) {
        size_t p = (size_t)z * NS_ + cstart[c] + gi;
        Msm[tid] = ml[p * 2]; Lsm[tid] = ml[p * 2 + 1];
      } else { Msm[tid] = 0.f; Lsm[tid] = 1.f; }
    }
    __syncthreads();
    f4v acc[4];
    #pragma unroll
    for (int mi = 0; mi < 4; ++mi) acc[mi] = (f4v)(0.f);
    #pragma unroll
    for (int kc = 0; kc < 4; ++kc) {
      s8v bfr = *(const s8v*)&Ks[(wid * 16 + lm) * LS + kc * 32 + quad * 8];
      #pragma unroll
      for (int mi = 0; mi < 4; ++mi) {
        s8v af = *(const s8v*)&Qs[(mi * 16 + lm) * LS + kc * 32 + quad * 8];
        acc[mi] = __builtin_amdgcn_mfma_f32_16x16x32_bf16(af, bfr, acc[mi], 0, 0, 0);
      }
    }
    #pragma unroll
    for (int mi = 0; mi < 4; ++mi) {
      #pragma unroll
      for (int r = 0; r < 4; ++r) {
        int lrow = mi * 16 + quad * 4 + r;
        int gi = i0 + lrow;
        if (gi < n) {
          float m = Msm[lrow];
          float invl = 1.f / Lsm[lrow];
          ca += __expf(acc[mi][r] * QSCALE - m) * invl;
        }
      }
    }
  }
  ca += __shfl_xor(ca, 16);
  ca += __shfl_xor(ca, 32);
  int col = j0 + wid * 16 + lm;
  if (quad == 0 && col < n)
    colsum[(size_t)z * NS_ + cstart[c] + col] = ca;
}

// ---- proto combine: K-chunked 2-stage ----
#define PCH 8
__global__ void proto_part_k(const short* __restrict__ qkv_all, const int* __restrict__ idx,
                             const int* __restrict__ cnt, const int* __restrict__ cstart,
                             const float* __restrict__ colsum, float* __restrict__ part) {
  int c = blockIdx.x, a = blockIdx.y, ch = blockIdx.z;
  int e = threadIdx.x, h = e >> 7, d = e & 127;
  int n = cnt[c];
  int k0 = ch * 256, k1 = min(k0 + 256, n);
  float s = 0.f;
  const short* qkv = qkv_all + (size_t)a * NS_ * 768;
  const float* csum = colsum + (size_t)(a * 2 + h) * NS_ + cstart[c];
  const int* myidx = idx + c * NS_;
  for (int k = k0; k < k1; ++k)
    s += csum[k] * bf2f(qkv[(size_t)myidx[k] * 768 + 512 + h * 128 + d]);
  part[(((size_t)a * NWAY_ + c) * PCH + ch) * E_ + e] = s;
}

__global__ void proto_comb2_k(const float* __restrict__ part, const int* __restrict__ cnt,
                              float* __restrict__ proto_pre) {
  int c = blockIdx.x, a = blockIdx.y, e = threadIdx.x;
  int n = cnt[c];
  float s = 0.f;
  for (int ch = 0; ch < PCH; ++ch)
    s += part[(((size_t)a * NWAY_ + c) * PCH + ch) * E_ + e];
  proto_pre[((size_t)a * NWAY_ + c) * E_ + e] = (n > 0) ? s / (float)n : 0.f;
}

__global__ void proto_outproj_k(const float* __restrict__ proto_pre, const void* __restrict__ ow,
                                const void* __restrict__ ob, const int* __restrict__ cnt,
                                float* __restrict__ protos_all, const int* __restrict__ flags) {
  int c = blockIdx.x, a = blockIdx.y, e = threadIdx.x;
  const int fW = flags[49], fB = flags[50];
  __shared__ float pp[E_];
  pp[e] = proto_pre[((size_t)a * NWAY_ + c) * E_ + e];
  __syncthreads();
  size_t wb = (size_t)a * E_ * E_ + (size_t)e * E_;
  float s = 0.f;
  for (int k = 0; k < E_; ++k) s += pp[k] * ldw(ow, wb + k, fW);
  float v = s + ldw(ob, (size_t)a * E_ + e, fB);
  protos_all[((size_t)a * NWAY_ + c) * E_ + e] = (cnt[c] > 0) ? v : 0.f;
}

// ---- biascat2[a][0:256] = ck@w1[256:512] + b1; [256:512] = 0 ----
__global__ void bias2_k(const float* __restrict__ ck, const void* __restrict__ w1,
                        const void* __restrict__ b1, float* __restrict__ biascat2,
                        const int* __restrict__ flags) {
  const int fW = flags[51], fB = flags[52];
  int a = blockIdx.x, n = threadIdx.x;
  __shared__ float c[E_];
  c[n] = ck[a * E_ + n]; __syncthreads();
  size_t wbase = (size_t)a * 2 * E_ * E_ + (size_t)E_ * E_ + n;
  float s = 0.f;
  for (int k = 0; k < E_; ++k) s += c[k] * ldw(w1, wbase + (size_t)k * E_, fW);
  biascat2[(size_t)a * 512 + n] = s + ldw(b1, (size_t)a * E_ + n, fB);
  biascat2[(size_t)a * 512 + 256 + n] = 0.f;
}

// ---- fusion combine: fh1 = relu(sum_a U[a][:,256:512] + f_b1) ----
__global__ void fcomb_k(const short* __restrict__ U, const void* __restrict__ b1,
                        short* __restrict__ fh1, const int* __restrict__ flags) {
  int i = blockIdx.x, n = threadIdx.x;
  const int fB = flags[59];
  float s = 0.f;
  #pragma unroll
  for (int a = 0; a < A_; ++a)
    s += bf2f(U[((size_t)a * NQ_ + i) * 512 + 256 + n]);
  s += ldw(b1, n, fB);
  fh1[(size_t)i * 256 + n] = f2bf(fmaxf(s, 0.f));
}

// ---------------- epilogues ----------------
__global__ __launch_bounds__(64) void logits_k(const short* __restrict__ fqbase,
                                               const float* __restrict__ protos_all,
                                               const bf16* __restrict__ c2all,
                                               const void* __restrict__ w3,
                                               const void* __restrict__ b3,
                                               float* __restrict__ out,
                                               const int* __restrict__ flags) {
  const int fW = flags[55], fB = flags[56];
  int i = blockIdx.x, a = blockIdx.y, lane = threadIdx.x;
  const short* fq = fqbase + (size_t)a * FSTR + (size_t)i * E_ + lane * 4;
  const float* protos = protos_all + (size_t)a * NWAY_ * E_;
  const bf16* c2 = c2all + ((size_t)a * NQ_ + i) * 128;
  s4v xv4 = *(const s4v*)fq;
  float x0 = bf2f(xv4[0]), x1 = bf2f(xv4[1]), x2 = bf2f(xv4[2]), x3 = bf2f(xv4[3]);
  float qq = wave_sum64(x0 * x0 + x1 * x1 + x2 * x2 + x3 * x3);
  float cpart = __bfloat162float(c2[lane * 2]) * ldw(w3, (size_t)a * 128 + lane * 2, fW) +
                __bfloat162float(c2[lane * 2 + 1]) * ldw(w3, (size_t)a * 128 + lane * 2 + 1, fW);
  float conf = wave_sum64(cpart);
  if (lane == 0) conf += ldw(b3, a, fB);
  for (int c = 0; c < NWAY_; ++c) {
    float4 pv = ((const float4*)(protos + c * E_))[lane];
    float dt = wave_sum64(x0 * pv.x + x1 * pv.y + x2 * pv.z + x3 * pv.w);
    float pp = wave_sum64(pv.x * pv.x + pv.y * pv.y + pv.z * pv.z + pv.w * pv.w);
    if (lane == 0) {
      float d2 = fmaxf(qq + pp - 2.f * dt, 1e-12f);
      out[((size_t)a * NQ_ + i) * NWAY_ + c] = -sqrtf(d2) + 0.1f * conf;
    }
  }
}

__global__ __launch_bounds__(64) void fused_k(const float* __restrict__ h2, const void* __restrict__ w3,
                                              const void* __restrict__ b3, float* __restrict__ out,
                                              const int* __restrict__ flags) {
  const int fW = flags[62], fB = flags[63];
  int i = blockIdx.x, lane = threadIdx.x;
  float s = h2[(size_t)i * 128 + lane * 2] * ldw(w3, lane * 2, fW) +
            h2[(size_t)i * 128 + lane * 2 + 1] * ldw(w3, lane * 2 + 1, fW);
  s = wave_sum64(s);
  if (lane == 0) out[i] = s + ldw(b3, 0, fB);
}

// ---------------- host ----------------
extern "C" void kernel_launch(void* const* d_in, const int* in_sizes, int n_in,
                              void* d_out, int out_size, void* d_ws, size_t ws_size,
                              hipStream_t stream) {
  (void)out_size; (void)ws_size;
  #define P(i) ((const void*)d_in[i])
  const int* support_y = (const int*)d_in[1];
  float* out = (float*)d_out;

  int* flags = (int*)d_ws;
  char* base = (char*)d_ws + 256;
  short* featsC = (short*)base;                        // bf16 [A][NM][E]
  char* R = base + (size_t)A_ * FSTR * 2;
  short* t1cat   = (short*)R;                          // [NM][2304] bf16
  short* qkv_all = (short*)R;                          // [A][NS][768] bf16
  short* U       = (short*)(R + (size_t)15728640);     // [A][NQ][512] bf16
  short* fh1     = (short*)R;                          // [NQ][256] bf16
  float* fh2     = (float*)(R + (size_t)8388608);      // [NQ][128] f32
  char* XCR = R + (size_t)57671680;
  short* XC   = (short*)XCR;
  short* tmp2 = (short*)XCR;
  short* b4   = (short*)(XCR + (size_t)NM_ * 256 * 2);
  short* clsC2_all = (short*)XCR;
  char* S = XCR + (size_t)10485760;
  float* state      = (float*)S;
  float* msg        = state + A_ * E_;
  float* ck         = msg + A_ * E_;
  float* protos_all = ck + A_ * E_;
  float* biascat2   = protos_all + A_ * NWAY_ * E_;
  float* ml         = biascat2 + A_ * 512;
  float* colsum     = ml + (size_t)A_ * 2 * NS_ * 2;
  float* proto_pre  = colsum + (size_t)A_ * 2 * NS_;
  int*   idx        = (int*)(proto_pre + A_ * NWAY_ * E_);
  int*   cnt        = idx + NWAY_ * NS_;
  int*   cstart     = cnt + NWAY_;
  float* statepart  = (float*)(cstart + NWAY_ + 3);
  float* mvp        = statepart + A_ * 16 * E_;
  float* qkvc       = mvp + A_ * 8 * E_;
  float* obar       = qkvc + A_ * 4 * 768;
  float* comb       = obar + A_ * E_;
  float* hh         = comb + A_ * E_;
  float* ckb        = hh + A_ * E_;
  float* ppart      = ckb + A_ * 768;
  float* bcat       = ppart + (size_t)A_ * NWAY_ * PCH * E_;
  short* Wcat       = (short*)(bcat + 2304);
  short* Bcat2      = Wcat + (size_t)2304 * 512;

  const short* fq_base = featsC + (size_t)NS_ * E_;

  Ptrs ps;
  for (int i = 0; i < 64; ++i) {
    ps.p[i] = (i < n_in) ? d_in[i] : nullptr;
    ps.sz[i] = (i < n_in) ? in_sizes[i] : 0;
  }
  probe_k<<<64, 64, 0, stream>>>(ps, flags);
  classidx_k<<<1, 256, 0, stream>>>(support_y, idx, cnt, cstart);
  xcopy_k<<<(NM_ * 512 / 4) / 256, 256, 0, stream>>>(P(0), P(2), XC, flags);
  wcat_k<<<dim3(9, 512), 256, 0, stream>>>(ps, Wcat, bcat, flags);
  wcls_k<<<dim3(512, A_), 256, 0, stream>>>(P(51), P(58), Bcat2, flags);

  // ---- FE: mega layer-1 GEMM (N = 2304), per-tile act map ----
  gemm<2, 2, false, true, 0, false, false, true, true>(
      stream, XC, 512, Wcat, 512, 0, bcat, 0, (float*)t1cat, 2304,
      NM_, 2304, 512, 1.f, -1, -1, -1, flags, 1, 0, 0, 0, 0, 0, 0x555555000ULL);
  ln_k<1, true, true><<<NM_, 256, 0, stream>>>(t1cat, P(6), P(7), t1cat, 512, 2304, 2304, 6, 7, flags);
  gemm<2, 1, true, false, 0, false, false, true>(stream, t1cat, 2304, P(8), 256, 0, P(9), 0,
                                                 (float*)tmp2, 256, NM_, 256, 512, 1.f, -1, 8, 9, flags);
  ln_k<1, true, true><<<NM_, 256, 0, stream>>>(tmp2, P(10), P(11), featsC, 256, 256, 256, 10, 11, flags);
  ln_k<1, true, true><<<NM_, 256, 0, stream>>>(t1cat + 512, P(14), P(15), t1cat + 512, 256, 2304, 2304, 14, 15, flags);
  gemm<2, 1, true, false, 2, false, false, true>(stream, t1cat + 512, 2304, P(16), 256, 0, P(17), 0,
                                                 (float*)(featsC + FSTR), 256, NM_, 256, 256, 1.f, -1, 16, 17, flags);
  gemm<2, 1, true, false, 0, false, false, true>(stream, t1cat + 768, 2304, P(20), 256, 0, P(21), 0,
                                                 (float*)tmp2, 256, NM_, 256, 768, 1.f, -1, 20, 21, flags);
  ln_k<1, true, true><<<NM_, 256, 0, stream>>>(tmp2, P(22), P(23), featsC + 2 * FSTR, 256, 256, 256, 22, 23, flags);
  gemm<2, 1, true, false, 0, false, false, true>(stream, t1cat + 1536, 2304, P(26), 256, 0, P(27), 0,
                                                 (float*)tmp2, 256, NM_, 256, 256, 1.f, -1, 26, 27, flags);
  ln_k<3, true, true><<<NM_, 256, 0, stream>>>(tmp2, P(28), P(29), featsC + 3 * FSTR, 256, 256, 256, 28, 29, flags);
  gemm<2, 1, true, false, 1, false, false, true>(stream, t1cat + 1792, 2304, P(32), 256, 0, P(33), 0,
                                                 (float*)b4, 256, NM_, 256, 512, 1.f, -1, 32, 33, flags);
  gemm<2, 1, true, false, 0, false, false, true>(stream, b4, 256, P(34), 256, 0, P(35), 0,
                                                 (float*)(featsC + 4 * FSTR), 256, NM_, 256, 256, 1.f, -1, 34, 35, flags);

  // ---- comm round ----
  statepart_k<<<dim3(A_, 16), 256, 0, stream>>>(featsC, statepart);
  statecomb_k<<<A_, 256, 0, stream>>>(statepart, P(46), state, flags);
  mvpart_k<<<dim3(A_, 8), 256, 0, stream>>>(state, P(36), 36, mvp, flags);
  mvcomb_k<2><<<A_, 256, 0, stream>>>(mvp, P(37), 37, msg, flags);
  qkvcomm_k<<<A_ * 768 / 4, 256, 0, stream>>>(msg, P(57), P(38), P(39), qkvc, flags);
  attn4_k<<<A_, 256, 0, stream>>>(qkvc, obar);
  combproj_k<<<A_ * E_ / 4, 256, 0, stream>>>(obar, P(40), P(41), P(46), comb, flags);
  mvpart_k<<<dim3(A_, 8), 256, 0, stream>>>(comb, P(42), 42, mvp, flags);
  mvcomb_k<1><<<A_, 256, 0, stream>>>(mvp, P(43), 43, hh, flags);
  mvpart_k<<<dim3(A_, 8), 256, 0, stream>>>(hh, P(44), 44, mvp, flags);
  mvcomb_k<0><<<A_, 256, 0, stream>>>(mvp, P(45), 45, ck, flags);

  // ---- batched prototype attention (ck folded into qkv bias; qkv bf16) ----
  ckb_k<<<A_ * 768 / 4, 256, 0, stream>>>(ck, P(47), P(48), ckb, flags);
  gemm<2, 1, false, true, 0, false, false, true>(stream, featsC, 256, P(47), 256, 0, ckb, 0,
                                    (float*)qkv_all, 768, NS_, 768, 256, 1.f, -1, 47, -1, flags,
                                    A_, FSTR, (size_t)3 * E_ * E_, (size_t)768, (size_t)NS_ * 768);
  {
    dim3 g(NWAY_, NS_ / 64, A_ * 2);
    attn_stats_k<<<g, 256, 0, stream>>>(qkv_all, idx, cnt, cstart, ml);
    attn_colsum_k<<<g, 256, 0, stream>>>(qkv_all, idx, cnt, cstart, ml, colsum);
  }
  proto_part_k<<<dim3(NWAY_, A_, PCH), 256, 0, stream>>>(qkv_all, idx, cnt, cstart, colsum, ppart);
  proto_comb2_k<<<dim3(NWAY_, A_), 256, 0, stream>>>(ppart, cnt, proto_pre);
  proto_outproj_k<<<dim3(NWAY_, A_), 256, 0, stream>>>(proto_pre, P(49), P(50), cnt, protos_all, flags);
  bias2_k<<<A_, 256, 0, stream>>>(ck, P(51), P(52), biascat2, flags);

  // ---- combined cls1 + fusion-partial GEMM ----
  gemm<2, 2, false, true, 0, false, false, true, true>(
      stream, fq_base, 256, Bcat2, 256, 0, biascat2, 0, (float*)U, 512,
      NQ_, 512, 256, 1.f, -1, -1, -1, flags,
      A_, FSTR, (size_t)512 * 256, (size_t)512, (size_t)NQ_ * 512, 0, 0x5ULL);
  fcomb_k<<<NQ_, 256, 0, stream>>>(U, P(59), fh1, flags);

  // ---- cls2 + logits ----
  gemm<2, 1, true, false, 1, false, false, true>(stream, U, 512, P(53), 128, 0,
                                     P(54), 0, (float*)clsC2_all, 128, NQ_, 128, 256, 1.f, -1, 53, 54, flags,
                                     A_, (size_t)NQ_ * 512, (size_t)E_ * 128, (size_t)128, (size_t)NQ_ * 128);
  logits_k<<<dim3(NQ_, A_), 64, 0, stream>>>(fq_base, protos_all, (const bf16*)clsC2_all, P(55), P(56), out, flags);

  // ---- fusion layer-2 + output ----
  gemm<2, 1, true, false, 1, false>(stream, fh1, 256, P(60), 128, 0, P(61), 0, fh2, 128, NQ_, 128, 256, 1.f, -1, 60, 61, flags);
  fused_k<<<NQ_, 64, 0, stream>>>(fh2, P(62), P(63), out + (size_t)A_ * NQ_ * NWAY_, flags);
}